// Round 2
// baseline (13825.368 us; speedup 1.0000x reference)
//
#include <hip/hip_runtime.h>
#include <cmath>

#define ROWS 8
#define THREADS 512
#define THREADS2 1024
#define NB 2048
#define TSTEPS 128
#define DXF 409

struct Params {
  const float *x;
  const float *Wl,*bWl,*Ul,*bUl,*Vl,*bVl;
  const float *Wa,*bWa,*Ua,*bUa,*Va,*bVa;
  const float *Wv,*bWv,*Uv,*bUv,*Vv,*bVv;
  const float *nlW1,*nlb1,*nlW2,*nlb2;
  const float *naW1,*nab1,*naW2,*nab2;
  const float *nvW1,*nvb1,*nvW2,*nvb2;
  const float *attW1,*attb1,*attW2,*attb2;
  const float *outW1,*outb1,*outW2,*outb2;
  const float *ws;   // precomputed XW [T*N][1024] (L:0-511, A:512-767, V:768-1023)
  float *out;
};

__device__ __forceinline__ float sigm(float x){ return 1.0f/(1.0f+__expf(-x)); }

// ---------------- original acc_mm (tail-capable) ----------------
template<int COLS,int KDIM,int INSTRIDE>
__device__ __forceinline__ void acc_mm(const float* __restrict__ W,
                                       const float* __restrict__ in,
                                       float acc[ROWS], int j)
{
  constexpr int K4 = KDIM/4;
  #pragma unroll 2
  for (int k4=0;k4<K4;k4++){
    const int k=4*k4;
    float w0=W[(k+0)*COLS+j];
    float w1=W[(k+1)*COLS+j];
    float w2=W[(k+2)*COLS+j];
    float w3=W[(k+3)*COLS+j];
    #pragma unroll
    for (int r=0;r<ROWS;r++){
      const float4 v = *(const float4*)(in + r*INSTRIDE + k);
      acc[r]=fmaf(v.w,w3,fmaf(v.z,w2,fmaf(v.y,w1,fmaf(v.x,w0,acc[r]))));
    }
  }
  if constexpr ((KDIM & 3) != 0) {
    #pragma unroll
    for (int k=K4*4;k<KDIM;k++){
      float wv=W[k*COLS+j];
      #pragma unroll
      for (int r=0;r<ROWS;r++) acc[r]=fmaf(in[r*INSTRIDE+k],wv,acc[r]);
    }
  }
}

// ---------------- prefetching acc_mm (KDIM % 4 == 0) ----------------
template<int COLS,int KDIM,int INSTRIDE>
__device__ __forceinline__ void acc_mm_p(const float* __restrict__ W,
                                         const float* __restrict__ in,
                                         float acc[ROWS], int j)
{
  static_assert((KDIM & 3) == 0, "KDIM must be multiple of 4");
  constexpr int K4 = KDIM/4;
  const float* wp = W + j;
  float w0=wp[0], w1=wp[COLS], w2=wp[2*COLS], w3=wp[3*COLS];
  #pragma unroll 4
  for (int k4=0;k4<K4;k4++){
    float n0=0.f,n1=0.f,n2=0.f,n3=0.f;
    if (k4+1<K4){
      const float* wn = wp + 4*COLS;
      n0=wn[0]; n1=wn[COLS]; n2=wn[2*COLS]; n3=wn[3*COLS];
    }
    const float* ip = in + 4*k4;
    #pragma unroll
    for (int r=0;r<ROWS;r++){
      const float4 v = *(const float4*)(ip + r*INSTRIDE);
      acc[r]=fmaf(v.w,w3,fmaf(v.z,w2,fmaf(v.y,w1,fmaf(v.x,w0,acc[r]))));
    }
    w0=n0;w1=n1;w2=n2;w3=n3;
    wp += 4*COLS;
  }
}

// ================= XW GEMM: out[m][cb+n] = sum_k x[m][xoff+k] * W[k][n] =================
// BM=128, BN=128, BK=32, 256 threads, 8x8 microtile.
__global__ __launch_bounds__(256)
void xw_gemm(const float* __restrict__ x, const float* __restrict__ W,
             float* __restrict__ out, int K, int WN, int cb, int xoff)
{
  __shared__ float As[32][128];
  __shared__ float Bs[32][128];
  const int t = threadIdx.x;
  const int m0 = blockIdx.x * 128;
  const int n0t = blockIdx.y * 128;
  const int arow = t & 127, akh = (t >> 7) * 16;
  const int bk = t >> 3,  bj = (t & 7) * 16;
  const int rbase = (t >> 4) * 8, cbase = (t & 15) * 4;

  float acc[8][8];
  #pragma unroll
  for (int i=0;i<8;i++)
    #pragma unroll
    for (int jj=0;jj<8;jj++) acc[i][jj]=0.f;

  const int nch = (K + 31) >> 5;
  for (int ch=0; ch<nch; ++ch){
    const int kc = ch*32;
    // stage A (transposed): As[k][row]
    const float* xp = x + (size_t)(m0+arow)*DXF + xoff + kc + akh;
    #pragma unroll
    for (int e=0;e<16;e++){
      int k = akh + e;
      As[k][arow] = (kc + k < K) ? xp[e] : 0.f;
    }
    // stage B: Bs[k][j]
    if (kc + bk < K){
      const float* wp = W + (size_t)(kc+bk)*WN + n0t + bj;
      #pragma unroll
      for (int e=0;e<16;e+=4)
        *(float4*)&Bs[bk][bj+e] = *(const float4*)&wp[e];
    } else {
      #pragma unroll
      for (int e=0;e<16;e++) Bs[bk][bj+e] = 0.f;
    }
    __syncthreads();
    #pragma unroll 8
    for (int k=0;k<32;k++){
      float4 a0 = *(const float4*)&As[k][rbase];
      float4 a1 = *(const float4*)&As[k][rbase+4];
      float4 b0 = *(const float4*)&Bs[k][cbase];
      float4 b1 = *(const float4*)&Bs[k][cbase+64];
      float av[8] = {a0.x,a0.y,a0.z,a0.w,a1.x,a1.y,a1.z,a1.w};
      float bv[8] = {b0.x,b0.y,b0.z,b0.w,b1.x,b1.y,b1.z,b1.w};
      #pragma unroll
      for (int i=0;i<8;i++)
        #pragma unroll
        for (int jj=0;jj<8;jj++)
          acc[i][jj] = fmaf(av[i], bv[jj], acc[i][jj]);
    }
    __syncthreads();
  }
  #pragma unroll
  for (int i=0;i<8;i++){
    float* op = out + (size_t)(m0+rbase+i)*1024 + cb + n0t;
    *(float4*)&op[cbase]    = make_float4(acc[i][0],acc[i][1],acc[i][2],acc[i][3]);
    *(float4*)&op[cbase+64] = make_float4(acc[i][4],acc[i][5],acc[i][6],acc[i][7]);
  }
}

// ================= recurrent kernel, PRE mode (x@W from ws), 1024 threads =================
__global__ __launch_bounds__(THREADS2)
void tman_kernel_pre(Params p)
{
  __shared__ float cl[ROWS][128], hl[ROWS][128];
  __shared__ float ca[ROWS][64],  ha[ROWS][64];
  __shared__ float cv[ROWS][64],  hv[ROWS][64];
  __shared__ float zz[ROWS][64];
  __shared__ float sl[ROWS][512];
  __shared__ float sa[ROWS][256];
  __shared__ float sv[ROWS][256];
  __shared__ float hidl[ROWS][128], hida[ROWS][128], hidv[ROWS][128];
  __shared__ float hidat0[ROWS][128], hidat1[ROWS][128];
  __shared__ float scl[ROWS][64], sca[ROWS][64], scv[ROWS][64];
  __shared__ float attlog[ROWS][4];
  __shared__ float bl[512], ba[256], bv[256];

  const int tid  = threadIdx.x;
  const int lane = tid & 63;
  const int wave = tid >> 6;
  const int n0   = blockIdx.x * ROWS;

  for (int i=tid;i<512;i+=THREADS2) bl[i]=p.bWl[i]+p.bUl[i]+p.bVl[i];
  for (int i=tid;i<256;i+=THREADS2){ ba[i]=p.bWa[i]+p.bUa[i]+p.bVa[i]; bv[i]=p.bWv[i]+p.bUv[i]+p.bVv[i]; }
  for (int i=tid;i<ROWS*128;i+=THREADS2){ (&cl[0][0])[i]=0.f; (&hl[0][0])[i]=0.f; }
  for (int i=tid;i<ROWS*64;i+=THREADS2){
    (&ca[0][0])[i]=0.f; (&ha[0][0])[i]=0.f;
    (&cv[0][0])[i]=0.f; (&hv[0][0])[i]=0.f;
    (&zz[0][0])[i]=0.f;
  }
  __syncthreads();

  for (int t=0;t<TSTEPS;++t){
    const float* wsr = p.ws + ((size_t)t*NB + n0)*1024;

    // ---- B: gate pre-activations s = (xW from ws) + hU + zV + b ----
    if (wave < 8){
      const int j = (wave<<6) + lane;
      float pre[ROWS];
      #pragma unroll
      for (int r=0;r<ROWS;r++) pre[r] = wsr[r*1024 + j];          // issue early
      float acc[ROWS];
      #pragma unroll
      for (int r=0;r<ROWS;r++) acc[r]=0.f;
      acc_mm_p<512,128,128>(p.Ul,&hl[0][0],acc,j);
      acc_mm_p<512, 64, 64>(p.Vl,&zz[0][0],acc,j);
      const float b = bl[j];
      #pragma unroll
      for (int r=0;r<ROWS;r++) sl[r][j]=acc[r]+pre[r]+b;
    } else if (wave < 12){
      const int j = ((wave-8)<<6) + lane;
      float pre[ROWS];
      #pragma unroll
      for (int r=0;r<ROWS;r++) pre[r] = wsr[r*1024 + 512 + j];
      float acc[ROWS];
      #pragma unroll
      for (int r=0;r<ROWS;r++) acc[r]=0.f;
      acc_mm_p<256,64,64>(p.Ua,&ha[0][0],acc,j);
      acc_mm_p<256,64,64>(p.Va,&zz[0][0],acc,j);
      const float b = ba[j];
      #pragma unroll
      for (int r=0;r<ROWS;r++) sa[r][j]=acc[r]+pre[r]+b;
    } else {
      const int j = ((wave-12)<<6) + lane;
      float pre[ROWS];
      #pragma unroll
      for (int r=0;r<ROWS;r++) pre[r] = wsr[r*1024 + 768 + j];
      float acc[ROWS];
      #pragma unroll
      for (int r=0;r<ROWS;r++) acc[r]=0.f;
      acc_mm_p<256,64,64>(p.Uv,&hv[0][0],acc,j);
      acc_mm_p<256,64,64>(p.Vv,&zz[0][0],acc,j);
      const float b = bv[j];
      #pragma unroll
      for (int r=0;r<ROWS;r++) sv[r][j]=acc[r]+pre[r]+b;
    }
    __syncthreads();

    // ---- C: gates -> new c,h ----
    {
      const int r=tid>>7, u=tid&127;
      float f =sigm(sl[r][u]);
      float ig=sigm(sl[r][128+u]);
      float o =sigm(sl[r][256+u]);
      float ch=tanhf(sl[r][384+u]);
      float c=f*cl[r][u]+ig*ch;
      cl[r][u]=c; hl[r][u]=tanhf(c)*o;
    }
    if (tid < ROWS*64){
      const int r=tid>>6, u=tid&63;
      { float f=sigm(sa[r][u]), ig=sigm(sa[r][64+u]), o=sigm(sa[r][128+u]), ch=tanhf(sa[r][192+u]);
        float c=f*ca[r][u]+ig*ch; ca[r][u]=c; ha[r][u]=tanhf(c)*o; }
      { float f=sigm(sv[r][u]), ig=sigm(sv[r][64+u]), o=sigm(sv[r][128+u]), ch=tanhf(sv[r][192+u]);
        float c=f*cv[r][u]+ig*ch; cv[r][u]=c; hv[r][u]=tanhf(c)*o; }
    }
    __syncthreads();

    // ---- D1: hidden layers (inputs = new cell states) ----
    if (wave<2){
      const int j=(wave<<6)+lane;
      float acc[ROWS]; const float b=p.nlb1[j];
      #pragma unroll
      for (int r=0;r<ROWS;r++) acc[r]=b;
      acc_mm_p<128,128,128>(p.nlW1,&cl[0][0],acc,j);
      #pragma unroll
      for (int r=0;r<ROWS;r++) hidl[r][j]=fmaxf(acc[r],0.f);
    } else if (wave<4){
      const int j=((wave-2)<<6)+lane;
      float acc[ROWS]; const float b=p.nab1[j];
      #pragma unroll
      for (int r=0;r<ROWS;r++) acc[r]=b;
      acc_mm_p<128,64,64>(p.naW1,&ca[0][0],acc,j);
      #pragma unroll
      for (int r=0;r<ROWS;r++) hida[r][j]=fmaxf(acc[r],0.f);
    } else if (wave<6){
      const int j=((wave-4)<<6)+lane;
      float acc[ROWS]; const float b=p.nvb1[j];
      #pragma unroll
      for (int r=0;r<ROWS;r++) acc[r]=b;
      acc_mm_p<128,64,64>(p.nvW1,&cv[0][0],acc,j);
      #pragma unroll
      for (int r=0;r<ROWS;r++) hidv[r][j]=fmaxf(acc[r],0.f);
    } else if (wave<8){
      const int j=((wave-6)<<6)+lane;
      float acc[ROWS]; const float b=p.attb1[j];
      #pragma unroll
      for (int r=0;r<ROWS;r++) acc[r]=b;
      acc_mm_p<128,128,128>(p.attW1,&cl[0][0],acc,j);
      #pragma unroll
      for (int r=0;r<ROWS;r++) hidat0[r][j]=acc[r];       // partial, no relu yet
    } else if (wave<10){
      const int j=((wave-8)<<6)+lane;
      float acc[ROWS];
      #pragma unroll
      for (int r=0;r<ROWS;r++) acc[r]=0.f;
      acc_mm_p<128,64,64>(p.attW1+128*128,&ca[0][0],acc,j);
      acc_mm_p<128,64,64>(p.attW1+192*128,&cv[0][0],acc,j);
      #pragma unroll
      for (int r=0;r<ROWS;r++) hidat1[r][j]=acc[r];       // partial
    }
    __syncthreads();

    // ---- D2: second layers ----
    if (wave==0){
      float acc[ROWS]; const float b=p.nlb2[lane];
      #pragma unroll
      for (int r=0;r<ROWS;r++) acc[r]=b;
      acc_mm_p<64,128,128>(p.nlW2,&hidl[0][0],acc,lane);
      #pragma unroll
      for (int r=0;r<ROWS;r++) scl[r][lane]=acc[r];
    } else if (wave==1){
      float acc[ROWS]; const float b=p.nab2[lane];
      #pragma unroll
      for (int r=0;r<ROWS;r++) acc[r]=b;
      acc_mm_p<64,128,128>(p.naW2,&hida[0][0],acc,lane);
      #pragma unroll
      for (int r=0;r<ROWS;r++) sca[r][lane]=acc[r];
    } else if (wave==2){
      float acc[ROWS]; const float b=p.nvb2[lane];
      #pragma unroll
      for (int r=0;r<ROWS;r++) acc[r]=b;
      acc_mm_p<64,128,128>(p.nvW2,&hidv[0][0],acc,lane);
      #pragma unroll
      for (int r=0;r<ROWS;r++) scv[r][lane]=acc[r];
    } else if (wave==3 && lane<ROWS*3){
      const int r=lane/3, m=lane-3*r;
      float a=p.attb2[m];
      for (int k=0;k<128;k++){
        float hvv = fmaxf(hidat0[r][k]+hidat1[r][k], 0.f);
        a=fmaf(hvv,p.attW2[k*3+m],a);
      }
      attlog[r][m]=a;
    }
    __syncthreads();

    // ---- D3: softmax over modalities + z ----
    if (tid < ROWS*64){
      const int r=tid>>6, u=tid&63;
      float a0=attlog[r][0], a1=attlog[r][1], a2=attlog[r][2];
      float m=fmaxf(a0,fmaxf(a1,a2));
      float e0=__expf(a0-m), e1=__expf(a1-m), e2=__expf(a2-m);
      float inv=1.f/(e0+e1+e2);
      zz[r][u]=(e0*scl[r][u]+e1*sca[r][u]+e2*scv[r][u])*inv;
    }
    __syncthreads();
  }

  // ---- final MLP ----
  if (wave<2){
    const int j=(wave<<6)+lane;
    float acc[ROWS]; const float b=p.outb1[j];
    #pragma unroll
    for (int r=0;r<ROWS;r++) acc[r]=b;
    acc_mm_p<128,128,128>(p.outW1,          &hl[0][0],acc,j);
    acc_mm_p<128, 64, 64>(p.outW1+128*128,  &ha[0][0],acc,j);
    acc_mm_p<128, 64, 64>(p.outW1+192*128,  &hv[0][0],acc,j);
    acc_mm_p<128, 64, 64>(p.outW1+256*128,  &zz[0][0],acc,j);
    #pragma unroll
    for (int r=0;r<ROWS;r++) hidl[r][j]=fmaxf(acc[r],0.f);
  }
  __syncthreads();
  if (tid<ROWS){
    float acc=p.outb2[0];
    for (int k=0;k<128;k++) acc=fmaf(hidl[tid][k],p.outW2[k],acc);
    p.out[n0+tid]=acc;
  }
}

// ================= fallback: original 512-thread kernel (proven) =================
__global__ __launch_bounds__(THREADS)
void tman_kernel(Params p)
{
  __shared__ float xsl[ROWS][300];
  __shared__ float xsa[ROWS][76];
  __shared__ float xsv[ROWS][36];
  __shared__ float cl[ROWS][128], hl[ROWS][128];
  __shared__ float ca[ROWS][64],  ha[ROWS][64];
  __shared__ float cv[ROWS][64],  hv[ROWS][64];
  __shared__ float zz[ROWS][64];
  __shared__ float sl[ROWS][512];
  __shared__ float sa[ROWS][256];
  __shared__ float sv[ROWS][256];
  __shared__ float hidl[ROWS][128], hida[ROWS][128], hidv[ROWS][128], hidat[ROWS][128];
  __shared__ float scl[ROWS][64], sca[ROWS][64], scv[ROWS][64];
  __shared__ float attlog[ROWS][4];
  __shared__ float bl[512], ba[256], bv[256];

  const int tid  = threadIdx.x;
  const int lane = tid & 63;
  const int wave = tid >> 6;
  const int n0   = blockIdx.x * ROWS;

  for (int i=tid;i<512;i+=THREADS) bl[i]=p.bWl[i]+p.bUl[i]+p.bVl[i];
  for (int i=tid;i<256;i+=THREADS){ ba[i]=p.bWa[i]+p.bUa[i]+p.bVa[i]; bv[i]=p.bWv[i]+p.bUv[i]+p.bVv[i]; }
  for (int i=tid;i<ROWS*128;i+=THREADS){ (&cl[0][0])[i]=0.f; (&hl[0][0])[i]=0.f; }
  for (int i=tid;i<ROWS*64;i+=THREADS){
    (&ca[0][0])[i]=0.f; (&ha[0][0])[i]=0.f;
    (&cv[0][0])[i]=0.f; (&hv[0][0])[i]=0.f;
    (&zz[0][0])[i]=0.f;
  }
  __syncthreads();

  for (int t=0;t<TSTEPS;++t){
    const float* xt = p.x + ((size_t)t*NB + n0)*DXF;
    for (int i=tid;i<ROWS*DXF;i+=THREADS){
      int r=i/DXF, d=i-r*DXF;
      float v=xt[(size_t)r*DXF+d];
      if (d<300) xsl[r][d]=v;
      else if (d<374) xsa[r][d-300]=v;
      else xsv[r][d-374]=v;
    }
    __syncthreads();

    {
      int j = wave*64 + lane;
      float acc[ROWS]; float b=bl[j];
      #pragma unroll
      for (int r=0;r<ROWS;r++) acc[r]=b;
      acc_mm<512,300,300>(p.Wl,&xsl[0][0],acc,j);
      acc_mm<512,128,128>(p.Ul,&hl[0][0],acc,j);
      acc_mm<512, 64, 64>(p.Vl,&zz[0][0],acc,j);
      #pragma unroll
      for (int r=0;r<ROWS;r++) sl[r][j]=acc[r];
    }
    {
      int item = 15-wave;
      if (item>=12){
        int j=(item-12)*64+lane;
        float acc[ROWS]; float b=bv[j];
        #pragma unroll
        for (int r=0;r<ROWS;r++) acc[r]=b;
        acc_mm<256,35,36>(p.Wv,&xsv[0][0],acc,j);
        acc_mm<256,64,64>(p.Uv,&hv[0][0],acc,j);
        acc_mm<256,64,64>(p.Vv,&zz[0][0],acc,j);
        #pragma unroll
        for (int r=0;r<ROWS;r++) sv[r][j]=acc[r];
      } else {
        int j=(item-8)*64+lane;
        float acc[ROWS]; float b=ba[j];
        #pragma unroll
        for (int r=0;r<ROWS;r++) acc[r]=b;
        acc_mm<256,74,76>(p.Wa,&xsa[0][0],acc,j);
        acc_mm<256,64,64>(p.Ua,&ha[0][0],acc,j);
        acc_mm<256,64,64>(p.Va,&zz[0][0],acc,j);
        #pragma unroll
        for (int r=0;r<ROWS;r++) sa[r][j]=acc[r];
      }
    }
    __syncthreads();

    for (int i=tid;i<ROWS*128;i+=THREADS){
      int r=i>>7, u=i&127;
      float f =sigm(sl[r][u]);
      float ig=sigm(sl[r][128+u]);
      float o =sigm(sl[r][256+u]);
      float ch=tanhf(sl[r][384+u]);
      float c=f*cl[r][u]+ig*ch;
      cl[r][u]=c; hl[r][u]=tanhf(c)*o;
    }
    for (int i=tid;i<ROWS*64;i+=THREADS){
      int r=i>>6, u=i&63;
      { float f=sigm(sa[r][u]), ig=sigm(sa[r][64+u]), o=sigm(sa[r][128+u]), ch=tanhf(sa[r][192+u]);
        float c=f*ca[r][u]+ig*ch; ca[r][u]=c; ha[r][u]=tanhf(c)*o; }
      { float f=sigm(sv[r][u]), ig=sigm(sv[r][64+u]), o=sigm(sv[r][128+u]), ch=tanhf(sv[r][192+u]);
        float c=f*cv[r][u]+ig*ch; cv[r][u]=c; hv[r][u]=tanhf(c)*o; }
    }
    __syncthreads();

    if (wave<2){
      int j=wave*64+lane;
      float acc[ROWS]; float b=p.nlb1[j];
      #pragma unroll
      for (int r=0;r<ROWS;r++) acc[r]=b;
      acc_mm<128,128,128>(p.nlW1,&cl[0][0],acc,j);
      #pragma unroll
      for (int r=0;r<ROWS;r++) hidl[r][j]=fmaxf(acc[r],0.f);
    } else if (wave<4){
      int j=(wave-2)*64+lane;
      float acc[ROWS]; float b=p.nab1[j];
      #pragma unroll
      for (int r=0;r<ROWS;r++) acc[r]=b;
      acc_mm<128,64,64>(p.naW1,&ca[0][0],acc,j);
      #pragma unroll
      for (int r=0;r<ROWS;r++) hida[r][j]=fmaxf(acc[r],0.f);
    } else if (wave<6){
      int j=(wave-4)*64+lane;
      float acc[ROWS]; float b=p.nvb1[j];
      #pragma unroll
      for (int r=0;r<ROWS;r++) acc[r]=b;
      acc_mm<128,64,64>(p.nvW1,&cv[0][0],acc,j);
      #pragma unroll
      for (int r=0;r<ROWS;r++) hidv[r][j]=fmaxf(acc[r],0.f);
    } else {
      int j=(wave-6)*64+lane;
      float acc[ROWS]; float b=p.attb1[j];
      #pragma unroll
      for (int r=0;r<ROWS;r++) acc[r]=b;
      acc_mm<128,128,128>(p.attW1,          &cl[0][0],acc,j);
      acc_mm<128, 64, 64>(p.attW1+128*128,  &ca[0][0],acc,j);
      acc_mm<128, 64, 64>(p.attW1+192*128,  &cv[0][0],acc,j);
      #pragma unroll
      for (int r=0;r<ROWS;r++) hidat[r][j]=fmaxf(acc[r],0.f);
    }
    __syncthreads();

    if (wave==0){
      float acc[ROWS]; float b=p.nlb2[lane];
      #pragma unroll
      for (int r=0;r<ROWS;r++) acc[r]=b;
      acc_mm<64,128,128>(p.nlW2,&hidl[0][0],acc,lane);
      #pragma unroll
      for (int r=0;r<ROWS;r++) scl[r][lane]=acc[r];
    } else if (wave==1){
      float acc[ROWS]; float b=p.nab2[lane];
      #pragma unroll
      for (int r=0;r<ROWS;r++) acc[r]=b;
      acc_mm<64,128,128>(p.naW2,&hida[0][0],acc,lane);
      #pragma unroll
      for (int r=0;r<ROWS;r++) sca[r][lane]=acc[r];
    } else if (wave==2){
      float acc[ROWS]; float b=p.nvb2[lane];
      #pragma unroll
      for (int r=0;r<ROWS;r++) acc[r]=b;
      acc_mm<64,128,128>(p.nvW2,&hidv[0][0],acc,lane);
      #pragma unroll
      for (int r=0;r<ROWS;r++) scv[r][lane]=acc[r];
    } else if (wave==3 && lane<ROWS*3){
      int r=lane/3, m=lane-3*r;
      float a=p.attb2[m];
      for (int k=0;k<128;k++) a=fmaf(hidat[r][k],p.attW2[k*3+m],a);
      attlog[r][m]=a;
    }
    __syncthreads();

    for (int i=tid;i<ROWS*64;i+=THREADS){
      int r=i>>6, u=i&63;
      float a0=attlog[r][0], a1=attlog[r][1], a2=attlog[r][2];
      float m=fmaxf(a0,fmaxf(a1,a2));
      float e0=__expf(a0-m), e1=__expf(a1-m), e2=__expf(a2-m);
      float inv=1.f/(e0+e1+e2);
      zz[r][u]=(e0*scl[r][u]+e1*sca[r][u]+e2*scv[r][u])*inv;
    }
    __syncthreads();
  }

  if (wave<2){
    int j=wave*64+lane;
    float acc[ROWS]; float b=p.outb1[j];
    #pragma unroll
    for (int r=0;r<ROWS;r++) acc[r]=b;
    acc_mm<128,128,128>(p.outW1,          &hl[0][0],acc,j);
    acc_mm<128, 64, 64>(p.outW1+128*128,  &ha[0][0],acc,j);
    acc_mm<128, 64, 64>(p.outW1+192*128,  &hv[0][0],acc,j);
    acc_mm<128, 64, 64>(p.outW1+256*128,  &zz[0][0],acc,j);
    #pragma unroll
    for (int r=0;r<ROWS;r++) hidl[r][j]=fmaxf(acc[r],0.f);
  }
  __syncthreads();
  if (tid<ROWS){
    float acc=p.outb2[0];
    for (int k=0;k<128;k++) acc=fmaf(hidl[tid][k],p.outW2[k],acc);
    p.out[n0+tid]=acc;
  }
}

extern "C" void kernel_launch(void* const* d_in, const int* in_sizes, int n_in,
                              void* d_out, int out_size, void* d_ws, size_t ws_size,
                              hipStream_t stream) {
  const float* const* f = (const float* const*)d_in;
  Params P;
  P.x  =f[0];
  P.Wl =f[1];  P.bWl=f[2];  P.Ul =f[3];  P.bUl=f[4];  P.Vl =f[5];  P.bVl=f[6];
  P.Wa =f[7];  P.bWa=f[8];  P.Ua =f[9];  P.bUa=f[10]; P.Va =f[11]; P.bVa=f[12];
  P.Wv =f[13]; P.bWv=f[14]; P.Uv =f[15]; P.bUv=f[16]; P.Vv =f[17]; P.bVv=f[18];
  P.nlW1=f[19]; P.nlb1=f[20]; P.nlW2=f[21]; P.nlb2=f[22];
  P.naW1=f[23]; P.nab1=f[24]; P.naW2=f[25]; P.nab2=f[26];
  P.nvW1=f[27]; P.nvb1=f[28]; P.nvW2=f[29]; P.nvb2=f[30];
  P.attW1=f[31]; P.attb1=f[32]; P.attW2=f[33]; P.attb2=f[34];
  P.outW1=f[35]; P.outb1=f[36]; P.outW2=f[37]; P.outb2=f[38];
  P.out=(float*)d_out;
  P.ws =(const float*)d_ws;

  const size_t XW_BYTES = (size_t)TSTEPS * NB * 1024 * sizeof(float);  // 1.07 GB
  if (ws_size >= XW_BYTES) {
    float* xw = (float*)d_ws;
    // XW precompute: three block GEMMs into [T*N][1024]
    hipLaunchKernelGGL(xw_gemm, dim3(TSTEPS*NB/128, 4), dim3(256), 0, stream,
                       P.x, P.Wl, xw, 300, 512,   0,   0);
    hipLaunchKernelGGL(xw_gemm, dim3(TSTEPS*NB/128, 2), dim3(256), 0, stream,
                       P.x, P.Wa, xw,  74, 256, 512, 300);
    hipLaunchKernelGGL(xw_gemm, dim3(TSTEPS*NB/128, 2), dim3(256), 0, stream,
                       P.x, P.Wv, xw,  35, 256, 768, 374);
    hipLaunchKernelGGL(tman_kernel_pre, dim3(NB/ROWS), dim3(THREADS2), 0, stream, P);
  } else {
    hipLaunchKernelGGL(tman_kernel, dim3(NB/ROWS), dim3(THREADS), 0, stream, P);
  }
}

// Round 3
// 6836.608 us; speedup vs baseline: 2.0223x; 2.0223x over previous
//
#include <hip/hip_runtime.h>
#include <cmath>

#define ROWS 8
#define THREADS 512
#define THREADS2 1024
#define NB 2048
#define TSTEPS 128
#define DXF 409

struct Params {
  const float *x;
  const float *Wl,*bWl,*Ul,*bUl,*Vl,*bVl;
  const float *Wa,*bWa,*Ua,*bUa,*Va,*bVa;
  const float *Wv,*bWv,*Uv,*bUv,*Vv,*bVv;
  const float *nlW1,*nlb1,*nlW2,*nlb2;
  const float *naW1,*nab1,*naW2,*nab2;
  const float *nvW1,*nvb1,*nvW2,*nvb2;
  const float *attW1,*attb1,*attW2,*attb2;
  const float *outW1,*outb1,*outW2,*outb2;
  const float *ws;   // precomputed XW [T*N][1024] (L:0-511, A:512-767, V:768-1023)
  float *out;
};

__device__ __forceinline__ float sigm(float x){ return 1.0f/(1.0f+__expf(-x)); }

// ---------------- original acc_mm (tail-capable, used by fallback) ----------------
template<int COLS,int KDIM,int INSTRIDE>
__device__ __forceinline__ void acc_mm(const float* __restrict__ W,
                                       const float* __restrict__ in,
                                       float acc[ROWS], int j)
{
  constexpr int K4 = KDIM/4;
  #pragma unroll 2
  for (int k4=0;k4<K4;k4++){
    const int k=4*k4;
    float w0=W[(k+0)*COLS+j];
    float w1=W[(k+1)*COLS+j];
    float w2=W[(k+2)*COLS+j];
    float w3=W[(k+3)*COLS+j];
    #pragma unroll
    for (int r=0;r<ROWS;r++){
      const float4 v = *(const float4*)(in + r*INSTRIDE + k);
      acc[r]=fmaf(v.w,w3,fmaf(v.z,w2,fmaf(v.y,w1,fmaf(v.x,w0,acc[r]))));
    }
  }
  if constexpr ((KDIM & 3) != 0) {
    #pragma unroll
    for (int k=K4*4;k<KDIM;k++){
      float wv=W[k*COLS+j];
      #pragma unroll
      for (int r=0;r<ROWS;r++) acc[r]=fmaf(in[r*INSTRIDE+k],wv,acc[r]);
    }
  }
}

// ---------------- prefetching acc_mm, branch-free (KDIM % 4 == 0) ----------------
template<int COLS,int KDIM,int INSTRIDE>
__device__ __forceinline__ void acc_mm_p(const float* __restrict__ W,
                                         const float* __restrict__ in,
                                         float acc[ROWS], int j)
{
  static_assert((KDIM & 3) == 0, "KDIM must be multiple of 4");
  constexpr int K4 = KDIM/4;
  const float* wp = W + j;
  float w0=wp[0], w1=wp[COLS], w2=wp[2*COLS], w3=wp[3*COLS];
  #pragma unroll 2
  for (int k4=0;k4<K4-1;k4++){
    const float* wn = wp + 4*COLS;
    float n0=wn[0], n1=wn[COLS], n2=wn[2*COLS], n3=wn[3*COLS];
    const float* ip = in + 4*k4;
    #pragma unroll
    for (int r=0;r<ROWS;r++){
      const float4 v = *(const float4*)(ip + r*INSTRIDE);
      acc[r]=fmaf(v.w,w3,fmaf(v.z,w2,fmaf(v.y,w1,fmaf(v.x,w0,acc[r]))));
    }
    w0=n0;w1=n1;w2=n2;w3=n3;
    wp = wn;
  }
  { // epilogue k4 = K4-1
    const float* ip = in + 4*(K4-1);
    #pragma unroll
    for (int r=0;r<ROWS;r++){
      const float4 v = *(const float4*)(ip + r*INSTRIDE);
      acc[r]=fmaf(v.w,w3,fmaf(v.z,w2,fmaf(v.y,w1,fmaf(v.x,w0,acc[r]))));
    }
  }
}

// ================= XW GEMM: out[m][cb+n] = sum_k x[m][xoff+k] * W[k][n] =================
// BM=128, BN=128, BK=32, 256 threads, 8x8 microtile.
__global__ __launch_bounds__(256)
void xw_gemm(const float* __restrict__ x, const float* __restrict__ W,
             float* __restrict__ out, int K, int WN, int cb, int xoff)
{
  __shared__ float As[32][128];
  __shared__ float Bs[32][128];
  const int t = threadIdx.x;
  const int m0 = blockIdx.x * 128;
  const int n0t = blockIdx.y * 128;
  const int arow = t & 127, akh = (t >> 7) * 16;
  const int bk = t >> 3,  bj = (t & 7) * 16;
  const int rbase = (t >> 4) * 8, cbase = (t & 15) * 4;

  float acc[8][8];
  #pragma unroll
  for (int i=0;i<8;i++)
    #pragma unroll
    for (int jj=0;jj<8;jj++) acc[i][jj]=0.f;

  const int nch = (K + 31) >> 5;
  for (int ch=0; ch<nch; ++ch){
    const int kc = ch*32;
    // stage A (transposed): As[k][row]
    const float* xp = x + (size_t)(m0+arow)*DXF + xoff + kc + akh;
    #pragma unroll
    for (int e=0;e<16;e++){
      int k = akh + e;
      As[k][arow] = (kc + k < K) ? xp[e] : 0.f;
    }
    // stage B: Bs[k][j]
    if (kc + bk < K){
      const float* wp = W + (size_t)(kc+bk)*WN + n0t + bj;
      #pragma unroll
      for (int e=0;e<16;e+=4)
        *(float4*)&Bs[bk][bj+e] = *(const float4*)&wp[e];
    } else {
      #pragma unroll
      for (int e=0;e<16;e++) Bs[bk][bj+e] = 0.f;
    }
    __syncthreads();
    #pragma unroll 8
    for (int k=0;k<32;k++){
      float4 a0 = *(const float4*)&As[k][rbase];
      float4 a1 = *(const float4*)&As[k][rbase+4];
      float4 b0 = *(const float4*)&Bs[k][cbase];
      float4 b1 = *(const float4*)&Bs[k][cbase+64];
      float av[8] = {a0.x,a0.y,a0.z,a0.w,a1.x,a1.y,a1.z,a1.w};
      float bv[8] = {b0.x,b0.y,b0.z,b0.w,b1.x,b1.y,b1.z,b1.w};
      #pragma unroll
      for (int i=0;i<8;i++)
        #pragma unroll
        for (int jj=0;jj<8;jj++)
          acc[i][jj] = fmaf(av[i], bv[jj], acc[i][jj]);
    }
    __syncthreads();
  }
  #pragma unroll
  for (int i=0;i<8;i++){
    float* op = out + (size_t)(m0+rbase+i)*1024 + cb + n0t;
    *(float4*)&op[cbase]    = make_float4(acc[i][0],acc[i][1],acc[i][2],acc[i][3]);
    *(float4*)&op[cbase+64] = make_float4(acc[i][4],acc[i][5],acc[i][6],acc[i][7]);
  }
}

// ================= recurrent kernel, PRE mode (x@W from ws), 1024 threads =================
// __launch_bounds__(1024, 4): 4 waves/EU = one block/CU -> VGPR cap 128 (round-2's
// implicit 64-VGPR cap caused 5.2 GB of scratch spills; this is the fix).
__global__ __launch_bounds__(THREADS2, 4)
void tman_kernel_pre(Params p)
{
  __shared__ float cl[ROWS][128], hl[ROWS][128];
  __shared__ float ca[ROWS][64],  ha[ROWS][64];
  __shared__ float cv[ROWS][64],  hv[ROWS][64];
  __shared__ float zz[ROWS][64];
  __shared__ float sl[ROWS][512];
  __shared__ float sa[ROWS][256];
  __shared__ float sv[ROWS][256];
  __shared__ float hidl[ROWS][128], hida[ROWS][128], hidv[ROWS][128];
  __shared__ float hidat0[ROWS][128], hidat1[ROWS][128];
  __shared__ float scl[ROWS][64], sca[ROWS][64], scv[ROWS][64];
  __shared__ float attlog[ROWS][4];
  __shared__ float bl[512], ba[256], bv[256];

  const int tid  = threadIdx.x;
  const int lane = tid & 63;
  const int wave = tid >> 6;
  const int n0   = blockIdx.x * ROWS;

  for (int i=tid;i<512;i+=THREADS2) bl[i]=p.bWl[i]+p.bUl[i]+p.bVl[i];
  for (int i=tid;i<256;i+=THREADS2){ ba[i]=p.bWa[i]+p.bUa[i]+p.bVa[i]; bv[i]=p.bWv[i]+p.bUv[i]+p.bVv[i]; }
  for (int i=tid;i<ROWS*128;i+=THREADS2){ (&cl[0][0])[i]=0.f; (&hl[0][0])[i]=0.f; }
  for (int i=tid;i<ROWS*64;i+=THREADS2){
    (&ca[0][0])[i]=0.f; (&ha[0][0])[i]=0.f;
    (&cv[0][0])[i]=0.f; (&hv[0][0])[i]=0.f;
    (&zz[0][0])[i]=0.f;
  }
  __syncthreads();

  for (int t=0;t<TSTEPS;++t){
    const float* wsr = p.ws + ((size_t)t*NB + n0)*1024;

    // ---- B: gate pre-activations s = (xW from ws) + hU + zV + b ----
    if (wave < 8){
      const int j = (wave<<6) + lane;
      float acc[ROWS];
      #pragma unroll
      for (int r=0;r<ROWS;r++) acc[r] = wsr[r*1024 + j];   // acc init = xW (issued early)
      acc_mm_p<512,128,128>(p.Ul,&hl[0][0],acc,j);
      acc_mm_p<512, 64, 64>(p.Vl,&zz[0][0],acc,j);
      const float b = bl[j];
      #pragma unroll
      for (int r=0;r<ROWS;r++) sl[r][j]=acc[r]+b;
    } else if (wave < 12){
      const int j = ((wave-8)<<6) + lane;
      float acc[ROWS];
      #pragma unroll
      for (int r=0;r<ROWS;r++) acc[r] = wsr[r*1024 + 512 + j];
      acc_mm_p<256,64,64>(p.Ua,&ha[0][0],acc,j);
      acc_mm_p<256,64,64>(p.Va,&zz[0][0],acc,j);
      const float b = ba[j];
      #pragma unroll
      for (int r=0;r<ROWS;r++) sa[r][j]=acc[r]+b;
    } else {
      const int j = ((wave-12)<<6) + lane;
      float acc[ROWS];
      #pragma unroll
      for (int r=0;r<ROWS;r++) acc[r] = wsr[r*1024 + 768 + j];
      acc_mm_p<256,64,64>(p.Uv,&hv[0][0],acc,j);
      acc_mm_p<256,64,64>(p.Vv,&zz[0][0],acc,j);
      const float b = bv[j];
      #pragma unroll
      for (int r=0;r<ROWS;r++) sv[r][j]=acc[r]+b;
    }
    __syncthreads();

    // ---- C: gates -> new c,h ----
    {
      const int r=tid>>7, u=tid&127;
      float f =sigm(sl[r][u]);
      float ig=sigm(sl[r][128+u]);
      float o =sigm(sl[r][256+u]);
      float ch=tanhf(sl[r][384+u]);
      float c=f*cl[r][u]+ig*ch;
      cl[r][u]=c; hl[r][u]=tanhf(c)*o;
    }
    if (tid < ROWS*64){
      const int r=tid>>6, u=tid&63;
      { float f=sigm(sa[r][u]), ig=sigm(sa[r][64+u]), o=sigm(sa[r][128+u]), ch=tanhf(sa[r][192+u]);
        float c=f*ca[r][u]+ig*ch; ca[r][u]=c; ha[r][u]=tanhf(c)*o; }
      { float f=sigm(sv[r][u]), ig=sigm(sv[r][64+u]), o=sigm(sv[r][128+u]), ch=tanhf(sv[r][192+u]);
        float c=f*cv[r][u]+ig*ch; cv[r][u]=c; hv[r][u]=tanhf(c)*o; }
    }
    __syncthreads();

    // ---- D1: hidden layers (inputs = new cell states) ----
    if (wave<2){
      const int j=(wave<<6)+lane;
      float acc[ROWS]; const float b=p.nlb1[j];
      #pragma unroll
      for (int r=0;r<ROWS;r++) acc[r]=b;
      acc_mm_p<128,128,128>(p.nlW1,&cl[0][0],acc,j);
      #pragma unroll
      for (int r=0;r<ROWS;r++) hidl[r][j]=fmaxf(acc[r],0.f);
    } else if (wave<4){
      const int j=((wave-2)<<6)+lane;
      float acc[ROWS]; const float b=p.nab1[j];
      #pragma unroll
      for (int r=0;r<ROWS;r++) acc[r]=b;
      acc_mm_p<128,64,64>(p.naW1,&ca[0][0],acc,j);
      #pragma unroll
      for (int r=0;r<ROWS;r++) hida[r][j]=fmaxf(acc[r],0.f);
    } else if (wave<6){
      const int j=((wave-4)<<6)+lane;
      float acc[ROWS]; const float b=p.nvb1[j];
      #pragma unroll
      for (int r=0;r<ROWS;r++) acc[r]=b;
      acc_mm_p<128,64,64>(p.nvW1,&cv[0][0],acc,j);
      #pragma unroll
      for (int r=0;r<ROWS;r++) hidv[r][j]=fmaxf(acc[r],0.f);
    } else if (wave<8){
      const int j=((wave-6)<<6)+lane;
      float acc[ROWS]; const float b=p.attb1[j];
      #pragma unroll
      for (int r=0;r<ROWS;r++) acc[r]=b;
      acc_mm_p<128,128,128>(p.attW1,&cl[0][0],acc,j);
      #pragma unroll
      for (int r=0;r<ROWS;r++) hidat0[r][j]=acc[r];       // partial, no relu yet
    } else if (wave<10){
      const int j=((wave-8)<<6)+lane;
      float acc[ROWS];
      #pragma unroll
      for (int r=0;r<ROWS;r++) acc[r]=0.f;
      acc_mm_p<128,64,64>(p.attW1+128*128,&ca[0][0],acc,j);
      acc_mm_p<128,64,64>(p.attW1+192*128,&cv[0][0],acc,j);
      #pragma unroll
      for (int r=0;r<ROWS;r++) hidat1[r][j]=acc[r];       // partial
    }
    __syncthreads();

    // ---- D2: second layers ----
    if (wave==0){
      float acc[ROWS]; const float b=p.nlb2[lane];
      #pragma unroll
      for (int r=0;r<ROWS;r++) acc[r]=b;
      acc_mm_p<64,128,128>(p.nlW2,&hidl[0][0],acc,lane);
      #pragma unroll
      for (int r=0;r<ROWS;r++) scl[r][lane]=acc[r];
    } else if (wave==1){
      float acc[ROWS]; const float b=p.nab2[lane];
      #pragma unroll
      for (int r=0;r<ROWS;r++) acc[r]=b;
      acc_mm_p<64,128,128>(p.naW2,&hida[0][0],acc,lane);
      #pragma unroll
      for (int r=0;r<ROWS;r++) sca[r][lane]=acc[r];
    } else if (wave==2){
      float acc[ROWS]; const float b=p.nvb2[lane];
      #pragma unroll
      for (int r=0;r<ROWS;r++) acc[r]=b;
      acc_mm_p<64,128,128>(p.nvW2,&hidv[0][0],acc,lane);
      #pragma unroll
      for (int r=0;r<ROWS;r++) scv[r][lane]=acc[r];
    } else if (wave==3 && lane<ROWS*3){
      const int r=lane/3, m=lane-3*r;
      float a=p.attb2[m];
      for (int k=0;k<128;k++){
        float hvv = fmaxf(hidat0[r][k]+hidat1[r][k], 0.f);
        a=fmaf(hvv,p.attW2[k*3+m],a);
      }
      attlog[r][m]=a;
    }
    __syncthreads();

    // ---- D3: softmax over modalities + z ----
    if (tid < ROWS*64){
      const int r=tid>>6, u=tid&63;
      float a0=attlog[r][0], a1=attlog[r][1], a2=attlog[r][2];
      float m=fmaxf(a0,fmaxf(a1,a2));
      float e0=__expf(a0-m), e1=__expf(a1-m), e2=__expf(a2-m);
      float inv=1.f/(e0+e1+e2);
      zz[r][u]=(e0*scl[r][u]+e1*sca[r][u]+e2*scv[r][u])*inv;
    }
    __syncthreads();
  }

  // ---- final MLP ----
  if (wave<2){
    const int j=(wave<<6)+lane;
    float acc[ROWS]; const float b=p.outb1[j];
    #pragma unroll
    for (int r=0;r<ROWS;r++) acc[r]=b;
    acc_mm_p<128,128,128>(p.outW1,          &hl[0][0],acc,j);
    acc_mm_p<128, 64, 64>(p.outW1+128*128,  &ha[0][0],acc,j);
    acc_mm_p<128, 64, 64>(p.outW1+192*128,  &hv[0][0],acc,j);
    acc_mm_p<128, 64, 64>(p.outW1+256*128,  &zz[0][0],acc,j);
    #pragma unroll
    for (int r=0;r<ROWS;r++) hidl[r][j]=fmaxf(acc[r],0.f);
  }
  __syncthreads();
  if (tid<ROWS){
    float acc=p.outb2[0];
    for (int k=0;k<128;k++) acc=fmaf(hidl[tid][k],p.outW2[k],acc);
    p.out[n0+tid]=acc;
  }
}

// ================= fallback: original 512-thread kernel (proven) =================
__global__ __launch_bounds__(THREADS)
void tman_kernel(Params p)
{
  __shared__ float xsl[ROWS][300];
  __shared__ float xsa[ROWS][76];
  __shared__ float xsv[ROWS][36];
  __shared__ float cl[ROWS][128], hl[ROWS][128];
  __shared__ float ca[ROWS][64],  ha[ROWS][64];
  __shared__ float cv[ROWS][64],  hv[ROWS][64];
  __shared__ float zz[ROWS][64];
  __shared__ float sl[ROWS][512];
  __shared__ float sa[ROWS][256];
  __shared__ float sv[ROWS][256];
  __shared__ float hidl[ROWS][128], hida[ROWS][128], hidv[ROWS][128], hidat[ROWS][128];
  __shared__ float scl[ROWS][64], sca[ROWS][64], scv[ROWS][64];
  __shared__ float attlog[ROWS][4];
  __shared__ float bl[512], ba[256], bv[256];

  const int tid  = threadIdx.x;
  const int lane = tid & 63;
  const int wave = tid >> 6;
  const int n0   = blockIdx.x * ROWS;

  for (int i=tid;i<512;i+=THREADS) bl[i]=p.bWl[i]+p.bUl[i]+p.bVl[i];
  for (int i=tid;i<256;i+=THREADS){ ba[i]=p.bWa[i]+p.bUa[i]+p.bVa[i]; bv[i]=p.bWv[i]+p.bUv[i]+p.bVv[i]; }
  for (int i=tid;i<ROWS*128;i+=THREADS){ (&cl[0][0])[i]=0.f; (&hl[0][0])[i]=0.f; }
  for (int i=tid;i<ROWS*64;i+=THREADS){
    (&ca[0][0])[i]=0.f; (&ha[0][0])[i]=0.f;
    (&cv[0][0])[i]=0.f; (&hv[0][0])[i]=0.f;
    (&zz[0][0])[i]=0.f;
  }
  __syncthreads();

  for (int t=0;t<TSTEPS;++t){
    const float* xt = p.x + ((size_t)t*NB + n0)*DXF;
    for (int i=tid;i<ROWS*DXF;i+=THREADS){
      int r=i/DXF, d=i-r*DXF;
      float v=xt[(size_t)r*DXF+d];
      if (d<300) xsl[r][d]=v;
      else if (d<374) xsa[r][d-300]=v;
      else xsv[r][d-374]=v;
    }
    __syncthreads();

    {
      int j = wave*64 + lane;
      float acc[ROWS]; float b=bl[j];
      #pragma unroll
      for (int r=0;r<ROWS;r++) acc[r]=b;
      acc_mm<512,300,300>(p.Wl,&xsl[0][0],acc,j);
      acc_mm<512,128,128>(p.Ul,&hl[0][0],acc,j);
      acc_mm<512, 64, 64>(p.Vl,&zz[0][0],acc,j);
      #pragma unroll
      for (int r=0;r<ROWS;r++) sl[r][j]=acc[r];
    }
    {
      int item = 15-wave;
      if (item>=12){
        int j=(item-12)*64+lane;
        float acc[ROWS]; float b=bv[j];
        #pragma unroll
        for (int r=0;r<ROWS;r++) acc[r]=b;
        acc_mm<256,35,36>(p.Wv,&xsv[0][0],acc,j);
        acc_mm<256,64,64>(p.Uv,&hv[0][0],acc,j);
        acc_mm<256,64,64>(p.Vv,&zz[0][0],acc,j);
        #pragma unroll
        for (int r=0;r<ROWS;r++) sv[r][j]=acc[r];
      } else {
        int j=(item-8)*64+lane;
        float acc[ROWS]; float b=ba[j];
        #pragma unroll
        for (int r=0;r<ROWS;r++) acc[r]=b;
        acc_mm<256,74,76>(p.Wa,&xsa[0][0],acc,j);
        acc_mm<256,64,64>(p.Ua,&ha[0][0],acc,j);
        acc_mm<256,64,64>(p.Va,&zz[0][0],acc,j);
        #pragma unroll
        for (int r=0;r<ROWS;r++) sa[r][j]=acc[r];
      }
    }
    __syncthreads();

    for (int i=tid;i<ROWS*128;i+=THREADS){
      int r=i>>7, u=i&127;
      float f =sigm(sl[r][u]);
      float ig=sigm(sl[r][128+u]);
      float o =sigm(sl[r][256+u]);
      float ch=tanhf(sl[r][384+u]);
      float c=f*cl[r][u]+ig*ch;
      cl[r][u]=c; hl[r][u]=tanhf(c)*o;
    }
    for (int i=tid;i<ROWS*64;i+=THREADS){
      int r=i>>6, u=i&63;
      { float f=sigm(sa[r][u]), ig=sigm(sa[r][64+u]), o=sigm(sa[r][128+u]), ch=tanhf(sa[r][192+u]);
        float c=f*ca[r][u]+ig*ch; ca[r][u]=c; ha[r][u]=tanhf(c)*o; }
      { float f=sigm(sv[r][u]), ig=sigm(sv[r][64+u]), o=sigm(sv[r][128+u]), ch=tanhf(sv[r][192+u]);
        float c=f*cv[r][u]+ig*ch; cv[r][u]=c; hv[r][u]=tanhf(c)*o; }
    }
    __syncthreads();

    if (wave<2){
      int j=wave*64+lane;
      float acc[ROWS]; float b=p.nlb1[j];
      #pragma unroll
      for (int r=0;r<ROWS;r++) acc[r]=b;
      acc_mm<128,128,128>(p.nlW1,&cl[0][0],acc,j);
      #pragma unroll
      for (int r=0;r<ROWS;r++) hidl[r][j]=fmaxf(acc[r],0.f);
    } else if (wave<4){
      int j=(wave-2)*64+lane;
      float acc[ROWS]; float b=p.nab1[j];
      #pragma unroll
      for (int r=0;r<ROWS;r++) acc[r]=b;
      acc_mm<128,64,64>(p.naW1,&ca[0][0],acc,j);
      #pragma unroll
      for (int r=0;r<ROWS;r++) hida[r][j]=fmaxf(acc[r],0.f);
    } else if (wave<6){
      int j=(wave-4)*64+lane;
      float acc[ROWS]; float b=p.nvb1[j];
      #pragma unroll
      for (int r=0;r<ROWS;r++) acc[r]=b;
      acc_mm<128,64,64>(p.nvW1,&cv[0][0],acc,j);
      #pragma unroll
      for (int r=0;r<ROWS;r++) hidv[r][j]=fmaxf(acc[r],0.f);
    } else {
      int j=(wave-6)*64+lane;
      float acc[ROWS]; float b=p.attb1[j];
      #pragma unroll
      for (int r=0;r<ROWS;r++) acc[r]=b;
      acc_mm<128,128,128>(p.attW1,          &cl[0][0],acc,j);
      acc_mm<128, 64, 64>(p.attW1+128*128,  &ca[0][0],acc,j);
      acc_mm<128, 64, 64>(p.attW1+192*128,  &cv[0][0],acc,j);
      #pragma unroll
      for (int r=0;r<ROWS;r++) hidat[r][j]=fmaxf(acc[r],0.f);
    }
    __syncthreads();

    if (wave==0){
      float acc[ROWS]; float b=p.nlb2[lane];
      #pragma unroll
      for (int r=0;r<ROWS;r++) acc[r]=b;
      acc_mm<64,128,128>(p.nlW2,&hidl[0][0],acc,lane);
      #pragma unroll
      for (int r=0;r<ROWS;r++) scl[r][lane]=acc[r];
    } else if (wave==1){
      float acc[ROWS]; float b=p.nab2[lane];
      #pragma unroll
      for (int r=0;r<ROWS;r++) acc[r]=b;
      acc_mm<64,128,128>(p.naW2,&hida[0][0],acc,lane);
      #pragma unroll
      for (int r=0;r<ROWS;r++) sca[r][lane]=acc[r];
    } else if (wave==2){
      float acc[ROWS]; float b=p.nvb2[lane];
      #pragma unroll
      for (int r=0;r<ROWS;r++) acc[r]=b;
      acc_mm<64,128,128>(p.nvW2,&hidv[0][0],acc,lane);
      #pragma unroll
      for (int r=0;r<ROWS;r++) scv[r][lane]=acc[r];
    } else if (wave==3 && lane<ROWS*3){
      int r=lane/3, m=lane-3*r;
      float a=p.attb2[m];
      for (int k=0;k<128;k++) a=fmaf(hidat[r][k],p.attW2[k*3+m],a);
      attlog[r][m]=a;
    }
    __syncthreads();

    for (int i=tid;i<ROWS*64;i+=THREADS){
      int r=i>>6, u=i&63;
      float a0=attlog[r][0], a1=attlog[r][1], a2=attlog[r][2];
      float m=fmaxf(a0,fmaxf(a1,a2));
      float e0=__expf(a0-m), e1=__expf(a1-m), e2=__expf(a2-m);
      float inv=1.f/(e0+e1+e2);
      zz[r][u]=(e0*scl[r][u]+e1*sca[r][u]+e2*scv[r][u])*inv;
    }
    __syncthreads();
  }

  if (wave<2){
    int j=wave*64+lane;
    float acc[ROWS]; float b=p.outb1[j];
    #pragma unroll
    for (int r=0;r<ROWS;r++) acc[r]=b;
    acc_mm<128,128,128>(p.outW1,          &hl[0][0],acc,j);
    acc_mm<128, 64, 64>(p.outW1+128*128,  &ha[0][0],acc,j);
    acc_mm<128, 64, 64>(p.outW1+192*128,  &hv[0][0],acc,j);
    acc_mm<128, 64, 64>(p.outW1+256*128,  &zz[0][0],acc,j);
    #pragma unroll
    for (int r=0;r<ROWS;r++) hidl[r][j]=fmaxf(acc[r],0.f);
  }
  __syncthreads();
  if (tid<ROWS){
    float acc=p.outb2[0];
    for (int k=0;k<128;k++) acc=fmaf(hidl[tid][k],p.outW2[k],acc);
    p.out[n0+tid]=acc;
  }
}

extern "C" void kernel_launch(void* const* d_in, const int* in_sizes, int n_in,
                              void* d_out, int out_size, void* d_ws, size_t ws_size,
                              hipStream_t stream) {
  const float* const* f = (const float* const*)d_in;
  Params P;
  P.x  =f[0];
  P.Wl =f[1];  P.bWl=f[2];  P.Ul =f[3];  P.bUl=f[4];  P.Vl =f[5];  P.bVl=f[6];
  P.Wa =f[7];  P.bWa=f[8];  P.Ua =f[9];  P.bUa=f[10]; P.Va =f[11]; P.bVa=f[12];
  P.Wv =f[13]; P.bWv=f[14]; P.Uv =f[15]; P.bUv=f[16]; P.Vv =f[17]; P.bVv=f[18];
  P.nlW1=f[19]; P.nlb1=f[20]; P.nlW2=f[21]; P.nlb2=f[22];
  P.naW1=f[23]; P.nab1=f[24]; P.naW2=f[25]; P.nab2=f[26];
  P.nvW1=f[27]; P.nvb1=f[28]; P.nvW2=f[29]; P.nvb2=f[30];
  P.attW1=f[31]; P.attb1=f[32]; P.attW2=f[33]; P.attb2=f[34];
  P.outW1=f[35]; P.outb1=f[36]; P.outW2=f[37]; P.outb2=f[38];
  P.out=(float*)d_out;
  P.ws =(const float*)d_ws;

  const size_t XW_BYTES = (size_t)TSTEPS * NB * 1024 * sizeof(float);  // 1.07 GB
  if (ws_size >= XW_BYTES) {
    float* xw = (float*)d_ws;
    // XW precompute: three block GEMMs into [T*N][1024]
    hipLaunchKernelGGL(xw_gemm, dim3(TSTEPS*NB/128, 4), dim3(256), 0, stream,
                       P.x, P.Wl, xw, 300, 512,   0,   0);
    hipLaunchKernelGGL(xw_gemm, dim3(TSTEPS*NB/128, 2), dim3(256), 0, stream,
                       P.x, P.Wa, xw,  74, 256, 512, 300);
    hipLaunchKernelGGL(xw_gemm, dim3(TSTEPS*NB/128, 2), dim3(256), 0, stream,
                       P.x, P.Wv, xw,  35, 256, 768, 374);
    hipLaunchKernelGGL(tman_kernel_pre, dim3(NB/ROWS), dim3(THREADS2), 0, stream, P);
  } else {
    hipLaunchKernelGGL(tman_kernel, dim3(NB/ROWS), dim3(THREADS), 0, stream, P);
  }
}

// Round 4
// 6252.411 us; speedup vs baseline: 2.2112x; 1.0934x over previous
//
#include <hip/hip_runtime.h>
#include <cmath>

#define ROWS 8          // fallback kernel rows
#define R2 4            // pre-mode rows per block
#define THREADS 512
#define NB 2048
#define TSTEPS 128
#define DXF 409

struct Params {
  const float *x;
  const float *Wl,*bWl,*Ul,*bUl,*Vl,*bVl;
  const float *Wa,*bWa,*Ua,*bUa,*Va,*bVa;
  const float *Wv,*bWv,*Uv,*bUv,*Vv,*bVv;
  const float *nlW1,*nlb1,*nlW2,*nlb2;
  const float *naW1,*nab1,*naW2,*nab2;
  const float *nvW1,*nvb1,*nvW2,*nvb2;
  const float *attW1,*attb1,*attW2,*attb2;
  const float *outW1,*outb1,*outW2,*outb2;
  const float *ws;   // precomputed XW [T*N][1024] (L:0-511, A:512-767, V:768-1023)
  float *out;
};

__device__ __forceinline__ float sigm(float x){ return 1.0f/(1.0f+__expf(-x)); }

// ---------------- generic acc_mm (tail-capable), R rows ----------------
template<int R,int COLS,int KDIM,int INSTRIDE>
__device__ __forceinline__ void acc_mm(const float* __restrict__ W,
                                       const float* __restrict__ in,
                                       float acc[R], int j)
{
  constexpr int K4 = KDIM/4;
  #pragma unroll 2
  for (int k4=0;k4<K4;k4++){
    const int k=4*k4;
    float w0=W[(k+0)*COLS+j];
    float w1=W[(k+1)*COLS+j];
    float w2=W[(k+2)*COLS+j];
    float w3=W[(k+3)*COLS+j];
    #pragma unroll
    for (int r=0;r<R;r++){
      const float4 v = *(const float4*)(in + r*INSTRIDE + k);
      acc[r]=fmaf(v.w,w3,fmaf(v.z,w2,fmaf(v.y,w1,fmaf(v.x,w0,acc[r]))));
    }
  }
  if constexpr ((KDIM & 3) != 0) {
    #pragma unroll
    for (int k=K4*4;k<KDIM;k++){
      float wv=W[k*COLS+j];
      #pragma unroll
      for (int r=0;r<R;r++) acc[r]=fmaf(in[r*INSTRIDE+k],wv,acc[r]);
    }
  }
}

// ---------------- prefetching acc_mm, branch-free (KDIM % 4 == 0), R rows ----------------
template<int R,int COLS,int KDIM,int INSTRIDE>
__device__ __forceinline__ void acc_mm_p(const float* __restrict__ W,
                                         const float* __restrict__ in,
                                         float acc[R], int j)
{
  static_assert((KDIM & 3) == 0, "KDIM must be multiple of 4");
  constexpr int K4 = KDIM/4;
  const float* wp = W + j;
  float w0=wp[0], w1=wp[COLS], w2=wp[2*COLS], w3=wp[3*COLS];
  #pragma unroll 4
  for (int k4=0;k4<K4-1;k4++){
    const float* wn = wp + 4*COLS;
    float n0=wn[0], n1=wn[COLS], n2=wn[2*COLS], n3=wn[3*COLS];
    const float* ip = in + 4*k4;
    #pragma unroll
    for (int r=0;r<R;r++){
      const float4 v = *(const float4*)(ip + r*INSTRIDE);
      acc[r]=fmaf(v.w,w3,fmaf(v.z,w2,fmaf(v.y,w1,fmaf(v.x,w0,acc[r]))));
    }
    w0=n0;w1=n1;w2=n2;w3=n3;
    wp = wn;
  }
  { // epilogue k4 = K4-1
    const float* ip = in + 4*(K4-1);
    #pragma unroll
    for (int r=0;r<R;r++){
      const float4 v = *(const float4*)(ip + r*INSTRIDE);
      acc[r]=fmaf(v.w,w3,fmaf(v.z,w2,fmaf(v.y,w1,fmaf(v.x,w0,acc[r]))));
    }
  }
}

// ================= XW GEMM: out[m][cb+n] = sum_k x[m][xoff+k] * W[k][n] =================
__global__ __launch_bounds__(256)
void xw_gemm(const float* __restrict__ x, const float* __restrict__ W,
             float* __restrict__ out, int K, int WN, int cb, int xoff)
{
  __shared__ float As[32][128];
  __shared__ float Bs[32][128];
  const int t = threadIdx.x;
  const int m0 = blockIdx.x * 128;
  const int n0t = blockIdx.y * 128;
  const int arow = t & 127, akh = (t >> 7) * 16;
  const int bk = t >> 3,  bj = (t & 7) * 16;
  const int rbase = (t >> 4) * 8, cbase = (t & 15) * 4;

  float acc[8][8];
  #pragma unroll
  for (int i=0;i<8;i++)
    #pragma unroll
    for (int jj=0;jj<8;jj++) acc[i][jj]=0.f;

  const int nch = (K + 31) >> 5;
  for (int ch=0; ch<nch; ++ch){
    const int kc = ch*32;
    const float* xp = x + (size_t)(m0+arow)*DXF + xoff + kc + akh;
    #pragma unroll
    for (int e=0;e<16;e++){
      int k = akh + e;
      As[k][arow] = (kc + k < K) ? xp[e] : 0.f;
    }
    if (kc + bk < K){
      const float* wp = W + (size_t)(kc+bk)*WN + n0t + bj;
      #pragma unroll
      for (int e=0;e<16;e+=4)
        *(float4*)&Bs[bk][bj+e] = *(const float4*)&wp[e];
    } else {
      #pragma unroll
      for (int e=0;e<16;e++) Bs[bk][bj+e] = 0.f;
    }
    __syncthreads();
    #pragma unroll 8
    for (int k=0;k<32;k++){
      float4 a0 = *(const float4*)&As[k][rbase];
      float4 a1 = *(const float4*)&As[k][rbase+4];
      float4 b0 = *(const float4*)&Bs[k][cbase];
      float4 b1 = *(const float4*)&Bs[k][cbase+64];
      float av[8] = {a0.x,a0.y,a0.z,a0.w,a1.x,a1.y,a1.z,a1.w};
      float bv[8] = {b0.x,b0.y,b0.z,b0.w,b1.x,b1.y,b1.z,b1.w};
      #pragma unroll
      for (int i=0;i<8;i++)
        #pragma unroll
        for (int jj=0;jj<8;jj++)
          acc[i][jj] = fmaf(av[i], bv[jj], acc[i][jj]);
    }
    __syncthreads();
  }
  #pragma unroll
  for (int i=0;i<8;i++){
    float* op = out + (size_t)(m0+rbase+i)*1024 + cb + n0t;
    *(float4*)&op[cbase]    = make_float4(acc[i][0],acc[i][1],acc[i][2],acc[i][3]);
    *(float4*)&op[cbase+64] = make_float4(acc[i][4],acc[i][5],acc[i][6],acc[i][7]);
  }
}

// ================= recurrent kernel, PRE mode: 512 threads, 4 rows, 2 blocks/CU =================
// Two independent barrier domains per CU -> barrier drain in one block is hidden by the
// sibling block's waves. All 8 waves balanced in every matmul phase.
__global__ __launch_bounds__(THREADS, 4)
void tman_kernel_pre(Params p)
{
  __shared__ float cl[R2][128], hl[R2][128];
  __shared__ float ca[R2][64],  ha[R2][64];
  __shared__ float cv[R2][64],  hv[R2][64];
  __shared__ float zz[R2][64];
  __shared__ float sl[R2][512];
  __shared__ float sa[R2][256];
  __shared__ float sv[R2][256];
  __shared__ float hidl[R2][128], hida[R2][128], hidv[R2][128];
  __shared__ float hidat0[R2][128], hidat1[R2][128];
  __shared__ float scl[R2][64], sca[R2][64], scv[R2][64];
  __shared__ float attlog[R2][4];
  __shared__ float bl[512], ba[256], bv[256];

  const int tid  = threadIdx.x;
  const int lane = tid & 63;
  const int wave = tid >> 6;
  const int n0   = blockIdx.x * R2;

  for (int i=tid;i<512;i+=THREADS) bl[i]=p.bWl[i]+p.bUl[i]+p.bVl[i];
  if (tid<256){ ba[tid]=p.bWa[tid]+p.bUa[tid]+p.bVa[tid]; bv[tid]=p.bWv[tid]+p.bUv[tid]+p.bVv[tid]; }
  for (int i=tid;i<R2*128;i+=THREADS){ (&cl[0][0])[i]=0.f; (&hl[0][0])[i]=0.f; }
  if (tid<R2*64){
    (&ca[0][0])[tid]=0.f; (&ha[0][0])[tid]=0.f;
    (&cv[0][0])[tid]=0.f; (&hv[0][0])[tid]=0.f;
    (&zz[0][0])[tid]=0.f;
  }
  __syncthreads();

  for (int t=0;t<TSTEPS;++t){
    const float* wsr = p.ws + ((size_t)t*NB + n0)*1024;

    // ---- B: each wave: one L column-block (K=192) + one A-or-V column-block (K=128) ----
    {
      const int jc  = (wave<<6) + lane;                 // L cols 0..511
      const int jc2 = ((wave&3)<<6) + lane;             // A/V cols 0..255
      const int off2 = (wave<4) ? (512+jc2) : (768+jc2);
      float acc1[R2], acc2[R2];
      #pragma unroll
      for (int r=0;r<R2;r++) acc1[r] = wsr[r*1024 + jc];      // issue xW loads early
      #pragma unroll
      for (int r=0;r<R2;r++) acc2[r] = wsr[r*1024 + off2];
      acc_mm_p<R2,512,128,128>(p.Ul,&hl[0][0],acc1,jc);
      acc_mm_p<R2,512, 64, 64>(p.Vl,&zz[0][0],acc1,jc);
      const float b1 = bl[jc];
      #pragma unroll
      for (int r=0;r<R2;r++) sl[r][jc]=acc1[r]+b1;
      if (wave<4){
        acc_mm_p<R2,256,64,64>(p.Ua,&ha[0][0],acc2,jc2);
        acc_mm_p<R2,256,64,64>(p.Va,&zz[0][0],acc2,jc2);
        const float b2 = ba[jc2];
        #pragma unroll
        for (int r=0;r<R2;r++) sa[r][jc2]=acc2[r]+b2;
      } else {
        acc_mm_p<R2,256,64,64>(p.Uv,&hv[0][0],acc2,jc2);
        acc_mm_p<R2,256,64,64>(p.Vv,&zz[0][0],acc2,jc2);
        const float b2 = bv[jc2];
        #pragma unroll
        for (int r=0;r<R2;r++) sv[r][jc2]=acc2[r]+b2;
      }
    }
    __syncthreads();

    // ---- C: gates -> new c,h (512 threads fully used) ----
    {
      const int r=tid>>7, u=tid&127;   // 4 rows x 128
      float f =sigm(sl[r][u]);
      float ig=sigm(sl[r][128+u]);
      float o =sigm(sl[r][256+u]);
      float ch=tanhf(sl[r][384+u]);
      float c=f*cl[r][u]+ig*ch;
      cl[r][u]=c; hl[r][u]=tanhf(c)*o;
    }
    if (tid<256){
      const int r=tid>>6, u=tid&63;
      float f=sigm(sa[r][u]), ig=sigm(sa[r][64+u]), o=sigm(sa[r][128+u]), ch=tanhf(sa[r][192+u]);
      float c=f*ca[r][u]+ig*ch; ca[r][u]=c; ha[r][u]=tanhf(c)*o;
    } else {
      const int tt=tid-256, r=tt>>6, u=tt&63;
      float f=sigm(sv[r][u]), ig=sigm(sv[r][64+u]), o=sigm(sv[r][128+u]), ch=tanhf(sv[r][192+u]);
      float c=f*cv[r][u]+ig*ch; cv[r][u]=c; hv[r][u]=tanhf(c)*o;
    }
    __syncthreads();

    // ---- D1: all 8 waves active, ~32 k4-iters each ----
    if (wave<2){                       // hidl (K=128)
      const int j=(wave<<6)+lane;
      float acc[R2]; const float b=p.nlb1[j];
      #pragma unroll
      for (int r=0;r<R2;r++) acc[r]=b;
      acc_mm_p<R2,128,128,128>(p.nlW1,&cl[0][0],acc,j);
      #pragma unroll
      for (int r=0;r<R2;r++) hidl[r][j]=fmaxf(acc[r],0.f);
    } else if (wave<4){                // hidat0 = attW1[0:128] @ cl (K=128)
      const int j=((wave-2)<<6)+lane;
      float acc[R2]; const float b=p.attb1[j];
      #pragma unroll
      for (int r=0;r<R2;r++) acc[r]=b;
      acc_mm_p<R2,128,128,128>(p.attW1,&cl[0][0],acc,j);
      #pragma unroll
      for (int r=0;r<R2;r++) hidat0[r][j]=acc[r];
    } else if (wave<6){                // hidat1 = attW1[128:256] @ [ca;cv] (K=64+64)
      const int j=((wave-4)<<6)+lane;
      float acc[R2];
      #pragma unroll
      for (int r=0;r<R2;r++) acc[r]=0.f;
      acc_mm_p<R2,128,64,64>(p.attW1+128*128,&ca[0][0],acc,j);
      acc_mm_p<R2,128,64,64>(p.attW1+192*128,&cv[0][0],acc,j);
      #pragma unroll
      for (int r=0;r<R2;r++) hidat1[r][j]=acc[r];
    } else if (wave==6){               // hida full 128 cols (2 x K=64)
      float acc[R2], acc2[R2];
      const float b0=p.nab1[lane], b1=p.nab1[64+lane];
      #pragma unroll
      for (int r=0;r<R2;r++){ acc[r]=b0; acc2[r]=b1; }
      acc_mm_p<R2,128,64,64>(p.naW1,   &ca[0][0],acc, lane);
      acc_mm_p<R2,128,64,64>(p.naW1,   &ca[0][0],acc2,64+lane);
      #pragma unroll
      for (int r=0;r<R2;r++){ hida[r][lane]=fmaxf(acc[r],0.f); hida[r][64+lane]=fmaxf(acc2[r],0.f); }
    } else {                           // hidv full 128 cols
      float acc[R2], acc2[R2];
      const float b0=p.nvb1[lane], b1=p.nvb1[64+lane];
      #pragma unroll
      for (int r=0;r<R2;r++){ acc[r]=b0; acc2[r]=b1; }
      acc_mm_p<R2,128,64,64>(p.nvW1,   &cv[0][0],acc, lane);
      acc_mm_p<R2,128,64,64>(p.nvW1,   &cv[0][0],acc2,64+lane);
      #pragma unroll
      for (int r=0;r<R2;r++){ hidv[r][lane]=fmaxf(acc[r],0.f); hidv[r][64+lane]=fmaxf(acc2[r],0.f); }
    }
    __syncthreads();

    // ---- D2: second layers ----
    if (wave==0){
      float acc[R2]; const float b=p.nlb2[lane];
      #pragma unroll
      for (int r=0;r<R2;r++) acc[r]=b;
      acc_mm_p<R2,64,128,128>(p.nlW2,&hidl[0][0],acc,lane);
      #pragma unroll
      for (int r=0;r<R2;r++) scl[r][lane]=acc[r];
    } else if (wave==1){
      float acc[R2]; const float b=p.nab2[lane];
      #pragma unroll
      for (int r=0;r<R2;r++) acc[r]=b;
      acc_mm_p<R2,64,128,128>(p.naW2,&hida[0][0],acc,lane);
      #pragma unroll
      for (int r=0;r<R2;r++) sca[r][lane]=acc[r];
    } else if (wave==2){
      float acc[R2]; const float b=p.nvb2[lane];
      #pragma unroll
      for (int r=0;r<R2;r++) acc[r]=b;
      acc_mm_p<R2,64,128,128>(p.nvW2,&hidv[0][0],acc,lane);
      #pragma unroll
      for (int r=0;r<R2;r++) scv[r][lane]=acc[r];
    } else if (wave==3 && lane<R2*3*4){
      // attlog: 12 dot-products (4 rows x 3 modalities), 4 lanes each
      const int g=lane>>2, q=lane&3;     // g in [0,12), q in [0,4)
      const int r=g/3, m=g-3*r;
      float s=0.f;
      const int k0=q*32;
      #pragma unroll 8
      for (int k=k0;k<k0+32;k++){
        float hvv = fmaxf(hidat0[r][k]+hidat1[r][k], 0.f);
        s=fmaf(hvv,p.attW2[k*3+m],s);
      }
      s += __shfl_xor(s,1);
      s += __shfl_xor(s,2);
      if (q==0) attlog[r][m]=s+p.attb2[m];
    }
    __syncthreads();

    // ---- D3: softmax over modalities + z ----
    if (tid < R2*64){
      const int r=tid>>6, u=tid&63;
      float a0=attlog[r][0], a1=attlog[r][1], a2=attlog[r][2];
      float m=fmaxf(a0,fmaxf(a1,a2));
      float e0=__expf(a0-m), e1=__expf(a1-m), e2=__expf(a2-m);
      float inv=1.f/(e0+e1+e2);
      zz[r][u]=(e0*scl[r][u]+e1*sca[r][u]+e2*scv[r][u])*inv;
    }
    __syncthreads();
  }

  // ---- final MLP: last=[hl,ha,hv,z] (320) -> 128 relu -> 1 ----
  if (wave<2){
    const int j=(wave<<6)+lane;
    float acc[R2]; const float b=p.outb1[j];
    #pragma unroll
    for (int r=0;r<R2;r++) acc[r]=b;
    acc_mm_p<R2,128,128,128>(p.outW1,          &hl[0][0],acc,j);
    acc_mm_p<R2,128, 64, 64>(p.outW1+128*128,  &ha[0][0],acc,j);
    acc_mm_p<R2,128, 64, 64>(p.outW1+192*128,  &hv[0][0],acc,j);
    acc_mm_p<R2,128, 64, 64>(p.outW1+256*128,  &zz[0][0],acc,j);
    #pragma unroll
    for (int r=0;r<R2;r++) hidl[r][j]=fmaxf(acc[r],0.f);
  }
  __syncthreads();
  if (tid<R2){
    float acc=p.outb2[0];
    for (int k=0;k<128;k++) acc=fmaf(hidl[tid][k],p.outW2[k],acc);
    p.out[n0+tid]=acc;
  }
}

// ================= fallback: original 512-thread kernel (proven, no-ws path) =================
__global__ __launch_bounds__(THREADS)
void tman_kernel(Params p)
{
  __shared__ float xsl[ROWS][300];
  __shared__ float xsa[ROWS][76];
  __shared__ float xsv[ROWS][36];
  __shared__ float cl[ROWS][128], hl[ROWS][128];
  __shared__ float ca[ROWS][64],  ha[ROWS][64];
  __shared__ float cv[ROWS][64],  hv[ROWS][64];
  __shared__ float zz[ROWS][64];
  __shared__ float sl[ROWS][512];
  __shared__ float sa[ROWS][256];
  __shared__ float sv[ROWS][256];
  __shared__ float hidl[ROWS][128], hida[ROWS][128], hidv[ROWS][128], hidat[ROWS][128];
  __shared__ float scl[ROWS][64], sca[ROWS][64], scv[ROWS][64];
  __shared__ float attlog[ROWS][4];
  __shared__ float bl[512], ba[256], bv[256];

  const int tid  = threadIdx.x;
  const int lane = tid & 63;
  const int wave = tid >> 6;
  const int n0   = blockIdx.x * ROWS;

  for (int i=tid;i<512;i+=THREADS) bl[i]=p.bWl[i]+p.bUl[i]+p.bVl[i];
  for (int i=tid;i<256;i+=THREADS){ ba[i]=p.bWa[i]+p.bUa[i]+p.bVa[i]; bv[i]=p.bWv[i]+p.bUv[i]+p.bVv[i]; }
  for (int i=tid;i<ROWS*128;i+=THREADS){ (&cl[0][0])[i]=0.f; (&hl[0][0])[i]=0.f; }
  for (int i=tid;i<ROWS*64;i+=THREADS){
    (&ca[0][0])[i]=0.f; (&ha[0][0])[i]=0.f;
    (&cv[0][0])[i]=0.f; (&hv[0][0])[i]=0.f;
    (&zz[0][0])[i]=0.f;
  }
  __syncthreads();

  for (int t=0;t<TSTEPS;++t){
    const float* xt = p.x + ((size_t)t*NB + n0)*DXF;
    for (int i=tid;i<ROWS*DXF;i+=THREADS){
      int r=i/DXF, d=i-r*DXF;
      float v=xt[(size_t)r*DXF+d];
      if (d<300) xsl[r][d]=v;
      else if (d<374) xsa[r][d-300]=v;
      else xsv[r][d-374]=v;
    }
    __syncthreads();

    {
      int j = wave*64 + lane;
      float acc[ROWS]; float b=bl[j];
      #pragma unroll
      for (int r=0;r<ROWS;r++) acc[r]=b;
      acc_mm<ROWS,512,300,300>(p.Wl,&xsl[0][0],acc,j);
      acc_mm<ROWS,512,128,128>(p.Ul,&hl[0][0],acc,j);
      acc_mm<ROWS,512, 64, 64>(p.Vl,&zz[0][0],acc,j);
      #pragma unroll
      for (int r=0;r<ROWS;r++) sl[r][j]=acc[r];
    }
    {
      int item = 15-wave;
      if (item>=12){
        int j=(item-12)*64+lane;
        float acc[ROWS]; float b=bv[j];
        #pragma unroll
        for (int r=0;r<ROWS;r++) acc[r]=b;
        acc_mm<ROWS,256,35,36>(p.Wv,&xsv[0][0],acc,j);
        acc_mm<ROWS,256,64,64>(p.Uv,&hv[0][0],acc,j);
        acc_mm<ROWS,256,64,64>(p.Vv,&zz[0][0],acc,j);
        #pragma unroll
        for (int r=0;r<ROWS;r++) sv[r][j]=acc[r];
      } else {
        int j=(item-8)*64+lane;
        float acc[ROWS]; float b=ba[j];
        #pragma unroll
        for (int r=0;r<ROWS;r++) acc[r]=b;
        acc_mm<ROWS,256,74,76>(p.Wa,&xsa[0][0],acc,j);
        acc_mm<ROWS,256,64,64>(p.Ua,&ha[0][0],acc,j);
        acc_mm<ROWS,256,64,64>(p.Va,&zz[0][0],acc,j);
        #pragma unroll
        for (int r=0;r<ROWS;r++) sa[r][j]=acc[r];
      }
    }
    __syncthreads();

    for (int i=tid;i<ROWS*128;i+=THREADS){
      int r=i>>7, u=i&127;
      float f =sigm(sl[r][u]);
      float ig=sigm(sl[r][128+u]);
      float o =sigm(sl[r][256+u]);
      float ch=tanhf(sl[r][384+u]);
      float c=f*cl[r][u]+ig*ch;
      cl[r][u]=c; hl[r][u]=tanhf(c)*o;
    }
    for (int i=tid;i<ROWS*64;i+=THREADS){
      int r=i>>6, u=i&63;
      { float f=sigm(sa[r][u]), ig=sigm(sa[r][64+u]), o=sigm(sa[r][128+u]), ch=tanhf(sa[r][192+u]);
        float c=f*ca[r][u]+ig*ch; ca[r][u]=c; ha[r][u]=tanhf(c)*o; }
      { float f=sigm(sv[r][u]), ig=sigm(sv[r][64+u]), o=sigm(sv[r][128+u]), ch=tanhf(sv[r][192+u]);
        float c=f*cv[r][u]+ig*ch; cv[r][u]=c; hv[r][u]=tanhf(c)*o; }
    }
    __syncthreads();

    if (wave<2){
      int j=wave*64+lane;
      float acc[ROWS]; float b=p.nlb1[j];
      #pragma unroll
      for (int r=0;r<ROWS;r++) acc[r]=b;
      acc_mm<ROWS,128,128,128>(p.nlW1,&cl[0][0],acc,j);
      #pragma unroll
      for (int r=0;r<ROWS;r++) hidl[r][j]=fmaxf(acc[r],0.f);
    } else if (wave<4){
      int j=(wave-2)*64+lane;
      float acc[ROWS]; float b=p.nab1[j];
      #pragma unroll
      for (int r=0;r<ROWS;r++) acc[r]=b;
      acc_mm<ROWS,128,64,64>(p.naW1,&ca[0][0],acc,j);
      #pragma unroll
      for (int r=0;r<ROWS;r++) hida[r][j]=fmaxf(acc[r],0.f);
    } else if (wave<6){
      int j=(wave-4)*64+lane;
      float acc[ROWS]; float b=p.nvb1[j];
      #pragma unroll
      for (int r=0;r<ROWS;r++) acc[r]=b;
      acc_mm<ROWS,128,64,64>(p.nvW1,&cv[0][0],acc,j);
      #pragma unroll
      for (int r=0;r<ROWS;r++) hidv[r][j]=fmaxf(acc[r],0.f);
    } else {
      int j=(wave-6)*64+lane;
      float acc[ROWS]; float b=p.attb1[j];
      #pragma unroll
      for (int r=0;r<ROWS;r++) acc[r]=b;
      acc_mm<ROWS,128,128,128>(p.attW1,          &cl[0][0],acc,j);
      acc_mm<ROWS,128, 64, 64>(p.attW1+128*128,  &ca[0][0],acc,j);
      acc_mm<ROWS,128, 64, 64>(p.attW1+192*128,  &cv[0][0],acc,j);
      #pragma unroll
      for (int r=0;r<ROWS;r++) hidat[r][j]=fmaxf(acc[r],0.f);
    }
    __syncthreads();

    if (wave==0){
      float acc[ROWS]; float b=p.nlb2[lane];
      #pragma unroll
      for (int r=0;r<ROWS;r++) acc[r]=b;
      acc_mm<ROWS,64,128,128>(p.nlW2,&hidl[0][0],acc,lane);
      #pragma unroll
      for (int r=0;r<ROWS;r++) scl[r][lane]=acc[r];
    } else if (wave==1){
      float acc[ROWS]; float b=p.nab2[lane];
      #pragma unroll
      for (int r=0;r<ROWS;r++) acc[r]=b;
      acc_mm<ROWS,64,128,128>(p.naW2,&hida[0][0],acc,lane);
      #pragma unroll
      for (int r=0;r<ROWS;r++) sca[r][lane]=acc[r];
    } else if (wave==2){
      float acc[ROWS]; float b=p.nvb2[lane];
      #pragma unroll
      for (int r=0;r<ROWS;r++) acc[r]=b;
      acc_mm<ROWS,64,128,128>(p.nvW2,&hidv[0][0],acc,lane);
      #pragma unroll
      for (int r=0;r<ROWS;r++) scv[r][lane]=acc[r];
    } else if (wave==3 && lane<ROWS*3){
      int r=lane/3, m=lane-3*r;
      float a=p.attb2[m];
      for (int k=0;k<128;k++) a=fmaf(hidat[r][k],p.attW2[k*3+m],a);
      attlog[r][m]=a;
    }
    __syncthreads();

    for (int i=tid;i<ROWS*64;i+=THREADS){
      int r=i>>6, u=i&63;
      float a0=attlog[r][0], a1=attlog[r][1], a2=attlog[r][2];
      float m=fmaxf(a0,fmaxf(a1,a2));
      float e0=__expf(a0-m), e1=__expf(a1-m), e2=__expf(a2-m);
      float inv=1.f/(e0+e1+e2);
      zz[r][u]=(e0*scl[r][u]+e1*sca[r][u]+e2*scv[r][u])*inv;
    }
    __syncthreads();
  }

  if (wave<2){
    int j=wave*64+lane;
    float acc[ROWS]; float b=p.outb1[j];
    #pragma unroll
    for (int r=0;r<ROWS;r++) acc[r]=b;
    acc_mm<ROWS,128,128,128>(p.outW1,          &hl[0][0],acc,j);
    acc_mm<ROWS,128, 64, 64>(p.outW1+128*128,  &ha[0][0],acc,j);
    acc_mm<ROWS,128, 64, 64>(p.outW1+192*128,  &hv[0][0],acc,j);
    acc_mm<ROWS,128, 64, 64>(p.outW1+256*128,  &zz[0][0],acc,j);
    #pragma unroll
    for (int r=0;r<ROWS;r++) hidl[r][j]=fmaxf(acc[r],0.f);
  }
  __syncthreads();
  if (tid<ROWS){
    float acc=p.outb2[0];
    for (int k=0;k<128;k++) acc=fmaf(hidl[tid][k],p.outW2[k],acc);
    p.out[n0+tid]=acc;
  }
}

extern "C" void kernel_launch(void* const* d_in, const int* in_sizes, int n_in,
                              void* d_out, int out_size, void* d_ws, size_t ws_size,
                              hipStream_t stream) {
  const float* const* f = (const float* const*)d_in;
  Params P;
  P.x  =f[0];
  P.Wl =f[1];  P.bWl=f[2];  P.Ul =f[3];  P.bUl=f[4];  P.Vl =f[5];  P.bVl=f[6];
  P.Wa =f[7];  P.bWa=f[8];  P.Ua =f[9];  P.bUa=f[10]; P.Va =f[11]; P.bVa=f[12];
  P.Wv =f[13]; P.bWv=f[14]; P.Uv =f[15]; P.bUv=f[16]; P.Vv =f[17]; P.bVv=f[18];
  P.nlW1=f[19]; P.nlb1=f[20]; P.nlW2=f[21]; P.nlb2=f[22];
  P.naW1=f[23]; P.nab1=f[24]; P.naW2=f[25]; P.nab2=f[26];
  P.nvW1=f[27]; P.nvb1=f[28]; P.nvW2=f[29]; P.nvb2=f[30];
  P.attW1=f[31]; P.attb1=f[32]; P.attW2=f[33]; P.attb2=f[34];
  P.outW1=f[35]; P.outb1=f[36]; P.outW2=f[37]; P.outb2=f[38];
  P.out=(float*)d_out;
  P.ws =(const float*)d_ws;

  const size_t XW_BYTES = (size_t)TSTEPS * NB * 1024 * sizeof(float);  // 1.07 GB
  if (ws_size >= XW_BYTES) {
    float* xw = (float*)d_ws;
    hipLaunchKernelGGL(xw_gemm, dim3(TSTEPS*NB/128, 4), dim3(256), 0, stream,
                       P.x, P.Wl, xw, 300, 512,   0,   0);
    hipLaunchKernelGGL(xw_gemm, dim3(TSTEPS*NB/128, 2), dim3(256), 0, stream,
                       P.x, P.Wa, xw,  74, 256, 512, 300);
    hipLaunchKernelGGL(xw_gemm, dim3(TSTEPS*NB/128, 2), dim3(256), 0, stream,
                       P.x, P.Wv, xw,  35, 256, 768, 374);
    hipLaunchKernelGGL(tman_kernel_pre, dim3(NB/R2), dim3(THREADS), 0, stream, P);
  } else {
    hipLaunchKernelGGL(tman_kernel, dim3(NB/ROWS), dim3(THREADS), 0, stream, P);
  }
}

// Round 5
// 6143.778 us; speedup vs baseline: 2.2503x; 1.0177x over previous
//
#include <hip/hip_runtime.h>
#include <cmath>

#define ROWS 8          // fallback kernel rows
#define THREADS 512
#define NB 2048
#define TSTEPS 128
#define DXF 409
#define MROWS 16        // MFMA kernel: rows per block

using bf16   = __bf16;
using bf16x8 = __attribute__((ext_vector_type(8))) __bf16;
using f32x4  = __attribute__((ext_vector_type(4))) float;

struct Params {
  const float *x;
  const float *Wl,*bWl,*Ul,*bUl,*Vl,*bVl;
  const float *Wa,*bWa,*Ua,*bUa,*Va,*bVa;
  const float *Wv,*bWv,*Uv,*bUv,*Vv,*bVv;
  const float *nlW1,*nlb1,*nlW2,*nlb2;
  const float *naW1,*nab1,*naW2,*nab2;
  const float *nvW1,*nvb1,*nvW2,*nvb2;
  const float *attW1,*attb1,*attW2,*attb2;
  const float *outW1,*outb1,*outW2,*outb2;
  const float *ws;
  float *out;
};

__device__ __forceinline__ float sigm(float x){ return 1.0f/(1.0f+__expf(-x)); }

// ===== packed-weight offsets (bf16 elements) =====
// layout per matrix: tile = tn*nKT + tk ; element ((tile*64)+lane)*8 + i =
//   W[tk*32 + (lane>>4)*8 + i][tn*16 + (lane&15)]   (zero beyond Kdim/N)
#define OFF_Wl    0
#define OFF_Wa    163840
#define OFF_Wv    188416
#define OFF_Ul    204800
#define OFF_Vl    270336
#define OFF_Ua    303104
#define OFF_Va    319488
#define OFF_Uv    335872
#define OFF_Vv    352256
#define OFF_nlW1  368640
#define OFF_naW1  385024
#define OFF_nvW1  393216
#define OFF_attW1 401408
#define OFF_nlW2  434176
#define OFF_naW2  442368
#define OFF_nvW2  450560
#define OFF_attW2 458752
#define WS_ELEMS  460800

// ================= weight packing: fp32 [Kdim][N] -> bf16 MFMA-B fragments =================
__global__ __launch_bounds__(256)
void pack_w(const float* __restrict__ W, bf16* __restrict__ dst,
            int Kdim, int Kpad, int N, int Npad)
{
  const int nKT = Kpad >> 5;
  const int total = (Npad >> 4) * nKT * 64;
  int idx = blockIdx.x*256 + threadIdx.x;
  if (idx >= total) return;
  int lane = idx & 63;
  int tile = idx >> 6;
  int tn = tile / nKT, tk = tile - tn*nKT;
  int col = (tn<<4) + (lane & 15);
  int k0  = (tk<<5) + ((lane>>4)<<3);
  bf16x8 v;
  #pragma unroll
  for (int i=0;i<8;i++){
    int kr = k0 + i;
    float f = (kr < Kdim && col < N) ? W[(size_t)kr*N + col] : 0.f;
    v[i] = (bf16)f;
  }
  ((bf16x8*)dst)[idx] = v;
}

__device__ __forceinline__ f32x4 mfma16(bf16x8 a, bf16x8 b, f32x4 c){
  return __builtin_amdgcn_mfma_f32_16x16x32_bf16(a, b, c, 0, 0, 0);
}
// A-fragment from LDS: row = lane&15, k = kt*32 + (lane>>4)*8 .. +8
__device__ __forceinline__ bf16x8 lda(const bf16* buf, int stride, int kt, int lane){
  return *(const bf16x8*)(buf + (lane&15)*stride + (kt<<5) + ((lane>>4)<<3));
}
// B-fragment from packed global
__device__ __forceinline__ bf16x8 ldb(const bf16* base, int tile, int lane){
  return ((const bf16x8*)base)[tile*64 + lane];
}

// ================= MFMA recurrent kernel: 16 rows/block, 512 threads, grid=128 =================
__global__ __launch_bounds__(512, 2)
void tman_mfma(Params p)
{
  // fp32 state (strides padded for 2-way-max write banking)
  __shared__ float cl32[16][132], hl32[16][132];
  __shared__ float ca32[16][68], ha32[16][68], cv32[16][68], hv32[16][68], zz32[16][68];
  __shared__ float scl[16][68], sca[16][68], scv[16][68];
  __shared__ float attlog[16][4];
  __shared__ float blb[512], bab[256], bvb[256];
  // bf16 A-operand buffers (strides chosen for uniform bank spread on transpose reads)
  __shared__ __align__(16) bf16 xl_b[16][328];   // x cols 0..299, zeros 300..319
  __shared__ __align__(16) bf16 xa_b[16][104];   // x cols 300..373 -> 0..73, zeros 74..95
  __shared__ __align__(16) bf16 xv_b[16][72];    // x cols 374..408 -> 0..34, zeros 35..63
  __shared__ __align__(16) bf16 hl_b[16][136], cl_b[16][136];
  __shared__ __align__(16) bf16 ha_b[16][72], hv_b[16][72], ca_b[16][72], cv_b[16][72], zz_b[16][72];
  __shared__ __align__(16) bf16 hidl_b[16][136], hida_b[16][136], hidv_b[16][136], hidat_b[16][136];

  const int tid  = threadIdx.x;
  const int lane = tid & 63;
  const int wave = tid >> 6;
  const int rb   = ((lane>>4)<<2);       // C/D row base
  const int cL   = lane & 15;            // C/D col within tile
  const int n0   = blockIdx.x * MROWS;
  const bf16* wsb = (const bf16*)p.ws;

  // ---- init ----
  if (tid < 512) blb[tid] = p.bWl[tid]+p.bUl[tid]+p.bVl[tid];
  if (tid < 256){ bab[tid]=p.bWa[tid]+p.bUa[tid]+p.bVa[tid]; bvb[tid]=p.bWv[tid]+p.bUv[tid]+p.bVv[tid]; }
  for (int i=tid;i<16*132;i+=512){ (&cl32[0][0])[i]=0.f; }
  for (int i=tid;i<16*68;i+=512){ (&ca32[0][0])[i]=0.f; (&cv32[0][0])[i]=0.f; }
  for (int i=tid;i<16*136;i+=512){ (&hl_b[0][0])[i]=(bf16)0.f; }
  for (int i=tid;i<16*72;i+=512){
    (&ha_b[0][0])[i]=(bf16)0.f; (&hv_b[0][0])[i]=(bf16)0.f; (&zz_b[0][0])[i]=(bf16)0.f;
  }
  for (int i=tid;i<16*328;i+=512) (&xl_b[0][0])[i]=(bf16)0.f;
  for (int i=tid;i<16*104;i+=512) (&xa_b[0][0])[i]=(bf16)0.f;
  for (int i=tid;i<16*72;i+=512)  (&xv_b[0][0])[i]=(bf16)0.f;
  __syncthreads();

  const int w2 = wave & 3;

  for (int t=0;t<TSTEPS;++t){
    // ---- stage x[t] (bf16) ----
    const float* xt = p.x + ((size_t)t*NB + n0)*DXF;
    for (int i=tid;i<MROWS*DXF;i+=512){
      int r=i/DXF, d=i-r*DXF;
      bf16 bv = (bf16)xt[(size_t)r*DXF + d];
      if (d<300) xl_b[r][d]=bv;
      else if (d<374) xa_b[r][d-300]=bv;
      else xv_b[r][d-374]=bv;
    }
    __syncthreads();

    // ---- phase B: gate preactivations via MFMA ----
    f32x4 accL[4] = {{0,0,0,0},{0,0,0,0},{0,0,0,0},{0,0,0,0}};
    f32x4 acc2[4] = {{0,0,0,0},{0,0,0,0},{0,0,0,0},{0,0,0,0}};
    // L: x part (K=320)
    #pragma unroll
    for (int tk=0;tk<10;tk++){
      bf16x8 a = lda(&xl_b[0][0],328,tk,lane);
      #pragma unroll
      for (int g=0;g<4;g++) accL[g]=mfma16(a, ldb(wsb+OFF_Wl,(wave+8*g)*10+tk,lane), accL[g]);
    }
    // L: h part (K=128)
    #pragma unroll
    for (int tk=0;tk<4;tk++){
      bf16x8 a = lda(&hl_b[0][0],136,tk,lane);
      #pragma unroll
      for (int g=0;g<4;g++) accL[g]=mfma16(a, ldb(wsb+OFF_Ul,(wave+8*g)*4+tk,lane), accL[g]);
    }
    // L: z part (K=64)
    #pragma unroll
    for (int tk=0;tk<2;tk++){
      bf16x8 a = lda(&zz_b[0][0],72,tk,lane);
      #pragma unroll
      for (int g=0;g<4;g++) accL[g]=mfma16(a, ldb(wsb+OFF_Vl,(wave+8*g)*2+tk,lane), accL[g]);
    }
    if (wave < 4){  // A gates
      #pragma unroll
      for (int tk=0;tk<3;tk++){
        bf16x8 a = lda(&xa_b[0][0],104,tk,lane);
        #pragma unroll
        for (int g=0;g<4;g++) acc2[g]=mfma16(a, ldb(wsb+OFF_Wa,(w2+4*g)*3+tk,lane), acc2[g]);
      }
      #pragma unroll
      for (int tk=0;tk<2;tk++){
        bf16x8 a = lda(&ha_b[0][0],72,tk,lane);
        #pragma unroll
        for (int g=0;g<4;g++) acc2[g]=mfma16(a, ldb(wsb+OFF_Ua,(w2+4*g)*2+tk,lane), acc2[g]);
      }
      #pragma unroll
      for (int tk=0;tk<2;tk++){
        bf16x8 a = lda(&zz_b[0][0],72,tk,lane);
        #pragma unroll
        for (int g=0;g<4;g++) acc2[g]=mfma16(a, ldb(wsb+OFF_Va,(w2+4*g)*2+tk,lane), acc2[g]);
      }
    } else {        // V gates
      #pragma unroll
      for (int tk=0;tk<2;tk++){
        bf16x8 a = lda(&xv_b[0][0],72,tk,lane);
        #pragma unroll
        for (int g=0;g<4;g++) acc2[g]=mfma16(a, ldb(wsb+OFF_Wv,(w2+4*g)*2+tk,lane), acc2[g]);
      }
      #pragma unroll
      for (int tk=0;tk<2;tk++){
        bf16x8 a = lda(&hv_b[0][0],72,tk,lane);
        #pragma unroll
        for (int g=0;g<4;g++) acc2[g]=mfma16(a, ldb(wsb+OFF_Uv,(w2+4*g)*2+tk,lane), acc2[g]);
      }
      #pragma unroll
      for (int tk=0;tk<2;tk++){
        bf16x8 a = lda(&zz_b[0][0],72,tk,lane);
        #pragma unroll
        for (int g=0;g<4;g++) acc2[g]=mfma16(a, ldb(wsb+OFF_Vv,(w2+4*g)*2+tk,lane), acc2[g]);
      }
    }
    __syncthreads();   // all reads of h/z/x done before state rewrite

    // ---- gate combine (in-register; this lane owns (row=rb+q, unit)) ----
    {
      const int uL = (wave<<4) + cL;
      #pragma unroll
      for (int q=0;q<4;q++){
        int row = rb+q;
        float f = sigm(accL[0][q] + blb[uL]);
        float ig= sigm(accL[1][q] + blb[128+uL]);
        float o = sigm(accL[2][q] + blb[256+uL]);
        float ch= tanhf(accL[3][q] + blb[384+uL]);
        float c = f*cl32[row][uL] + ig*ch;
        float h = tanhf(c)*o;
        cl32[row][uL]=c; hl32[row][uL]=h;
        cl_b[row][uL]=(bf16)c; hl_b[row][uL]=(bf16)h;
      }
      const int u2 = (w2<<4) + cL;
      if (wave<4){
        #pragma unroll
        for (int q=0;q<4;q++){
          int row = rb+q;
          float f = sigm(acc2[0][q] + bab[u2]);
          float ig= sigm(acc2[1][q] + bab[64+u2]);
          float o = sigm(acc2[2][q] + bab[128+u2]);
          float ch= tanhf(acc2[3][q] + bab[192+u2]);
          float c = f*ca32[row][u2] + ig*ch;
          float h = tanhf(c)*o;
          ca32[row][u2]=c; ha32[row][u2]=h;
          ca_b[row][u2]=(bf16)c; ha_b[row][u2]=(bf16)h;
        }
      } else {
        #pragma unroll
        for (int q=0;q<4;q++){
          int row = rb+q;
          float f = sigm(acc2[0][q] + bvb[u2]);
          float ig= sigm(acc2[1][q] + bvb[64+u2]);
          float o = sigm(acc2[2][q] + bvb[128+u2]);
          float ch= tanhf(acc2[3][q] + bvb[192+u2]);
          float c = f*cv32[row][u2] + ig*ch;
          float h = tanhf(c)*o;
          cv32[row][u2]=c; hv32[row][u2]=h;
          cv_b[row][u2]=(bf16)c; hv_b[row][u2]=(bf16)h;
        }
      }
    }
    __syncthreads();

    // ---- D1: hidden layers (inputs = new cell states) ----
    if (wave<2){          // nl: tiles wave*4..+3, K=128 (cl)
      f32x4 acc[4] = {{0,0,0,0},{0,0,0,0},{0,0,0,0},{0,0,0,0}};
      #pragma unroll
      for (int tk=0;tk<4;tk++){
        bf16x8 a = lda(&cl_b[0][0],136,tk,lane);
        #pragma unroll
        for (int g=0;g<4;g++) acc[g]=mfma16(a, ldb(wsb+OFF_nlW1,((wave<<2)+g)*4+tk,lane), acc[g]);
      }
      #pragma unroll
      for (int g=0;g<4;g++){
        int col = ((wave<<2)+g)*16 + cL;
        float b = p.nlb1[col];
        #pragma unroll
        for (int q=0;q<4;q++) hidl_b[rb+q][col] = (bf16)fmaxf(acc[g][q]+b, 0.f);
      }
    } else if (wave==2){  // na: 8 tiles, K=64 (ca)
      f32x4 acc[8] = {{0,0,0,0},{0,0,0,0},{0,0,0,0},{0,0,0,0},{0,0,0,0},{0,0,0,0},{0,0,0,0},{0,0,0,0}};
      #pragma unroll
      for (int tk=0;tk<2;tk++){
        bf16x8 a = lda(&ca_b[0][0],72,tk,lane);
        #pragma unroll
        for (int g=0;g<8;g++) acc[g]=mfma16(a, ldb(wsb+OFF_naW1,g*2+tk,lane), acc[g]);
      }
      #pragma unroll
      for (int g=0;g<8;g++){
        int col = g*16 + cL;
        float b = p.nab1[col];
        #pragma unroll
        for (int q=0;q<4;q++) hida_b[rb+q][col] = (bf16)fmaxf(acc[g][q]+b, 0.f);
      }
    } else if (wave==3){  // nv
      f32x4 acc[8] = {{0,0,0,0},{0,0,0,0},{0,0,0,0},{0,0,0,0},{0,0,0,0},{0,0,0,0},{0,0,0,0},{0,0,0,0}};
      #pragma unroll
      for (int tk=0;tk<2;tk++){
        bf16x8 a = lda(&cv_b[0][0],72,tk,lane);
        #pragma unroll
        for (int g=0;g<8;g++) acc[g]=mfma16(a, ldb(wsb+OFF_nvW1,g*2+tk,lane), acc[g]);
      }
      #pragma unroll
      for (int g=0;g<8;g++){
        int col = g*16 + cL;
        float b = p.nvb1[col];
        #pragma unroll
        for (int q=0;q<4;q++) hidv_b[rb+q][col] = (bf16)fmaxf(acc[g][q]+b, 0.f);
      }
    } else {              // waves 4-7: att, tiles (w-4)*2..+1, K=256 = [cl;ca;cv]
      f32x4 acc[2] = {{0,0,0,0},{0,0,0,0}};
      #pragma unroll
      for (int tk=0;tk<8;tk++){
        bf16x8 a = (tk<4) ? lda(&cl_b[0][0],136,tk,lane)
                 : (tk<6) ? lda(&ca_b[0][0],72,tk-4,lane)
                          : lda(&cv_b[0][0],72,tk-6,lane);
        #pragma unroll
        for (int g=0;g<2;g++) acc[g]=mfma16(a, ldb(wsb+OFF_attW1,(((wave-4)<<1)+g)*8+tk,lane), acc[g]);
      }
      #pragma unroll
      for (int g=0;g<2;g++){
        int col = (((wave-4)<<1)+g)*16 + cL;
        float b = p.attb1[col];
        #pragma unroll
        for (int q=0;q<4;q++) hidat_b[rb+q][col] = (bf16)fmaxf(acc[g][q]+b, 0.f);
      }
    }
    __syncthreads();

    // ---- D2: second layers ----
    if (wave==0){
      f32x4 acc[4] = {{0,0,0,0},{0,0,0,0},{0,0,0,0},{0,0,0,0}};
      #pragma unroll
      for (int tk=0;tk<4;tk++){
        bf16x8 a = lda(&hidl_b[0][0],136,tk,lane);
        #pragma unroll
        for (int g=0;g<4;g++) acc[g]=mfma16(a, ldb(wsb+OFF_nlW2,g*4+tk,lane), acc[g]);
      }
      #pragma unroll
      for (int g=0;g<4;g++){
        int col=g*16+cL; float b=p.nlb2[col];
        #pragma unroll
        for (int q=0;q<4;q++) scl[rb+q][col]=acc[g][q]+b;
      }
    } else if (wave==1){
      f32x4 acc[4] = {{0,0,0,0},{0,0,0,0},{0,0,0,0},{0,0,0,0}};
      #pragma unroll
      for (int tk=0;tk<4;tk++){
        bf16x8 a = lda(&hida_b[0][0],136,tk,lane);
        #pragma unroll
        for (int g=0;g<4;g++) acc[g]=mfma16(a, ldb(wsb+OFF_naW2,g*4+tk,lane), acc[g]);
      }
      #pragma unroll
      for (int g=0;g<4;g++){
        int col=g*16+cL; float b=p.nab2[col];
        #pragma unroll
        for (int q=0;q<4;q++) sca[rb+q][col]=acc[g][q]+b;
      }
    } else if (wave==2){
      f32x4 acc[4] = {{0,0,0,0},{0,0,0,0},{0,0,0,0},{0,0,0,0}};
      #pragma unroll
      for (int tk=0;tk<4;tk++){
        bf16x8 a = lda(&hidv_b[0][0],136,tk,lane);
        #pragma unroll
        for (int g=0;g<4;g++) acc[g]=mfma16(a, ldb(wsb+OFF_nvW2,g*4+tk,lane), acc[g]);
      }
      #pragma unroll
      for (int g=0;g<4;g++){
        int col=g*16+cL; float b=p.nvb2[col];
        #pragma unroll
        for (int q=0;q<4;q++) scv[rb+q][col]=acc[g][q]+b;
      }
    } else if (wave==3){
      f32x4 acc = {0,0,0,0};
      #pragma unroll
      for (int tk=0;tk<4;tk++){
        bf16x8 a = lda(&hidat_b[0][0],136,tk,lane);
        acc = mfma16(a, ldb(wsb+OFF_attW2,tk,lane), acc);
      }
      if (cL < 3){
        float b = p.attb2[cL];
        #pragma unroll
        for (int q=0;q<4;q++) attlog[rb+q][cL] = acc[q]+b;
      }
    }
    __syncthreads();

    // ---- D3: 3-way softmax + z update ----
    #pragma unroll
    for (int s=0;s<2;s++){
      int item = tid + s*512;               // 0..1023 = 16 rows x 64
      int r = item>>6, u = item&63;
      float a0=attlog[r][0], a1=attlog[r][1], a2=attlog[r][2];
      float m=fmaxf(a0,fmaxf(a1,a2));
      float e0=__expf(a0-m), e1=__expf(a1-m), e2=__expf(a2-m);
      float inv=1.f/(e0+e1+e2);
      float z=(e0*scl[r][u]+e1*sca[r][u]+e2*scv[r][u])*inv;
      zz32[r][u]=z; zz_b[r][u]=(bf16)z;
    }
    __syncthreads();
  }

  // ---- final MLP (fp32 VALU, once): last=[hl,ha,hv,z](320) -> 128 relu -> 1 ----
  if (wave<2){
    const int j=(wave<<6)+lane;
    float acc[16];
    #pragma unroll
    for (int r=0;r<16;r++) acc[r]=p.outb1[j];
    for (int k=0;k<128;k++){ float wv=p.outW1[k*128+j];
      #pragma unroll
      for (int r=0;r<16;r++) acc[r]=fmaf(hl32[r][k],wv,acc[r]); }
    for (int k=0;k<64;k++){ float wv=p.outW1[(128+k)*128+j];
      #pragma unroll
      for (int r=0;r<16;r++) acc[r]=fmaf(ha32[r][k],wv,acc[r]); }
    for (int k=0;k<64;k++){ float wv=p.outW1[(192+k)*128+j];
      #pragma unroll
      for (int r=0;r<16;r++) acc[r]=fmaf(hv32[r][k],wv,acc[r]); }
    for (int k=0;k<64;k++){ float wv=p.outW1[(256+k)*128+j];
      #pragma unroll
      for (int r=0;r<16;r++) acc[r]=fmaf(zz32[r][k],wv,acc[r]); }
    #pragma unroll
    for (int r=0;r<16;r++) cl32[r][j]=fmaxf(acc[r],0.f);   // reuse as hidden
  }
  __syncthreads();
  if (tid<16){
    float acc=p.outb2[0];
    for (int k=0;k<128;k++) acc=fmaf(cl32[tid][k],p.outW2[k],acc);
    p.out[n0+tid]=acc;
  }
}

// ================= fallback: original fp32 kernel (proven, no-ws path) =================
template<int R,int COLS,int KDIM,int INSTRIDE>
__device__ __forceinline__ void acc_mm(const float* __restrict__ W,
                                       const float* __restrict__ in,
                                       float acc[R], int j)
{
  constexpr int K4 = KDIM/4;
  #pragma unroll 2
  for (int k4=0;k4<K4;k4++){
    const int k=4*k4;
    float w0=W[(k+0)*COLS+j];
    float w1=W[(k+1)*COLS+j];
    float w2=W[(k+2)*COLS+j];
    float w3=W[(k+3)*COLS+j];
    #pragma unroll
    for (int r=0;r<R;r++){
      const float4 v = *(const float4*)(in + r*INSTRIDE + k);
      acc[r]=fmaf(v.w,w3,fmaf(v.z,w2,fmaf(v.y,w1,fmaf(v.x,w0,acc[r]))));
    }
  }
  if constexpr ((KDIM & 3) != 0) {
    #pragma unroll
    for (int k=K4*4;k<KDIM;k++){
      float wv=W[k*COLS+j];
      #pragma unroll
      for (int r=0;r<R;r++) acc[r]=fmaf(in[r*INSTRIDE+k],wv,acc[r]);
    }
  }
}

__global__ __launch_bounds__(THREADS)
void tman_kernel(Params p)
{
  __shared__ float xsl[ROWS][300];
  __shared__ float xsa[ROWS][76];
  __shared__ float xsv[ROWS][36];
  __shared__ float cl[ROWS][128], hl[ROWS][128];
  __shared__ float ca[ROWS][64],  ha[ROWS][64];
  __shared__ float cv[ROWS][64],  hv[ROWS][64];
  __shared__ float zz[ROWS][64];
  __shared__ float sl[ROWS][512];
  __shared__ float sa[ROWS][256];
  __shared__ float sv[ROWS][256];
  __shared__ float hidl[ROWS][128], hida[ROWS][128], hidv[ROWS][128], hidat[ROWS][128];
  __shared__ float scl[ROWS][64], sca[ROWS][64], scv[ROWS][64];
  __shared__ float attlog[ROWS][4];
  __shared__ float bl[512], ba[256], bv[256];

  const int tid  = threadIdx.x;
  const int lane = tid & 63;
  const int wave = tid >> 6;
  const int n0   = blockIdx.x * ROWS;

  for (int i=tid;i<512;i+=THREADS) bl[i]=p.bWl[i]+p.bUl[i]+p.bVl[i];
  for (int i=tid;i<256;i+=THREADS){ ba[i]=p.bWa[i]+p.bUa[i]+p.bVa[i]; bv[i]=p.bWv[i]+p.bUv[i]+p.bVv[i]; }
  for (int i=tid;i<ROWS*128;i+=THREADS){ (&cl[0][0])[i]=0.f; (&hl[0][0])[i]=0.f; }
  for (int i=tid;i<ROWS*64;i+=THREADS){
    (&ca[0][0])[i]=0.f; (&ha[0][0])[i]=0.f;
    (&cv[0][0])[i]=0.f; (&hv[0][0])[i]=0.f;
    (&zz[0][0])[i]=0.f;
  }
  __syncthreads();

  for (int t=0;t<TSTEPS;++t){
    const float* xt = p.x + ((size_t)t*NB + n0)*DXF;
    for (int i=tid;i<ROWS*DXF;i+=THREADS){
      int r=i/DXF, d=i-r*DXF;
      float v=xt[(size_t)r*DXF+d];
      if (d<300) xsl[r][d]=v;
      else if (d<374) xsa[r][d-300]=v;
      else xsv[r][d-374]=v;
    }
    __syncthreads();

    {
      int j = wave*64 + lane;
      float acc[ROWS]; float b=bl[j];
      #pragma unroll
      for (int r=0;r<ROWS;r++) acc[r]=b;
      acc_mm<ROWS,512,300,300>(p.Wl,&xsl[0][0],acc,j);
      acc_mm<ROWS,512,128,128>(p.Ul,&hl[0][0],acc,j);
      acc_mm<ROWS,512, 64, 64>(p.Vl,&zz[0][0],acc,j);
      #pragma unroll
      for (int r=0;r<ROWS;r++) sl[r][j]=acc[r];
    }
    {
      int item = 15-wave;
      if (item>=12){
        int j=(item-12)*64+lane;
        float acc[ROWS]; float b=bv[j];
        #pragma unroll
        for (int r=0;r<ROWS;r++) acc[r]=b;
        acc_mm<ROWS,256,35,36>(p.Wv,&xsv[0][0],acc,j);
        acc_mm<ROWS,256,64,64>(p.Uv,&hv[0][0],acc,j);
        acc_mm<ROWS,256,64,64>(p.Vv,&zz[0][0],acc,j);
        #pragma unroll
        for (int r=0;r<ROWS;r++) sv[r][j]=acc[r];
      } else {
        int j=(item-8)*64+lane;
        float acc[ROWS]; float b=ba[j];
        #pragma unroll
        for (int r=0;r<ROWS;r++) acc[r]=b;
        acc_mm<ROWS,256,74,76>(p.Wa,&xsa[0][0],acc,j);
        acc_mm<ROWS,256,64,64>(p.Ua,&ha[0][0],acc,j);
        acc_mm<ROWS,256,64,64>(p.Va,&zz[0][0],acc,j);
        #pragma unroll
        for (int r=0;r<ROWS;r++) sa[r][j]=acc[r];
      }
    }
    __syncthreads();

    for (int i=tid;i<ROWS*128;i+=THREADS){
      int r=i>>7, u=i&127;
      float f =sigm(sl[r][u]);
      float ig=sigm(sl[r][128+u]);
      float o =sigm(sl[r][256+u]);
      float ch=tanhf(sl[r][384+u]);
      float c=f*cl[r][u]+ig*ch;
      cl[r][u]=c; hl[r][u]=tanhf(c)*o;
    }
    for (int i=tid;i<ROWS*64;i+=THREADS){
      int r=i>>6, u=i&63;
      { float f=sigm(sa[r][u]), ig=sigm(sa[r][64+u]), o=sigm(sa[r][128+u]), ch=tanhf(sa[r][192+u]);
        float c=f*ca[r][u]+ig*ch; ca[r][u]=c; ha[r][u]=tanhf(c)*o; }
      { float f=sigm(sv[r][u]), ig=sigm(sv[r][64+u]), o=sigm(sv[r][128+u]), ch=tanhf(sv[r][192+u]);
        float c=f*cv[r][u]+ig*ch; cv[r][u]=c; hv[r][u]=tanhf(c)*o; }
    }
    __syncthreads();

    if (wave<2){
      int j=wave*64+lane;
      float acc[ROWS]; float b=p.nlb1[j];
      #pragma unroll
      for (int r=0;r<ROWS;r++) acc[r]=b;
      acc_mm<ROWS,128,128,128>(p.nlW1,&cl[0][0],acc,j);
      #pragma unroll
      for (int r=0;r<ROWS;r++) hidl[r][j]=fmaxf(acc[r],0.f);
    } else if (wave<4){
      int j=(wave-2)*64+lane;
      float acc[ROWS]; float b=p.nab1[j];
      #pragma unroll
      for (int r=0;r<ROWS;r++) acc[r]=b;
      acc_mm<ROWS,128,64,64>(p.naW1,&ca[0][0],acc,j);
      #pragma unroll
      for (int r=0;r<ROWS;r++) hida[r][j]=fmaxf(acc[r],0.f);
    } else if (wave<6){
      int j=(wave-4)*64+lane;
      float acc[ROWS]; float b=p.nvb1[j];
      #pragma unroll
      for (int r=0;r<ROWS;r++) acc[r]=b;
      acc_mm<ROWS,128,64,64>(p.nvW1,&cv[0][0],acc,j);
      #pragma unroll
      for (int r=0;r<ROWS;r++) hidv[r][j]=fmaxf(acc[r],0.f);
    } else {
      int j=(wave-6)*64+lane;
      float acc[ROWS]; float b=p.attb1[j];
      #pragma unroll
      for (int r=0;r<ROWS;r++) acc[r]=b;
      acc_mm<ROWS,128,128,128>(p.attW1,          &cl[0][0],acc,j);
      acc_mm<ROWS,128, 64, 64>(p.attW1+128*128,  &ca[0][0],acc,j);
      acc_mm<ROWS,128, 64, 64>(p.attW1+192*128,  &cv[0][0],acc,j);
      #pragma unroll
      for (int r=0;r<ROWS;r++) hidat[r][j]=fmaxf(acc[r],0.f);
    }
    __syncthreads();

    if (wave==0){
      float acc[ROWS]; float b=p.nlb2[lane];
      #pragma unroll
      for (int r=0;r<ROWS;r++) acc[r]=b;
      acc_mm<ROWS,64,128,128>(p.nlW2,&hidl[0][0],acc,lane);
      #pragma unroll
      for (int r=0;r<ROWS;r++) scl[r][lane]=acc[r];
    } else if (wave==1){
      float acc[ROWS]; float b=p.nab2[lane];
      #pragma unroll
      for (int r=0;r<ROWS;r++) acc[r]=b;
      acc_mm<ROWS,64,128,128>(p.naW2,&hida[0][0],acc,lane);
      #pragma unroll
      for (int r=0;r<ROWS;r++) sca[r][lane]=acc[r];
    } else if (wave==2){
      float acc[ROWS]; float b=p.nvb2[lane];
      #pragma unroll
      for (int r=0;r<ROWS;r++) acc[r]=b;
      acc_mm<ROWS,64,128,128>(p.nvW2,&hidv[0][0],acc,lane);
      #pragma unroll
      for (int r=0;r<ROWS;r++) scv[r][lane]=acc[r];
    } else if (wave==3 && lane<ROWS*3){
      int r=lane/3, m=lane-3*r;
      float a=p.attb2[m];
      for (int k=0;k<128;k++) a=fmaf(hidat[r][k],p.attW2[k*3+m],a);
      attlog[r][m]=a;
    }
    __syncthreads();

    for (int i=tid;i<ROWS*64;i+=THREADS){
      int r=i>>6, u=i&63;
      float a0=attlog[r][0], a1=attlog[r][1], a2=attlog[r][2];
      float m=fmaxf(a0,fmaxf(a1,a2));
      float e0=__expf(a0-m), e1=__expf(a1-m), e2=__expf(a2-m);
      float inv=1.f/(e0+e1+e2);
      zz[r][u]=(e0*scl[r][u]+e1*sca[r][u]+e2*scv[r][u])*inv;
    }
    __syncthreads();
  }

  if (wave<2){
    int j=wave*64+lane;
    float acc[ROWS]; float b=p.outb1[j];
    #pragma unroll
    for (int r=0;r<ROWS;r++) acc[r]=b;
    acc_mm<ROWS,128,128,128>(p.outW1,          &hl[0][0],acc,j);
    acc_mm<ROWS,128, 64, 64>(p.outW1+128*128,  &ha[0][0],acc,j);
    acc_mm<ROWS,128, 64, 64>(p.outW1+192*128,  &hv[0][0],acc,j);
    acc_mm<ROWS,128, 64, 64>(p.outW1+256*128,  &zz[0][0],acc,j);
    #pragma unroll
    for (int r=0;r<ROWS;r++) hidl[r][j]=fmaxf(acc[r],0.f);
  }
  __syncthreads();
  if (tid<ROWS){
    float acc=p.outb2[0];
    for (int k=0;k<128;k++) acc=fmaf(hidl[tid][k],p.outW2[k],acc);
    p.out[n0+tid]=acc;
  }
}

extern "C" void kernel_launch(void* const* d_in, const int* in_sizes, int n_in,
                              void* d_out, int out_size, void* d_ws, size_t ws_size,
                              hipStream_t stream) {
  const float* const* f = (const float* const*)d_in;
  Params P;
  P.x  =f[0];
  P.Wl =f[1];  P.bWl=f[2];  P.Ul =f[3];  P.bUl=f[4];  P.Vl =f[5];  P.bVl=f[6];
  P.Wa =f[7];  P.bWa=f[8];  P.Ua =f[9];  P.bUa=f[10]; P.Va =f[11]; P.bVa=f[12];
  P.Wv =f[13]; P.bWv=f[14]; P.Uv =f[15]; P.bUv=f[16]; P.Vv =f[17]; P.bVv=f[18];
  P.nlW1=f[19]; P.nlb1=f[20]; P.nlW2=f[21]; P.nlb2=f[22];
  P.naW1=f[23]; P.nab1=f[24]; P.naW2=f[25]; P.nab2=f[26];
  P.nvW1=f[27]; P.nvb1=f[28]; P.nvW2=f[29]; P.nvb2=f[30];
  P.attW1=f[31]; P.attb1=f[32]; P.attW2=f[33]; P.attb2=f[34];
  P.outW1=f[35]; P.outb1=f[36]; P.outW2=f[37]; P.outb2=f[38];
  P.out=(float*)d_out;
  P.ws =(const float*)d_ws;

  if (ws_size >= (size_t)WS_ELEMS * sizeof(bf16)) {
    bf16* wsb = (bf16*)d_ws;
    struct Pk { const float* src; int off, K, Kp, N, Np; } pk[17] = {
      { f[1],  OFF_Wl,   300, 320, 512, 512 },
      { f[7],  OFF_Wa,    74,  96, 256, 256 },
      { f[13], OFF_Wv,    35,  64, 256, 256 },
      { f[3],  OFF_Ul,   128, 128, 512, 512 },
      { f[5],  OFF_Vl,    64,  64, 512, 512 },
      { f[9],  OFF_Ua,    64,  64, 256, 256 },
      { f[11], OFF_Va,    64,  64, 256, 256 },
      { f[15], OFF_Uv,    64,  64, 256, 256 },
      { f[17], OFF_Vv,    64,  64, 256, 256 },
      { f[19], OFF_nlW1, 128, 128, 128, 128 },
      { f[23], OFF_naW1,  64,  64, 128, 128 },
      { f[27], OFF_nvW1,  64,  64, 128, 128 },
      { f[31], OFF_attW1,256, 256, 128, 128 },
      { f[21], OFF_nlW2, 128, 128,  64,  64 },
      { f[25], OFF_naW2, 128, 128,  64,  64 },
      { f[29], OFF_nvW2, 128, 128,  64,  64 },
      { f[33], OFF_attW2,128, 128,   3,  16 },
    };
    for (int i=0;i<17;i++){
      int total = (pk[i].Np>>4) * (pk[i].Kp>>5) * 64;
      hipLaunchKernelGGL(pack_w, dim3((total+255)/256), dim3(256), 0, stream,
                         pk[i].src, wsb + pk[i].off, pk[i].K, pk[i].Kp, pk[i].N, pk[i].Np);
    }
    hipLaunchKernelGGL(tman_mfma, dim3(NB/MROWS), dim3(512), 0, stream, P);
  } else {
    hipLaunchKernelGGL(tman_kernel, dim3(NB/ROWS), dim3(THREADS), 0, stream, P);
  }
}

// Round 6
// 5014.111 us; speedup vs baseline: 2.7573x; 1.2253x over previous
//
#include <hip/hip_runtime.h>
#include <cmath>

#define ROWS 8          // fallback kernel rows
#define THREADS 512
#define NB 2048
#define TSTEPS 128
#define DXF 409
#define MROWS 16        // MFMA kernel: rows per block

using bf16   = __bf16;
using bf16x8 = __attribute__((ext_vector_type(8))) __bf16;
using f32x4  = __attribute__((ext_vector_type(4))) float;

struct Params {
  const float *x;
  const float *Wl,*bWl,*Ul,*bUl,*Vl,*bVl;
  const float *Wa,*bWa,*Ua,*bUa,*Va,*bVa;
  const float *Wv,*bWv,*Uv,*bUv,*Vv,*bVv;
  const float *nlW1,*nlb1,*nlW2,*nlb2;
  const float *naW1,*nab1,*naW2,*nab2;
  const float *nvW1,*nvb1,*nvW2,*nvb2;
  const float *attW1,*attb1,*attW2,*attb2;
  const float *outW1,*outb1,*outW2,*outb2;
  const float *ws;
  float *out;
};

__device__ __forceinline__ float sigm(float x){ return 1.0f/(1.0f+__expf(-x)); }
__device__ __forceinline__ float ftanh(float x){
  x = fminf(fmaxf(x,-15.f),15.f);
  float e = __expf(2.f*x);
  return (e-1.f)/(e+1.f);
}

// ===== packed-weight offsets (bf16 elements) — layout identical to round 5 (verified) =====
#define OFF_Wl    0
#define OFF_Wa    163840
#define OFF_Wv    188416
#define OFF_Ul    204800
#define OFF_Vl    270336
#define OFF_Ua    303104
#define OFF_Va    319488
#define OFF_Uv    335872
#define OFF_Vv    352256
#define OFF_nlW1  368640
#define OFF_naW1  385024
#define OFF_nvW1  393216
#define OFF_attW1 401408
#define OFF_nlW2  434176
#define OFF_naW2  442368
#define OFF_nvW2  450560
#define OFF_attW2 458752
#define WS_ELEMS  460800

// ================= weight packing: fp32 [Kdim][N] -> bf16 MFMA-B fragments =================
__global__ __launch_bounds__(256)
void pack_w(const float* __restrict__ W, bf16* __restrict__ dst,
            int Kdim, int Kpad, int N, int Npad)
{
  const int nKT = Kpad >> 5;
  const int total = (Npad >> 4) * nKT * 64;
  int idx = blockIdx.x*256 + threadIdx.x;
  if (idx >= total) return;
  int lane = idx & 63;
  int tile = idx >> 6;
  int tn = tile / nKT, tk = tile - tn*nKT;
  int col = (tn<<4) + (lane & 15);
  int k0  = (tk<<5) + ((lane>>4)<<3);
  bf16x8 v;
  #pragma unroll
  for (int i=0;i<8;i++){
    int kr = k0 + i;
    float f = (kr < Kdim && col < N) ? W[(size_t)kr*N + col] : 0.f;
    v[i] = (bf16)f;
  }
  ((bf16x8*)dst)[idx] = v;
}

__device__ __forceinline__ f32x4 mfma16(bf16x8 a, bf16x8 b, f32x4 c){
  return __builtin_amdgcn_mfma_f32_16x16x32_bf16(a, b, c, 0, 0, 0);
}
__device__ __forceinline__ bf16x8 lda(const bf16* buf, int stride, int kt, int lane){
  return *(const bf16x8*)(buf + (lane&15)*stride + (kt<<5) + ((lane>>4)<<3));
}
__device__ __forceinline__ bf16x8 ldb(const bf16* base, int tile, int lane){
  return ((const bf16x8*)base)[tile*64 + lane];
}

// ================= MFMA recurrent kernel, register-persistent weights =================
__global__ __launch_bounds__(512, 2)
void tman_mfma(Params p)
{
  __shared__ float cl32[16][132], hl32[16][132];
  __shared__ float ca32[16][68], ha32[16][68], cv32[16][68], hv32[16][68], zz32[16][68];
  __shared__ float scl[16][68], sca[16][68], scv[16][68];
  __shared__ float attlog[16][4];
  __shared__ float blb[512], bab[256], bvb[256];
  __shared__ __align__(16) bf16 xl_b[16][328];
  __shared__ __align__(16) bf16 xa_b[16][104];
  __shared__ __align__(16) bf16 xv_b[16][72];
  __shared__ __align__(16) bf16 hl_b[16][136], cl_b[16][136];
  __shared__ __align__(16) bf16 ha_b[16][72], hv_b[16][72], ca_b[16][72], cv_b[16][72], zz_b[16][72];
  __shared__ __align__(16) bf16 hidl_b[16][136], hida_b[16][136], hidv_b[16][136], hidat_b[16][136];

  const int tid  = threadIdx.x;
  const int lane = tid & 63;
  const int wave = tid >> 6;
  const int w2   = wave & 3;
  const int rb   = ((lane>>4)<<2);
  const int cL   = lane & 15;
  const int n0   = blockIdx.x * MROWS;
  const bf16* wsb = (const bf16*)p.ws;

  // ---- persistent weight fragments (loaded ONCE; live across the t-loop) ----
  bf16x8 wUl[4][4], wVl[4][2];   // L gates: h-part, z-part
  bf16x8 wU2[4][2], wV2[4][2];   // A gates (waves 0-3) / V gates (waves 4-7)
  bf16x8 wD1[16];                // role-dependent hidden-layer weights
  bf16x8 wD2[16];                // role-dependent second-layer weights
  #pragma unroll
  for (int g=0;g<4;g++){
    #pragma unroll
    for (int tk=0;tk<4;tk++) wUl[g][tk]=ldb(wsb+OFF_Ul,(wave+8*g)*4+tk,lane);
    #pragma unroll
    for (int tk=0;tk<2;tk++) wVl[g][tk]=ldb(wsb+OFF_Vl,(wave+8*g)*2+tk,lane);
  }
  if (wave<4){
    #pragma unroll
    for (int g=0;g<4;g++)
      #pragma unroll
      for (int tk=0;tk<2;tk++){
        wU2[g][tk]=ldb(wsb+OFF_Ua,(w2+4*g)*2+tk,lane);
        wV2[g][tk]=ldb(wsb+OFF_Va,(w2+4*g)*2+tk,lane);
      }
  } else {
    #pragma unroll
    for (int g=0;g<4;g++)
      #pragma unroll
      for (int tk=0;tk<2;tk++){
        wU2[g][tk]=ldb(wsb+OFF_Uv,(w2+4*g)*2+tk,lane);
        wV2[g][tk]=ldb(wsb+OFF_Vv,(w2+4*g)*2+tk,lane);
      }
  }
  if (wave<2){
    #pragma unroll
    for (int g=0;g<4;g++)
      #pragma unroll
      for (int tk=0;tk<4;tk++) wD1[g*4+tk]=ldb(wsb+OFF_nlW1,((wave*4+g)*4+tk),lane);
  } else if (wave==2){
    #pragma unroll
    for (int g=0;g<8;g++)
      #pragma unroll
      for (int tk=0;tk<2;tk++) wD1[g*2+tk]=ldb(wsb+OFF_naW1,g*2+tk,lane);
  } else if (wave==3){
    #pragma unroll
    for (int g=0;g<8;g++)
      #pragma unroll
      for (int tk=0;tk<2;tk++) wD1[g*2+tk]=ldb(wsb+OFF_nvW1,g*2+tk,lane);
  } else {
    #pragma unroll
    for (int g=0;g<2;g++)
      #pragma unroll
      for (int tk=0;tk<8;tk++) wD1[g*8+tk]=ldb(wsb+OFF_attW1,((wave-4)*2+g)*8+tk,lane);
  }
  if (wave==0){
    #pragma unroll
    for (int g=0;g<4;g++)
      #pragma unroll
      for (int tk=0;tk<4;tk++) wD2[g*4+tk]=ldb(wsb+OFF_nlW2,g*4+tk,lane);
  } else if (wave==1){
    #pragma unroll
    for (int g=0;g<4;g++)
      #pragma unroll
      for (int tk=0;tk<4;tk++) wD2[g*4+tk]=ldb(wsb+OFF_naW2,g*4+tk,lane);
  } else if (wave==2){
    #pragma unroll
    for (int g=0;g<4;g++)
      #pragma unroll
      for (int tk=0;tk<4;tk++) wD2[g*4+tk]=ldb(wsb+OFF_nvW2,g*4+tk,lane);
  } else if (wave==3){
    #pragma unroll
    for (int tk=0;tk<4;tk++) wD2[tk]=ldb(wsb+OFF_attW2,tk,lane);
  }

  // ---- init ----
  if (tid < 512) blb[tid] = p.bWl[tid]+p.bUl[tid]+p.bVl[tid];
  if (tid < 256){ bab[tid]=p.bWa[tid]+p.bUa[tid]+p.bVa[tid]; bvb[tid]=p.bWv[tid]+p.bUv[tid]+p.bVv[tid]; }
  for (int i=tid;i<16*132;i+=512){ (&cl32[0][0])[i]=0.f; }
  for (int i=tid;i<16*68;i+=512){ (&ca32[0][0])[i]=0.f; (&cv32[0][0])[i]=0.f; }
  for (int i=tid;i<16*136;i+=512){ (&hl_b[0][0])[i]=(bf16)0.f; }
  for (int i=tid;i<16*72;i+=512){
    (&ha_b[0][0])[i]=(bf16)0.f; (&hv_b[0][0])[i]=(bf16)0.f; (&zz_b[0][0])[i]=(bf16)0.f;
  }
  for (int i=tid;i<16*328;i+=512) (&xl_b[0][0])[i]=(bf16)0.f;
  for (int i=tid;i<16*104;i+=512) (&xa_b[0][0])[i]=(bf16)0.f;
  for (int i=tid;i<16*72;i+=512)  (&xv_b[0][0])[i]=(bf16)0.f;
  __syncthreads();
  { // stage x[0]
    const float* xt = p.x + (size_t)n0*DXF;
    for (int i=tid;i<MROWS*DXF;i+=512){
      int r=i/DXF, d=i-r*DXF;
      bf16 bv = (bf16)xt[(size_t)r*DXF + d];
      if (d<300) xl_b[r][d]=bv;
      else if (d<374) xa_b[r][d-300]=bv;
      else xv_b[r][d-374]=bv;
    }
  }
  __syncthreads();

  for (int t=0;t<TSTEPS;++t){
    // ---- issue x[t+1] prefetch (HBM; lands during this step's compute) ----
    float xp[13];
    const float* xnext = p.x + ((size_t)(t+1)*NB + n0)*DXF;
    if (t+1 < TSTEPS){
      #pragma unroll
      for (int s=0;s<13;s++){
        int i = tid + s*512;
        if (i < MROWS*DXF) xp[s] = xnext[i];
      }
    }

    // ---- phase B: gate pre-activations ----
    f32x4 accL[4] = {{0,0,0,0},{0,0,0,0},{0,0,0,0},{0,0,0,0}};
    f32x4 acc2[4] = {{0,0,0,0},{0,0,0,0},{0,0,0,0},{0,0,0,0}};
    // issue first Wl-x B-frags (depth-3 rolling buffer)
    bf16x8 bw[3][4];
    #pragma unroll
    for (int d=0;d<3;d++)
      #pragma unroll
      for (int g=0;g<4;g++) bw[d][g]=ldb(wsb+OFF_Wl,(wave+8*g)*10+d,lane);
    // L: h-part (register weights) — covers the in-flight loads
    #pragma unroll
    for (int tk=0;tk<4;tk++){
      bf16x8 a = lda(&hl_b[0][0],136,tk,lane);
      #pragma unroll
      for (int g=0;g<4;g++) accL[g]=mfma16(a,wUl[g][tk],accL[g]);
    }
    // L: z-part (register weights)
    #pragma unroll
    for (int tk=0;tk<2;tk++){
      bf16x8 a = lda(&zz_b[0][0],72,tk,lane);
      #pragma unroll
      for (int g=0;g<4;g++) accL[g]=mfma16(a,wVl[g][tk],accL[g]);
    }
    // L: x-part, rolling prefetch
    #pragma unroll
    for (int tk=0;tk<10;tk++){
      bf16x8 a = lda(&xl_b[0][0],328,tk,lane);
      #pragma unroll
      for (int g=0;g<4;g++) accL[g]=mfma16(a,bw[tk%3][g],accL[g]);
      if (tk+3<10){
        #pragma unroll
        for (int g=0;g<4;g++) bw[tk%3][g]=ldb(wsb+OFF_Wl,(wave+8*g)*10+tk+3,lane);
      }
    }
    // A or V gates
    if (wave < 4){
      bf16x8 xw2[12];
      #pragma unroll
      for (int g=0;g<4;g++)
        #pragma unroll
        for (int tk=0;tk<3;tk++) xw2[g*3+tk]=ldb(wsb+OFF_Wa,(w2+4*g)*3+tk,lane);
      #pragma unroll
      for (int tk=0;tk<2;tk++){
        bf16x8 a = lda(&ha_b[0][0],72,tk,lane);
        #pragma unroll
        for (int g=0;g<4;g++) acc2[g]=mfma16(a,wU2[g][tk],acc2[g]);
      }
      #pragma unroll
      for (int tk=0;tk<2;tk++){
        bf16x8 a = lda(&zz_b[0][0],72,tk,lane);
        #pragma unroll
        for (int g=0;g<4;g++) acc2[g]=mfma16(a,wV2[g][tk],acc2[g]);
      }
      #pragma unroll
      for (int tk=0;tk<3;tk++){
        bf16x8 a = lda(&xa_b[0][0],104,tk,lane);
        #pragma unroll
        for (int g=0;g<4;g++) acc2[g]=mfma16(a,xw2[g*3+tk],acc2[g]);
      }
    } else {
      bf16x8 xw2[8];
      #pragma unroll
      for (int g=0;g<4;g++)
        #pragma unroll
        for (int tk=0;tk<2;tk++) xw2[g*2+tk]=ldb(wsb+OFF_Wv,(w2+4*g)*2+tk,lane);
      #pragma unroll
      for (int tk=0;tk<2;tk++){
        bf16x8 a = lda(&hv_b[0][0],72,tk,lane);
        #pragma unroll
        for (int g=0;g<4;g++) acc2[g]=mfma16(a,wU2[g][tk],acc2[g]);
      }
      #pragma unroll
      for (int tk=0;tk<2;tk++){
        bf16x8 a = lda(&zz_b[0][0],72,tk,lane);
        #pragma unroll
        for (int g=0;g<4;g++) acc2[g]=mfma16(a,wV2[g][tk],acc2[g]);
      }
      #pragma unroll
      for (int tk=0;tk<2;tk++){
        bf16x8 a = lda(&xv_b[0][0],72,tk,lane);
        #pragma unroll
        for (int g=0;g<4;g++) acc2[g]=mfma16(a,xw2[g*2+tk],acc2[g]);
      }
    }
    __syncthreads();   // all reads of x/h/z done

    // ---- gate combine (in-register) + x[t+1] LDS write ----
    {
      const int uL = (wave<<4) + cL;
      #pragma unroll
      for (int q=0;q<4;q++){
        int row = rb+q;
        float f = sigm(accL[0][q] + blb[uL]);
        float ig= sigm(accL[1][q] + blb[128+uL]);
        float o = sigm(accL[2][q] + blb[256+uL]);
        float ch= ftanh(accL[3][q] + blb[384+uL]);
        float c = f*cl32[row][uL] + ig*ch;
        float h = ftanh(c)*o;
        cl32[row][uL]=c; hl32[row][uL]=h;
        cl_b[row][uL]=(bf16)c; hl_b[row][uL]=(bf16)h;
      }
      const int u2 = (w2<<4) + cL;
      if (wave<4){
        #pragma unroll
        for (int q=0;q<4;q++){
          int row = rb+q;
          float f = sigm(acc2[0][q] + bab[u2]);
          float ig= sigm(acc2[1][q] + bab[64+u2]);
          float o = sigm(acc2[2][q] + bab[128+u2]);
          float ch= ftanh(acc2[3][q] + bab[192+u2]);
          float c = f*ca32[row][u2] + ig*ch;
          float h = ftanh(c)*o;
          ca32[row][u2]=c; ha32[row][u2]=h;
          ca_b[row][u2]=(bf16)c; ha_b[row][u2]=(bf16)h;
        }
      } else {
        #pragma unroll
        for (int q=0;q<4;q++){
          int row = rb+q;
          float f = sigm(acc2[0][q] + bvb[u2]);
          float ig= sigm(acc2[1][q] + bvb[64+u2]);
          float o = sigm(acc2[2][q] + bvb[128+u2]);
          float ch= ftanh(acc2[3][q] + bvb[192+u2]);
          float c = f*cv32[row][u2] + ig*ch;
          float h = ftanh(c)*o;
          cv32[row][u2]=c; hv32[row][u2]=h;
          cv_b[row][u2]=(bf16)c; hv_b[row][u2]=(bf16)h;
        }
      }
    }
    if (t+1 < TSTEPS){
      #pragma unroll
      for (int s=0;s<13;s++){
        int i = tid + s*512;
        if (i < MROWS*DXF){
          int r=i/DXF, d=i-r*DXF;
          bf16 bv = (bf16)xp[s];
          if (d<300) xl_b[r][d]=bv;
          else if (d<374) xa_b[r][d-300]=bv;
          else xv_b[r][d-374]=bv;
        }
      }
    }
    __syncthreads();

    // ---- D1: hidden layers (register weights) ----
    if (wave<2){
      f32x4 acc[4] = {{0,0,0,0},{0,0,0,0},{0,0,0,0},{0,0,0,0}};
      #pragma unroll
      for (int tk=0;tk<4;tk++){
        bf16x8 a = lda(&cl_b[0][0],136,tk,lane);
        #pragma unroll
        for (int g=0;g<4;g++) acc[g]=mfma16(a,wD1[g*4+tk],acc[g]);
      }
      #pragma unroll
      for (int g=0;g<4;g++){
        int col = ((wave<<2)+g)*16 + cL;
        float b = p.nlb1[col];
        #pragma unroll
        for (int q=0;q<4;q++) hidl_b[rb+q][col] = (bf16)fmaxf(acc[g][q]+b, 0.f);
      }
    } else if (wave==2){
      f32x4 acc[8] = {{0,0,0,0},{0,0,0,0},{0,0,0,0},{0,0,0,0},{0,0,0,0},{0,0,0,0},{0,0,0,0},{0,0,0,0}};
      #pragma unroll
      for (int tk=0;tk<2;tk++){
        bf16x8 a = lda(&ca_b[0][0],72,tk,lane);
        #pragma unroll
        for (int g=0;g<8;g++) acc[g]=mfma16(a,wD1[g*2+tk],acc[g]);
      }
      #pragma unroll
      for (int g=0;g<8;g++){
        int col = g*16 + cL;
        float b = p.nab1[col];
        #pragma unroll
        for (int q=0;q<4;q++) hida_b[rb+q][col] = (bf16)fmaxf(acc[g][q]+b, 0.f);
      }
    } else if (wave==3){
      f32x4 acc[8] = {{0,0,0,0},{0,0,0,0},{0,0,0,0},{0,0,0,0},{0,0,0,0},{0,0,0,0},{0,0,0,0},{0,0,0,0}};
      #pragma unroll
      for (int tk=0;tk<2;tk++){
        bf16x8 a = lda(&cv_b[0][0],72,tk,lane);
        #pragma unroll
        for (int g=0;g<8;g++) acc[g]=mfma16(a,wD1[g*2+tk],acc[g]);
      }
      #pragma unroll
      for (int g=0;g<8;g++){
        int col = g*16 + cL;
        float b = p.nvb1[col];
        #pragma unroll
        for (int q=0;q<4;q++) hidv_b[rb+q][col] = (bf16)fmaxf(acc[g][q]+b, 0.f);
      }
    } else {
      f32x4 acc[2] = {{0,0,0,0},{0,0,0,0}};
      #pragma unroll
      for (int tk=0;tk<8;tk++){
        bf16x8 a = (tk<4) ? lda(&cl_b[0][0],136,tk,lane)
                 : (tk<6) ? lda(&ca_b[0][0],72,tk-4,lane)
                          : lda(&cv_b[0][0],72,tk-6,lane);
        #pragma unroll
        for (int g=0;g<2;g++) acc[g]=mfma16(a,wD1[g*8+tk],acc[g]);
      }
      #pragma unroll
      for (int g=0;g<2;g++){
        int col = (((wave-4)<<1)+g)*16 + cL;
        float b = p.attb1[col];
        #pragma unroll
        for (int q=0;q<4;q++) hidat_b[rb+q][col] = (bf16)fmaxf(acc[g][q]+b, 0.f);
      }
    }
    __syncthreads();

    // ---- D2: second layers (register weights) ----
    if (wave==0){
      f32x4 acc[4] = {{0,0,0,0},{0,0,0,0},{0,0,0,0},{0,0,0,0}};
      #pragma unroll
      for (int tk=0;tk<4;tk++){
        bf16x8 a = lda(&hidl_b[0][0],136,tk,lane);
        #pragma unroll
        for (int g=0;g<4;g++) acc[g]=mfma16(a,wD2[g*4+tk],acc[g]);
      }
      #pragma unroll
      for (int g=0;g<4;g++){
        int col=g*16+cL; float b=p.nlb2[col];
        #pragma unroll
        for (int q=0;q<4;q++) scl[rb+q][col]=acc[g][q]+b;
      }
    } else if (wave==1){
      f32x4 acc[4] = {{0,0,0,0},{0,0,0,0},{0,0,0,0},{0,0,0,0}};
      #pragma unroll
      for (int tk=0;tk<4;tk++){
        bf16x8 a = lda(&hida_b[0][0],136,tk,lane);
        #pragma unroll
        for (int g=0;g<4;g++) acc[g]=mfma16(a,wD2[g*4+tk],acc[g]);
      }
      #pragma unroll
      for (int g=0;g<4;g++){
        int col=g*16+cL; float b=p.nab2[col];
        #pragma unroll
        for (int q=0;q<4;q++) sca[rb+q][col]=acc[g][q]+b;
      }
    } else if (wave==2){
      f32x4 acc[4] = {{0,0,0,0},{0,0,0,0},{0,0,0,0},{0,0,0,0}};
      #pragma unroll
      for (int tk=0;tk<4;tk++){
        bf16x8 a = lda(&hidv_b[0][0],136,tk,lane);
        #pragma unroll
        for (int g=0;g<4;g++) acc[g]=mfma16(a,wD2[g*4+tk],acc[g]);
      }
      #pragma unroll
      for (int g=0;g<4;g++){
        int col=g*16+cL; float b=p.nvb2[col];
        #pragma unroll
        for (int q=0;q<4;q++) scv[rb+q][col]=acc[g][q]+b;
      }
    } else if (wave==3){
      f32x4 acc = {0,0,0,0};
      #pragma unroll
      for (int tk=0;tk<4;tk++){
        bf16x8 a = lda(&hidat_b[0][0],136,tk,lane);
        acc = mfma16(a,wD2[tk],acc);
      }
      if (cL < 3){
        float b = p.attb2[cL];
        #pragma unroll
        for (int q=0;q<4;q++) attlog[rb+q][cL] = acc[q]+b;
      }
    }
    __syncthreads();

    // ---- D3: 3-way softmax + z update ----
    #pragma unroll
    for (int s=0;s<2;s++){
      int item = tid + s*512;
      int r = item>>6, u = item&63;
      float a0=attlog[r][0], a1=attlog[r][1], a2=attlog[r][2];
      float m=fmaxf(a0,fmaxf(a1,a2));
      float e0=__expf(a0-m), e1=__expf(a1-m), e2=__expf(a2-m);
      float inv=1.f/(e0+e1+e2);
      float z=(e0*scl[r][u]+e1*sca[r][u]+e2*scv[r][u])*inv;
      zz32[r][u]=z; zz_b[r][u]=(bf16)z;
    }
    __syncthreads();
  }

  // ---- final MLP (fp32, once) ----
  if (wave<2){
    const int j=(wave<<6)+lane;
    float acc[16];
    #pragma unroll
    for (int r=0;r<16;r++) acc[r]=p.outb1[j];
    for (int k=0;k<128;k++){ float wv=p.outW1[k*128+j];
      #pragma unroll
      for (int r=0;r<16;r++) acc[r]=fmaf(hl32[r][k],wv,acc[r]); }
    for (int k=0;k<64;k++){ float wv=p.outW1[(128+k)*128+j];
      #pragma unroll
      for (int r=0;r<16;r++) acc[r]=fmaf(ha32[r][k],wv,acc[r]); }
    for (int k=0;k<64;k++){ float wv=p.outW1[(192+k)*128+j];
      #pragma unroll
      for (int r=0;r<16;r++) acc[r]=fmaf(hv32[r][k],wv,acc[r]); }
    for (int k=0;k<64;k++){ float wv=p.outW1[(256+k)*128+j];
      #pragma unroll
      for (int r=0;r<16;r++) acc[r]=fmaf(zz32[r][k],wv,acc[r]); }
    #pragma unroll
    for (int r=0;r<16;r++) cl32[r][j]=fmaxf(acc[r],0.f);
  }
  __syncthreads();
  if (tid<16){
    float acc=p.outb2[0];
    for (int k=0;k<128;k++) acc=fmaf(cl32[tid][k],p.outW2[k],acc);
    p.out[n0+tid]=acc;
  }
}

// ================= fallback: original fp32 kernel (proven, no-ws path) =================
template<int R,int COLS,int KDIM,int INSTRIDE>
__device__ __forceinline__ void acc_mm(const float* __restrict__ W,
                                       const float* __restrict__ in,
                                       float acc[R], int j)
{
  constexpr int K4 = KDIM/4;
  #pragma unroll 2
  for (int k4=0;k4<K4;k4++){
    const int k=4*k4;
    float w0=W[(k+0)*COLS+j];
    float w1=W[(k+1)*COLS+j];
    float w2=W[(k+2)*COLS+j];
    float w3=W[(k+3)*COLS+j];
    #pragma unroll
    for (int r=0;r<R;r++){
      const float4 v = *(const float4*)(in + r*INSTRIDE + k);
      acc[r]=fmaf(v.w,w3,fmaf(v.z,w2,fmaf(v.y,w1,fmaf(v.x,w0,acc[r]))));
    }
  }
  if constexpr ((KDIM & 3) != 0) {
    #pragma unroll
    for (int k=K4*4;k<KDIM;k++){
      float wv=W[k*COLS+j];
      #pragma unroll
      for (int r=0;r<R;r++) acc[r]=fmaf(in[r*INSTRIDE+k],wv,acc[r]);
    }
  }
}

__global__ __launch_bounds__(THREADS)
void tman_kernel(Params p)
{
  __shared__ float xsl[ROWS][300];
  __shared__ float xsa[ROWS][76];
  __shared__ float xsv[ROWS][36];
  __shared__ float cl[ROWS][128], hl[ROWS][128];
  __shared__ float ca[ROWS][64],  ha[ROWS][64];
  __shared__ float cv[ROWS][64],  hv[ROWS][64];
  __shared__ float zz[ROWS][64];
  __shared__ float sl[ROWS][512];
  __shared__ float sa[ROWS][256];
  __shared__ float sv[ROWS][256];
  __shared__ float hidl[ROWS][128], hida[ROWS][128], hidv[ROWS][128], hidat[ROWS][128];
  __shared__ float scl[ROWS][64], sca[ROWS][64], scv[ROWS][64];
  __shared__ float attlog[ROWS][4];
  __shared__ float bl[512], ba[256], bv[256];

  const int tid  = threadIdx.x;
  const int lane = tid & 63;
  const int wave = tid >> 6;
  const int n0   = blockIdx.x * ROWS;

  for (int i=tid;i<512;i+=THREADS) bl[i]=p.bWl[i]+p.bUl[i]+p.bVl[i];
  for (int i=tid;i<256;i+=THREADS){ ba[i]=p.bWa[i]+p.bUa[i]+p.bVa[i]; bv[i]=p.bWv[i]+p.bUv[i]+p.bVv[i]; }
  for (int i=tid;i<ROWS*128;i+=THREADS){ (&cl[0][0])[i]=0.f; (&hl[0][0])[i]=0.f; }
  for (int i=tid;i<ROWS*64;i+=THREADS){
    (&ca[0][0])[i]=0.f; (&ha[0][0])[i]=0.f;
    (&cv[0][0])[i]=0.f; (&hv[0][0])[i]=0.f;
    (&zz[0][0])[i]=0.f;
  }
  __syncthreads();

  for (int t=0;t<TSTEPS;++t){
    const float* xt = p.x + ((size_t)t*NB + n0)*DXF;
    for (int i=tid;i<ROWS*DXF;i+=THREADS){
      int r=i/DXF, d=i-r*DXF;
      float v=xt[(size_t)r*DXF+d];
      if (d<300) xsl[r][d]=v;
      else if (d<374) xsa[r][d-300]=v;
      else xsv[r][d-374]=v;
    }
    __syncthreads();

    {
      int j = wave*64 + lane;
      float acc[ROWS]; float b=bl[j];
      #pragma unroll
      for (int r=0;r<ROWS;r++) acc[r]=b;
      acc_mm<ROWS,512,300,300>(p.Wl,&xsl[0][0],acc,j);
      acc_mm<ROWS,512,128,128>(p.Ul,&hl[0][0],acc,j);
      acc_mm<ROWS,512, 64, 64>(p.Vl,&zz[0][0],acc,j);
      #pragma unroll
      for (int r=0;r<ROWS;r++) sl[r][j]=acc[r];
    }
    {
      int item = 15-wave;
      if (item>=12){
        int j=(item-12)*64+lane;
        float acc[ROWS]; float b=bv[j];
        #pragma unroll
        for (int r=0;r<ROWS;r++) acc[r]=b;
        acc_mm<ROWS,256,35,36>(p.Wv,&xsv[0][0],acc,j);
        acc_mm<ROWS,256,64,64>(p.Uv,&hv[0][0],acc,j);
        acc_mm<ROWS,256,64,64>(p.Vv,&zz[0][0],acc,j);
        #pragma unroll
        for (int r=0;r<ROWS;r++) sv[r][j]=acc[r];
      } else {
        int j=(item-8)*64+lane;
        float acc[ROWS]; float b=ba[j];
        #pragma unroll
        for (int r=0;r<ROWS;r++) acc[r]=b;
        acc_mm<ROWS,256,74,76>(p.Wa,&xsa[0][0],acc,j);
        acc_mm<ROWS,256,64,64>(p.Ua,&ha[0][0],acc,j);
        acc_mm<ROWS,256,64,64>(p.Va,&zz[0][0],acc,j);
        #pragma unroll
        for (int r=0;r<ROWS;r++) sa[r][j]=acc[r];
      }
    }
    __syncthreads();

    for (int i=tid;i<ROWS*128;i+=THREADS){
      int r=i>>7, u=i&127;
      float f =sigm(sl[r][u]);
      float ig=sigm(sl[r][128+u]);
      float o =sigm(sl[r][256+u]);
      float ch=tanhf(sl[r][384+u]);
      float c=f*cl[r][u]+ig*ch;
      cl[r][u]=c; hl[r][u]=tanhf(c)*o;
    }
    for (int i=tid;i<ROWS*64;i+=THREADS){
      int r=i>>6, u=i&63;
      { float f=sigm(sa[r][u]), ig=sigm(sa[r][64+u]), o=sigm(sa[r][128+u]), ch=tanhf(sa[r][192+u]);
        float c=f*ca[r][u]+ig*ch; ca[r][u]=c; ha[r][u]=tanhf(c)*o; }
      { float f=sigm(sv[r][u]), ig=sigm(sv[r][64+u]), o=sigm(sv[r][128+u]), ch=tanhf(sv[r][192+u]);
        float c=f*cv[r][u]+ig*ch; cv[r][u]=c; hv[r][u]=tanhf(c)*o; }
    }
    __syncthreads();

    if (wave<2){
      int j=wave*64+lane;
      float acc[ROWS]; float b=p.nlb1[j];
      #pragma unroll
      for (int r=0;r<ROWS;r++) acc[r]=b;
      acc_mm<ROWS,128,128,128>(p.nlW1,&cl[0][0],acc,j);
      #pragma unroll
      for (int r=0;r<ROWS;r++) hidl[r][j]=fmaxf(acc[r],0.f);
    } else if (wave<4){
      int j=(wave-2)*64+lane;
      float acc[ROWS]; float b=p.nab1[j];
      #pragma unroll
      for (int r=0;r<ROWS;r++) acc[r]=b;
      acc_mm<ROWS,128,64,64>(p.naW1,&ca[0][0],acc,j);
      #pragma unroll
      for (int r=0;r<ROWS;r++) hida[r][j]=fmaxf(acc[r],0.f);
    } else if (wave<6){
      int j=(wave-4)*64+lane;
      float acc[ROWS]; float b=p.nvb1[j];
      #pragma unroll
      for (int r=0;r<ROWS;r++) acc[r]=b;
      acc_mm<ROWS,128,64,64>(p.nvW1,&cv[0][0],acc,j);
      #pragma unroll
      for (int r=0;r<ROWS;r++) hidv[r][j]=fmaxf(acc[r],0.f);
    } else {
      int j=(wave-6)*64+lane;
      float acc[ROWS]; float b=p.attb1[j];
      #pragma unroll
      for (int r=0;r<ROWS;r++) acc[r]=b;
      acc_mm<ROWS,128,128,128>(p.attW1,          &cl[0][0],acc,j);
      acc_mm<ROWS,128, 64, 64>(p.attW1+128*128,  &ca[0][0],acc,j);
      acc_mm<ROWS,128, 64, 64>(p.attW1+192*128,  &cv[0][0],acc,j);
      #pragma unroll
      for (int r=0;r<ROWS;r++) hidat[r][j]=fmaxf(acc[r],0.f);
    }
    __syncthreads();

    if (wave==0){
      float acc[ROWS]; float b=p.nlb2[lane];
      #pragma unroll
      for (int r=0;r<ROWS;r++) acc[r]=b;
      acc_mm<ROWS,64,128,128>(p.nlW2,&hidl[0][0],acc,lane);
      #pragma unroll
      for (int r=0;r<ROWS;r++) scl[r][lane]=acc[r];
    } else if (wave==1){
      float acc[ROWS]; float b=p.nab2[lane];
      #pragma unroll
      for (int r=0;r<ROWS;r++) acc[r]=b;
      acc_mm<ROWS,64,128,128>(p.naW2,&hida[0][0],acc,lane);
      #pragma unroll
      for (int r=0;r<ROWS;r++) sca[r][lane]=acc[r];
    } else if (wave==2){
      float acc[ROWS]; float b=p.nvb2[lane];
      #pragma unroll
      for (int r=0;r<ROWS;r++) acc[r]=b;
      acc_mm<ROWS,64,128,128>(p.nvW2,&hidv[0][0],acc,lane);
      #pragma unroll
      for (int r=0;r<ROWS;r++) scv[r][lane]=acc[r];
    } else if (wave==3 && lane<ROWS*3){
      int r=lane/3, m=lane-3*r;
      float a=p.attb2[m];
      for (int k=0;k<128;k++) a=fmaf(hidat[r][k],p.attW2[k*3+m],a);
      attlog[r][m]=a;
    }
    __syncthreads();

    for (int i=tid;i<ROWS*64;i+=THREADS){
      int r=i>>6, u=i&63;
      float a0=attlog[r][0], a1=attlog[r][1], a2=attlog[r][2];
      float m=fmaxf(a0,fmaxf(a1,a2));
      float e0=__expf(a0-m), e1=__expf(a1-m), e2=__expf(a2-m);
      float inv=1.f/(e0+e1+e2);
      zz[r][u]=(e0*scl[r][u]+e1*sca[r][u]+e2*scv[r][u])*inv;
    }
    __syncthreads();
  }

  if (wave<2){
    int j=wave*64+lane;
    float acc[ROWS]; float b=p.outb1[j];
    #pragma unroll
    for (int r=0;r<ROWS;r++) acc[r]=b;
    acc_mm<ROWS,128,128,128>(p.outW1,          &hl[0][0],acc,j);
    acc_mm<ROWS,128, 64, 64>(p.outW1+128*128,  &ha[0][0],acc,j);
    acc_mm<ROWS,128, 64, 64>(p.outW1+192*128,  &hv[0][0],acc,j);
    acc_mm<ROWS,128, 64, 64>(p.outW1+256*128,  &zz[0][0],acc,j);
    #pragma unroll
    for (int r=0;r<ROWS;r++) hidl[r][j]=fmaxf(acc[r],0.f);
  }
  __syncthreads();
  if (tid<ROWS){
    float acc=p.outb2[0];
    for (int k=0;k<128;k++) acc=fmaf(hidl[tid][k],p.outW2[k],acc);
    p.out[n0+tid]=acc;
  }
}

extern "C" void kernel_launch(void* const* d_in, const int* in_sizes, int n_in,
                              void* d_out, int out_size, void* d_ws, size_t ws_size,
                              hipStream_t stream) {
  const float* const* f = (const float* const*)d_in;
  Params P;
  P.x  =f[0];
  P.Wl =f[1];  P.bWl=f[2];  P.Ul =f[3];  P.bUl=f[4];  P.Vl =f[5];  P.bVl=f[6];
  P.Wa =f[7];  P.bWa=f[8];  P.Ua =f[9];  P.bUa=f[10]; P.Va =f[11]; P.bVa=f[12];
  P.Wv =f[13]; P.bWv=f[14]; P.Uv =f[15]; P.bUv=f[16]; P.Vv =f[17]; P.bVv=f[18];
  P.nlW1=f[19]; P.nlb1=f[20]; P.nlW2=f[21]; P.nlb2=f[22];
  P.naW1=f[23]; P.nab1=f[24]; P.naW2=f[25]; P.nab2=f[26];
  P.nvW1=f[27]; P.nvb1=f[28]; P.nvW2=f[29]; P.nvb2=f[30];
  P.attW1=f[31]; P.attb1=f[32]; P.attW2=f[33]; P.attb2=f[34];
  P.outW1=f[35]; P.outb1=f[36]; P.outW2=f[37]; P.outb2=f[38];
  P.out=(float*)d_out;
  P.ws =(const float*)d_ws;

  if (ws_size >= (size_t)WS_ELEMS * sizeof(bf16)) {
    bf16* wsb = (bf16*)d_ws;
    struct Pk { const float* src; int off, K, Kp, N, Np; } pk[17] = {
      { f[1],  OFF_Wl,   300, 320, 512, 512 },
      { f[7],  OFF_Wa,    74,  96, 256, 256 },
      { f[13], OFF_Wv,    35,  64, 256, 256 },
      { f[3],  OFF_Ul,   128, 128, 512, 512 },
      { f[5],  OFF_Vl,    64,  64, 512, 512 },
      { f[9],  OFF_Ua,    64,  64, 256, 256 },
      { f[11], OFF_Va,    64,  64, 256, 256 },
      { f[15], OFF_Uv,    64,  64, 256, 256 },
      { f[17], OFF_Vv,    64,  64, 256, 256 },
      { f[19], OFF_nlW1, 128, 128, 128, 128 },
      { f[23], OFF_naW1,  64,  64, 128, 128 },
      { f[27], OFF_nvW1,  64,  64, 128, 128 },
      { f[31], OFF_attW1,256, 256, 128, 128 },
      { f[21], OFF_nlW2, 128, 128,  64,  64 },
      { f[25], OFF_naW2, 128, 128,  64,  64 },
      { f[29], OFF_nvW2, 128, 128,  64,  64 },
      { f[33], OFF_attW2,128, 128,   3,  16 },
    };
    for (int i=0;i<17;i++){
      int total = (pk[i].Np>>4) * (pk[i].Kp>>5) * 64;
      hipLaunchKernelGGL(pack_w, dim3((total+255)/256), dim3(256), 0, stream,
                         pk[i].src, wsb + pk[i].off, pk[i].K, pk[i].Kp, pk[i].N, pk[i].Np);
    }
    hipLaunchKernelGGL(tman_mfma, dim3(NB/MROWS), dim3(512), 0, stream, P);
  } else {
    hipLaunchKernelGGL(tman_kernel, dim3(NB/ROWS), dim3(THREADS), 0, stream, P);
  }
}

// Round 7
// 2936.640 us; speedup vs baseline: 4.7079x; 1.7074x over previous
//
#include <hip/hip_runtime.h>
#include <cmath>

#define ROWS 8
#define THREADS 512
#define NB 2048
#define TSTEPS 128
#define DXF 409
#define MROWS 16

using bf16   = __bf16;
using bf16x8 = __attribute__((ext_vector_type(8))) __bf16;
using bf16x4 = __attribute__((ext_vector_type(4))) __bf16;
using f32x4  = __attribute__((ext_vector_type(4))) float;

struct Params {
  const float *x;
  const float *Wl,*bWl,*Ul,*bUl,*Vl,*bVl;
  const float *Wa,*bWa,*Ua,*bUa,*Va,*bVa;
  const float *Wv,*bWv,*Uv,*bUv,*Vv,*bVv;
  const float *nlW1,*nlb1,*nlW2,*nlb2;
  const float *naW1,*nab1,*naW2,*nab2;
  const float *nvW1,*nvb1,*nvW2,*nvb2;
  const float *attW1,*attb1,*attW2,*attb2;
  const float *outW1,*outb1,*outW2,*outb2;
  const float *ws;
  float *out;
};

__device__ __forceinline__ float sigm(float x){ return 1.0f/(1.0f+__expf(-x)); }
__device__ __forceinline__ float ftanh(float x){
  x = fminf(fmaxf(x,-15.f),15.f);
  float e = __expf(2.f*x);
  return (e-1.f)/(e+1.f);
}

// ===== packed-weight offsets (bf16 elements) — layout verified in round 5 =====
#define OFF_Wl    0
#define OFF_Wa    163840
#define OFF_Wv    188416
#define OFF_Ul    204800
#define OFF_Vl    270336
#define OFF_Ua    303104
#define OFF_Va    319488
#define OFF_Uv    335872
#define OFF_Vv    352256
#define OFF_nlW1  368640
#define OFF_naW1  385024
#define OFF_nvW1  393216
#define OFF_attW1 401408
#define OFF_nlW2  434176
#define OFF_naW2  442368
#define OFF_nvW2  450560
#define OFF_attW2 458752
#define WS_ELEMS  460800
#define XWF_OFF   460800              // xw fragment file starts here (bf16 elems)
#define XWF_ELEMS ((size_t)16384*64*64*4)

__global__ __launch_bounds__(256)
void pack_w(const float* __restrict__ W, bf16* __restrict__ dst,
            int Kdim, int Kpad, int N, int Npad)
{
  const int nKT = Kpad >> 5;
  const int total = (Npad >> 4) * nKT * 64;
  int idx = blockIdx.x*256 + threadIdx.x;
  if (idx >= total) return;
  int lane = idx & 63;
  int tile = idx >> 6;
  int tn = tile / nKT, tk = tile - tn*nKT;
  int col = (tn<<4) + (lane & 15);
  int k0  = (tk<<5) + ((lane>>4)<<3);
  bf16x8 v;
  #pragma unroll
  for (int i=0;i<8;i++){
    int kr = k0 + i;
    float f = (kr < Kdim && col < N) ? W[(size_t)kr*N + col] : 0.f;
    v[i] = (bf16)f;
  }
  ((bf16x8*)dst)[idx] = v;
}

__device__ __forceinline__ f32x4 mfma16(bf16x8 a, bf16x8 b, f32x4 c){
  return __builtin_amdgcn_mfma_f32_16x16x32_bf16(a, b, c, 0, 0, 0);
}
__device__ __forceinline__ bf16x8 lda(const bf16* buf, int stride, int kt, int lane){
  return *(const bf16x8*)(buf + (lane&15)*stride + (kt<<5) + ((lane>>4)<<3));
}
__device__ __forceinline__ bf16x8 ldb(const bf16* base, int tile, int lane){
  return ((const bf16x8*)base)[tile*64 + lane];
}

// ================= XW GEMM (MFMA): xwf[mt][nt][lane][q] = (x @ [Wl|Wa|Wv]) fragments =================
__global__ __launch_bounds__(256)
void xw_gemm_mfma(const float* __restrict__ x, const bf16* __restrict__ wsb,
                  bf16* __restrict__ xwf)
{
  __shared__ __align__(16) bf16 axl[64][324];   // x cols 0..299 (+pad zeros to 320)
  __shared__ __align__(16) bf16 axa[64][104];   // cols 300..373 (+pad to 96)
  __shared__ __align__(16) bf16 axv[64][72];    // cols 374..408 (+pad to 64)
  const int tid=threadIdx.x, lane=tid&63, wave=tid>>6;
  const int m0 = blockIdx.x * 64;

  for (int i=tid;i<64*324;i+=256) (&axl[0][0])[i]=(bf16)0.f;
  for (int i=tid;i<64*104;i+=256) (&axa[0][0])[i]=(bf16)0.f;
  for (int i=tid;i<64*72;i+=256)  (&axv[0][0])[i]=(bf16)0.f;
  __syncthreads();
  for (int i=tid;i<64*DXF;i+=256){
    int r=i/DXF, d=i-r*DXF;
    bf16 v = (bf16)x[(size_t)(m0+r)*DXF + d];
    if (d<300) axl[r][d]=v;
    else if (d<374) axa[r][d-300]=v;
    else axv[r][d-374]=v;
  }
  __syncthreads();

  const size_t mt = (size_t)blockIdx.x*4 + wave;
  const int r0 = ((wave<<4) + (lane&15));
  const int k8 = ((lane>>4)<<3);

  // L region: nt 0..31, 10 k-tiles
  for (int nt=0;nt<32;nt++){
    f32x4 acc = {0,0,0,0};
    #pragma unroll
    for (int kt=0;kt<10;kt++){
      bf16x8 a = *(const bf16x8*)(&axl[r0][(kt<<5)+k8]);
      acc = mfma16(a, ldb(wsb+OFF_Wl, nt*10+kt, lane), acc);
    }
    bf16x4 o;
    #pragma unroll
    for (int q=0;q<4;q++) o[q]=(bf16)acc[q];
    *(bf16x4*)(xwf + ((mt*64 + nt)*64 + lane)*4) = o;
  }
  // A region: nt 32..47, 3 k-tiles
  for (int tn=0;tn<16;tn++){
    f32x4 acc = {0,0,0,0};
    #pragma unroll
    for (int kt=0;kt<3;kt++){
      bf16x8 a = *(const bf16x8*)(&axa[r0][(kt<<5)+k8]);
      acc = mfma16(a, ldb(wsb+OFF_Wa, tn*3+kt, lane), acc);
    }
    bf16x4 o;
    #pragma unroll
    for (int q=0;q<4;q++) o[q]=(bf16)acc[q];
    *(bf16x4*)(xwf + ((mt*64 + 32 + tn)*64 + lane)*4) = o;
  }
  // V region: nt 48..63, 2 k-tiles
  for (int tn=0;tn<16;tn++){
    f32x4 acc = {0,0,0,0};
    #pragma unroll
    for (int kt=0;kt<2;kt++){
      bf16x8 a = *(const bf16x8*)(&axv[r0][(kt<<5)+k8]);
      acc = mfma16(a, ldb(wsb+OFF_Wv, tn*2+kt, lane), acc);
    }
    bf16x4 o;
    #pragma unroll
    for (int q=0;q<4;q++) o[q]=(bf16)acc[q];
    *(bf16x4*)(xwf + ((mt*64 + 48 + tn)*64 + lane)*4) = o;
  }
}

// ================= recurrent kernel: 256 threads (4 waves, 1/SIMD -> 512 VGPR cap) =================
__global__ __launch_bounds__(256, 1)
void tman_mfma2(Params p)
{
  __shared__ float cl32[16][132], hl32[16][132];
  __shared__ float ca32[16][68], ha32[16][68], cv32[16][68], hv32[16][68], zz32[16][68];
  __shared__ float scl[16][68], sca[16][68], scv[16][68];
  __shared__ float attlog[16][4];
  __shared__ float blb[512], bab[256], bvb[256];
  __shared__ float b_nl1[128], b_na1[128], b_nv1[128], b_at1[128];
  __shared__ float b_nl2[64], b_na2[64], b_nv2[64], b_at2[4];
  __shared__ __align__(16) bf16 hl_b[16][136], cl_b[16][136];
  __shared__ __align__(16) bf16 ha_b[16][72], hv_b[16][72], ca_b[16][72], cv_b[16][72], zz_b[16][72];
  __shared__ __align__(16) bf16 hidl_b[16][136], hida_b[16][136], hidv_b[16][136], hidat_b[16][136];
  __shared__ __align__(16) bf16 w2lds[26624];   // nlW2 | naW2 | nvW2 | attW2 fragments

  const int tid=threadIdx.x, lane=tid&63, wave=tid>>6;
  const int rb=((lane>>4)<<2), cL=lane&15;
  const int n0=blockIdx.x*MROWS;
  const bf16* wsb=(const bf16*)p.ws;
  const bf16* xwf=wsb + XWF_OFF;

  // biases + D2 weights to LDS
  for (int i=tid;i<512;i+=256) blb[i]=p.bWl[i]+p.bUl[i]+p.bVl[i];
  if (tid<256){ bab[tid]=p.bWa[tid]+p.bUa[tid]+p.bVa[tid]; bvb[tid]=p.bWv[tid]+p.bUv[tid]+p.bVv[tid]; }
  if (tid<128){ b_nl1[tid]=p.nlb1[tid]; b_na1[tid]=p.nab1[tid]; b_nv1[tid]=p.nvb1[tid]; b_at1[tid]=p.attb1[tid]; }
  if (tid<64){ b_nl2[tid]=p.nlb2[tid]; b_na2[tid]=p.nab2[tid]; b_nv2[tid]=p.nvb2[tid]; }
  if (tid<4) b_at2[tid] = (tid<3) ? p.attb2[tid] : 0.f;
  for (int i=tid;i<8192;i+=256){
    w2lds[i]        = wsb[OFF_nlW2+i];
    w2lds[8192+i]   = wsb[OFF_naW2+i];
    w2lds[16384+i]  = wsb[OFF_nvW2+i];
  }
  for (int i=tid;i<2048;i+=256) w2lds[24576+i] = wsb[OFF_attW2+i];
  // zero state
  for (int i=tid;i<16*132;i+=256) (&cl32[0][0])[i]=0.f;
  for (int i=tid;i<16*68;i+=256){ (&ca32[0][0])[i]=0.f; (&cv32[0][0])[i]=0.f; }
  for (int i=tid;i<16*136;i+=256) (&hl_b[0][0])[i]=(bf16)0.f;
  for (int i=tid;i<16*72;i+=256){ (&ha_b[0][0])[i]=(bf16)0.f; (&hv_b[0][0])[i]=(bf16)0.f; (&zz_b[0][0])[i]=(bf16)0.f; }

  // ---- persistent gate weights (256 regs/wave target) ----
  bf16x8 wUl[4][2][4];   // L h-part
  bf16x8 wVl[4][2][2];   // L z-part
  bf16x8 wU2[4][2][2];   // A (waves 0-1) / V (waves 2-3) h-part
  #pragma unroll
  for (int g=0;g<4;g++)
    #pragma unroll
    for (int s=0;s<2;s++){
      int nt = g*8 + wave*2 + s;
      #pragma unroll
      for (int kt=0;kt<4;kt++) wUl[g][s][kt]=ldb(wsb+OFF_Ul, nt*4+kt, lane);
      #pragma unroll
      for (int kt=0;kt<2;kt++) wVl[g][s][kt]=ldb(wsb+OFF_Vl, nt*2+kt, lane);
    }
  {
    const int woff = (wave<2) ? wave*2 : (wave-2)*2;
    const int uoff = (wave<2) ? OFF_Ua : OFF_Uv;
    #pragma unroll
    for (int g=0;g<4;g++)
      #pragma unroll
      for (int s=0;s<2;s++){
        int tn = g*4 + woff + s;
        #pragma unroll
        for (int kt=0;kt<2;kt++) wU2[g][s][kt]=ldb(wsb+uoff, tn*2+kt, lane);
      }
  }
  // streamed: A/V z-part weights (reloaded each step, prologue load here)
  bf16x8 wV2s[4][2][2];
  {
    const int woff = (wave<2) ? wave*2 : (wave-2)*2;
    const int voff = (wave<2) ? OFF_Va : OFF_Vv;
    #pragma unroll
    for (int g=0;g<4;g++)
      #pragma unroll
      for (int s=0;s<2;s++){
        int tn = g*4 + woff + s;
        #pragma unroll
        for (int kt=0;kt<2;kt++) wV2s[g][s][kt]=ldb(wsb+voff, tn*2+kt, lane);
      }
  }
  __syncthreads();

  const bf16* hbuf = (wave<2) ? &ha_b[0][0] : &hv_b[0][0];

  for (int t=0;t<TSTEPS;++t){
    const bf16* xwt = xwf + ((size_t)(t*128 + blockIdx.x))*16384;

    // ---- phase B ----
    // xw fragment loads (issued first; consumed at combine)
    bf16x4 xwL[4][2], xw2[4][2];
    #pragma unroll
    for (int g=0;g<4;g++)
      #pragma unroll
      for (int s=0;s<2;s++){
        int ntL = g*8 + wave*2 + s;
        xwL[g][s] = *(const bf16x4*)(xwt + ((size_t)ntL*64+lane)*4);
        int nt2 = (wave<2) ? (32 + g*4 + wave*2 + s) : (48 + g*4 + (wave-2)*2 + s);
        xw2[g][s] = *(const bf16x4*)(xwt + ((size_t)nt2*64+lane)*4);
      }

    f32x4 accL[4][2], acc2[4][2];
    #pragma unroll
    for (int g=0;g<4;g++)
      #pragma unroll
      for (int s=0;s<2;s++){ accL[g][s]=(f32x4){0,0,0,0}; acc2[g][s]=(f32x4){0,0,0,0}; }

    // A/V z-part first (kills wV2s liveness early)
    #pragma unroll
    for (int kt=0;kt<2;kt++){
      bf16x8 a = lda(&zz_b[0][0],72,kt,lane);
      #pragma unroll
      for (int g=0;g<4;g++)
        #pragma unroll
        for (int s=0;s<2;s++) acc2[g][s]=mfma16(a,wV2s[g][s][kt],acc2[g][s]);
    }
    // L z-part
    #pragma unroll
    for (int kt=0;kt<2;kt++){
      bf16x8 a = lda(&zz_b[0][0],72,kt,lane);
      #pragma unroll
      for (int g=0;g<4;g++)
        #pragma unroll
        for (int s=0;s<2;s++) accL[g][s]=mfma16(a,wVl[g][s][kt],accL[g][s]);
    }

    // issue D1 score-weight stream (used after next barrier)
    bf16x8 d1a[16];
    if (wave==0){
      #pragma unroll
      for (int ntv=0;ntv<4;ntv++)
        #pragma unroll
        for (int kt=0;kt<4;kt++) d1a[ntv*4+kt]=ldb(wsb+OFF_nlW1, ntv*4+kt, lane);
    } else if (wave==1){
      #pragma unroll
      for (int ntv=0;ntv<4;ntv++)
        #pragma unroll
        for (int kt=0;kt<4;kt++) d1a[ntv*4+kt]=ldb(wsb+OFF_nlW1, (ntv+4)*4+kt, lane);
    } else if (wave==2){
      #pragma unroll
      for (int ntv=0;ntv<8;ntv++)
        #pragma unroll
        for (int kt=0;kt<2;kt++) d1a[ntv*2+kt]=ldb(wsb+OFF_naW1, ntv*2+kt, lane);
    } else {
      #pragma unroll
      for (int ntv=0;ntv<8;ntv++)
        #pragma unroll
        for (int kt=0;kt<2;kt++) d1a[ntv*2+kt]=ldb(wsb+OFF_nvW1, ntv*2+kt, lane);
    }

    // A/V h-part
    #pragma unroll
    for (int kt=0;kt<2;kt++){
      bf16x8 a = lda(hbuf,72,kt,lane);
      #pragma unroll
      for (int g=0;g<4;g++)
        #pragma unroll
        for (int s=0;s<2;s++) acc2[g][s]=mfma16(a,wU2[g][s][kt],acc2[g][s]);
    }
    // L h-part
    #pragma unroll
    for (int kt=0;kt<4;kt++){
      bf16x8 a = lda(&hl_b[0][0],136,kt,lane);
      #pragma unroll
      for (int g=0;g<4;g++)
        #pragma unroll
        for (int s=0;s<2;s++) accL[g][s]=mfma16(a,wUl[g][s][kt],accL[g][s]);
    }
    __syncthreads();   // bar1: all reads of prev state done

    // ---- gate combine ----
    #pragma unroll
    for (int s=0;s<2;s++){
      const int uL = (wave*2+s)*16 + cL;
      #pragma unroll
      for (int q=0;q<4;q++){
        const int row = rb+q;
        float f  = sigm (accL[0][s][q] + (float)xwL[0][s][q] + blb[uL]);
        float ig = sigm (accL[1][s][q] + (float)xwL[1][s][q] + blb[128+uL]);
        float o  = sigm (accL[2][s][q] + (float)xwL[2][s][q] + blb[256+uL]);
        float ch = ftanh(accL[3][s][q] + (float)xwL[3][s][q] + blb[384+uL]);
        float c = f*cl32[row][uL] + ig*ch;
        float h = ftanh(c)*o;
        cl32[row][uL]=c; hl32[row][uL]=h;
        cl_b[row][uL]=(bf16)c; hl_b[row][uL]=(bf16)h;
      }
    }
    #pragma unroll
    for (int s=0;s<2;s++){
      const int u2 = ((wave&1)*2+s)*16 + cL;
      if (wave<2){
        #pragma unroll
        for (int q=0;q<4;q++){
          const int row = rb+q;
          float f  = sigm (acc2[0][s][q] + (float)xw2[0][s][q] + bab[u2]);
          float ig = sigm (acc2[1][s][q] + (float)xw2[1][s][q] + bab[64+u2]);
          float o  = sigm (acc2[2][s][q] + (float)xw2[2][s][q] + bab[128+u2]);
          float ch = ftanh(acc2[3][s][q] + (float)xw2[3][s][q] + bab[192+u2]);
          float c = f*ca32[row][u2] + ig*ch;
          float h = ftanh(c)*o;
          ca32[row][u2]=c; ha32[row][u2]=h;
          ca_b[row][u2]=(bf16)c; ha_b[row][u2]=(bf16)h;
        }
      } else {
        #pragma unroll
        for (int q=0;q<4;q++){
          const int row = rb+q;
          float f  = sigm (acc2[0][s][q] + (float)xw2[0][s][q] + bvb[u2]);
          float ig = sigm (acc2[1][s][q] + (float)xw2[1][s][q] + bvb[64+u2]);
          float o  = sigm (acc2[2][s][q] + (float)xw2[2][s][q] + bvb[128+u2]);
          float ch = ftanh(acc2[3][s][q] + (float)xw2[3][s][q] + bvb[192+u2]);
          float c = f*cv32[row][u2] + ig*ch;
          float h = ftanh(c)*o;
          cv32[row][u2]=c; hv32[row][u2]=h;
          cv_b[row][u2]=(bf16)c; hv_b[row][u2]=(bf16)h;
        }
      }
    }
    // issue D1 att-weight stream (used after bar2)
    bf16x8 d1b[16];
    #pragma unroll
    for (int j=0;j<2;j++)
      #pragma unroll
      for (int kt=0;kt<8;kt++) d1b[j*8+kt]=ldb(wsb+OFF_attW1, (wave*2+j)*8+kt, lane);
    __syncthreads();   // bar2: new c,h visible

    // ---- D1 ----
    if (wave<2){          // nlW1: 4 n-tiles each
      #pragma unroll
      for (int g=0;g<4;g++){
        f32x4 acc={0,0,0,0};
        #pragma unroll
        for (int kt=0;kt<4;kt++){
          bf16x8 a = lda(&cl_b[0][0],136,kt,lane);
          acc = mfma16(a, d1a[g*4+kt], acc);
        }
        const int col=(wave*4+g)*16+cL;
        const float b=b_nl1[col];
        #pragma unroll
        for (int q=0;q<4;q++) hidl_b[rb+q][col]=(bf16)fmaxf(acc[q]+b,0.f);
      }
    } else if (wave==2){  // naW1: 8 n-tiles
      #pragma unroll
      for (int g=0;g<8;g++){
        f32x4 acc={0,0,0,0};
        #pragma unroll
        for (int kt=0;kt<2;kt++){
          bf16x8 a = lda(&ca_b[0][0],72,kt,lane);
          acc = mfma16(a, d1a[g*2+kt], acc);
        }
        const int col=g*16+cL;
        const float b=b_na1[col];
        #pragma unroll
        for (int q=0;q<4;q++) hida_b[rb+q][col]=(bf16)fmaxf(acc[q]+b,0.f);
      }
    } else {              // nvW1
      #pragma unroll
      for (int g=0;g<8;g++){
        f32x4 acc={0,0,0,0};
        #pragma unroll
        for (int kt=0;kt<2;kt++){
          bf16x8 a = lda(&cv_b[0][0],72,kt,lane);
          acc = mfma16(a, d1a[g*2+kt], acc);
        }
        const int col=g*16+cL;
        const float b=b_nv1[col];
        #pragma unroll
        for (int q=0;q<4;q++) hidv_b[rb+q][col]=(bf16)fmaxf(acc[q]+b,0.f);
      }
    }
    // att part: every wave does 2 n-tiles (K=256 over [cl;ca;cv])
    #pragma unroll
    for (int j=0;j<2;j++){
      f32x4 acc={0,0,0,0};
      #pragma unroll
      for (int kt=0;kt<8;kt++){
        bf16x8 a = (kt<4) ? lda(&cl_b[0][0],136,kt,lane)
                 : (kt<6) ? lda(&ca_b[0][0],72,kt-4,lane)
                          : lda(&cv_b[0][0],72,kt-6,lane);
        acc = mfma16(a, d1b[j*8+kt], acc);
      }
      const int col=(wave*2+j)*16+cL;
      const float b=b_at1[col];
      #pragma unroll
      for (int q=0;q<4;q++) hidat_b[rb+q][col]=(bf16)fmaxf(acc[q]+b,0.f);
    }
    __syncthreads();   // bar3

    // ---- D2 (B-fragments from LDS) ----
    if (wave==0){
      #pragma unroll
      for (int g=0;g<4;g++){
        f32x4 acc={0,0,0,0};
        #pragma unroll
        for (int kt=0;kt<4;kt++){
          bf16x8 a = lda(&hidl_b[0][0],136,kt,lane);
          bf16x8 b = *(const bf16x8*)(w2lds + ((g*4+kt)*64+lane)*8);
          acc = mfma16(a,b,acc);
        }
        const int col=g*16+cL; const float b=b_nl2[col];
        #pragma unroll
        for (int q=0;q<4;q++) scl[rb+q][col]=acc[q]+b;
      }
    } else if (wave==1){
      #pragma unroll
      for (int g=0;g<4;g++){
        f32x4 acc={0,0,0,0};
        #pragma unroll
        for (int kt=0;kt<4;kt++){
          bf16x8 a = lda(&hida_b[0][0],136,kt,lane);
          bf16x8 b = *(const bf16x8*)(w2lds + 8192 + ((g*4+kt)*64+lane)*8);
          acc = mfma16(a,b,acc);
        }
        const int col=g*16+cL; const float b=b_na2[col];
        #pragma unroll
        for (int q=0;q<4;q++) sca[rb+q][col]=acc[q]+b;
      }
    } else if (wave==2){
      #pragma unroll
      for (int g=0;g<4;g++){
        f32x4 acc={0,0,0,0};
        #pragma unroll
        for (int kt=0;kt<4;kt++){
          bf16x8 a = lda(&hidv_b[0][0],136,kt,lane);
          bf16x8 b = *(const bf16x8*)(w2lds + 16384 + ((g*4+kt)*64+lane)*8);
          acc = mfma16(a,b,acc);
        }
        const int col=g*16+cL; const float b=b_nv2[col];
        #pragma unroll
        for (int q=0;q<4;q++) scv[rb+q][col]=acc[q]+b;
      }
    } else {
      f32x4 acc={0,0,0,0};
      #pragma unroll
      for (int kt=0;kt<4;kt++){
        bf16x8 a = lda(&hidat_b[0][0],136,kt,lane);
        bf16x8 b = *(const bf16x8*)(w2lds + 24576 + (kt*64+lane)*8);
        acc = mfma16(a,b,acc);
      }
      if (cL<3){
        const float b=b_at2[cL];
        #pragma unroll
        for (int q=0;q<4;q++) attlog[rb+q][cL]=acc[q]+b;
      }
    }
    // reload streamed z-part weights for next step (latency hidden across bar4/D3)
    {
      const int woff = (wave<2) ? wave*2 : (wave-2)*2;
      const int voff = (wave<2) ? OFF_Va : OFF_Vv;
      #pragma unroll
      for (int g=0;g<4;g++)
        #pragma unroll
        for (int s=0;s<2;s++){
          int tn = g*4 + woff + s;
          #pragma unroll
          for (int kt=0;kt<2;kt++) wV2s[g][s][kt]=ldb(wsb+voff, tn*2+kt, lane);
        }
    }
    __syncthreads();   // bar4

    // ---- D3: softmax + z ----
    #pragma unroll
    for (int s=0;s<4;s++){
      int item = tid + s*256;       // 16 rows x 64
      int r = item>>6, u = item&63;
      float a0=attlog[r][0], a1=attlog[r][1], a2=attlog[r][2];
      float m=fmaxf(a0,fmaxf(a1,a2));
      float e0=__expf(a0-m), e1=__expf(a1-m), e2=__expf(a2-m);
      float inv=1.f/(e0+e1+e2);
      float z=(e0*scl[r][u]+e1*sca[r][u]+e2*scv[r][u])*inv;
      zz32[r][u]=z; zz_b[r][u]=(bf16)z;
    }
    __syncthreads();   // bar5
  }

  // ---- final MLP (fp32) ----
  if (tid<128){
    const int j=tid;
    float acc[16];
    #pragma unroll
    for (int r=0;r<16;r++) acc[r]=p.outb1[j];
    for (int k=0;k<128;k++){ float wv=p.outW1[k*128+j];
      #pragma unroll
      for (int r=0;r<16;r++) acc[r]=fmaf(hl32[r][k],wv,acc[r]); }
    for (int k=0;k<64;k++){ float wv=p.outW1[(128+k)*128+j];
      #pragma unroll
      for (int r=0;r<16;r++) acc[r]=fmaf(ha32[r][k],wv,acc[r]); }
    for (int k=0;k<64;k++){ float wv=p.outW1[(192+k)*128+j];
      #pragma unroll
      for (int r=0;r<16;r++) acc[r]=fmaf(hv32[r][k],wv,acc[r]); }
    for (int k=0;k<64;k++){ float wv=p.outW1[(256+k)*128+j];
      #pragma unroll
      for (int r=0;r<16;r++) acc[r]=fmaf(zz32[r][k],wv,acc[r]); }
    #pragma unroll
    for (int r=0;r<16;r++) cl32[r][j]=fmaxf(acc[r],0.f);
  }
  __syncthreads();
  if (tid<16){
    float acc=p.outb2[0];
    for (int k=0;k<128;k++) acc=fmaf(cl32[tid][k],p.outW2[k],acc);
    p.out[n0+tid]=acc;
  }
}

// ================= fallback: original fp32 kernel (proven, no-ws path) =================
template<int R,int COLS,int KDIM,int INSTRIDE>
__device__ __forceinline__ void acc_mm(const float* __restrict__ W,
                                       const float* __restrict__ in,
                                       float acc[R], int j)
{
  constexpr int K4 = KDIM/4;
  #pragma unroll 2
  for (int k4=0;k4<K4;k4++){
    const int k=4*k4;
    float w0=W[(k+0)*COLS+j];
    float w1=W[(k+1)*COLS+j];
    float w2=W[(k+2)*COLS+j];
    float w3=W[(k+3)*COLS+j];
    #pragma unroll
    for (int r=0;r<R;r++){
      const float4 v = *(const float4*)(in + r*INSTRIDE + k);
      acc[r]=fmaf(v.w,w3,fmaf(v.z,w2,fmaf(v.y,w1,fmaf(v.x,w0,acc[r]))));
    }
  }
  if constexpr ((KDIM & 3) != 0) {
    #pragma unroll
    for (int k=K4*4;k<KDIM;k++){
      float wv=W[k*COLS+j];
      #pragma unroll
      for (int r=0;r<R;r++) acc[r]=fmaf(in[r*INSTRIDE+k],wv,acc[r]);
    }
  }
}

__global__ __launch_bounds__(THREADS)
void tman_kernel(Params p)
{
  __shared__ float xsl[ROWS][300];
  __shared__ float xsa[ROWS][76];
  __shared__ float xsv[ROWS][36];
  __shared__ float cl[ROWS][128], hl[ROWS][128];
  __shared__ float ca[ROWS][64],  ha[ROWS][64];
  __shared__ float cv[ROWS][64],  hv[ROWS][64];
  __shared__ float zz[ROWS][64];
  __shared__ float sl[ROWS][512];
  __shared__ float sa[ROWS][256];
  __shared__ float sv[ROWS][256];
  __shared__ float hidl[ROWS][128], hida[ROWS][128], hidv[ROWS][128], hidat[ROWS][128];
  __shared__ float scl[ROWS][64], sca[ROWS][64], scv[ROWS][64];
  __shared__ float attlog[ROWS][4];
  __shared__ float bl[512], ba[256], bv[256];

  const int tid  = threadIdx.x;
  const int lane = tid & 63;
  const int wave = tid >> 6;
  const int n0   = blockIdx.x * ROWS;

  for (int i=tid;i<512;i+=THREADS) bl[i]=p.bWl[i]+p.bUl[i]+p.bVl[i];
  for (int i=tid;i<256;i+=THREADS){ ba[i]=p.bWa[i]+p.bUa[i]+p.bVa[i]; bv[i]=p.bWv[i]+p.bUv[i]+p.bVv[i]; }
  for (int i=tid;i<ROWS*128;i+=THREADS){ (&cl[0][0])[i]=0.f; (&hl[0][0])[i]=0.f; }
  for (int i=tid;i<ROWS*64;i+=THREADS){
    (&ca[0][0])[i]=0.f; (&ha[0][0])[i]=0.f;
    (&cv[0][0])[i]=0.f; (&hv[0][0])[i]=0.f;
    (&zz[0][0])[i]=0.f;
  }
  __syncthreads();

  for (int t=0;t<TSTEPS;++t){
    const float* xt = p.x + ((size_t)t*NB + n0)*DXF;
    for (int i=tid;i<ROWS*DXF;i+=THREADS){
      int r=i/DXF, d=i-r*DXF;
      float v=xt[(size_t)r*DXF+d];
      if (d<300) xsl[r][d]=v;
      else if (d<374) xsa[r][d-300]=v;
      else xsv[r][d-374]=v;
    }
    __syncthreads();

    {
      int j = wave*64 + lane;
      float acc[ROWS]; float b=bl[j];
      #pragma unroll
      for (int r=0;r<ROWS;r++) acc[r]=b;
      acc_mm<ROWS,512,300,300>(p.Wl,&xsl[0][0],acc,j);
      acc_mm<ROWS,512,128,128>(p.Ul,&hl[0][0],acc,j);
      acc_mm<ROWS,512, 64, 64>(p.Vl,&zz[0][0],acc,j);
      #pragma unroll
      for (int r=0;r<ROWS;r++) sl[r][j]=acc[r];
    }
    {
      int item = 15-wave;
      if (item>=12){
        int j=(item-12)*64+lane;
        float acc[ROWS]; float b=bv[j];
        #pragma unroll
        for (int r=0;r<ROWS;r++) acc[r]=b;
        acc_mm<ROWS,256,35,36>(p.Wv,&xsv[0][0],acc,j);
        acc_mm<ROWS,256,64,64>(p.Uv,&hv[0][0],acc,j);
        acc_mm<ROWS,256,64,64>(p.Vv,&zz[0][0],acc,j);
        #pragma unroll
        for (int r=0;r<ROWS;r++) sv[r][j]=acc[r];
      } else {
        int j=(item-8)*64+lane;
        float acc[ROWS]; float b=ba[j];
        #pragma unroll
        for (int r=0;r<ROWS;r++) acc[r]=b;
        acc_mm<ROWS,256,74,76>(p.Wa,&xsa[0][0],acc,j);
        acc_mm<ROWS,256,64,64>(p.Ua,&ha[0][0],acc,j);
        acc_mm<ROWS,256,64,64>(p.Va,&zz[0][0],acc,j);
        #pragma unroll
        for (int r=0;r<ROWS;r++) sa[r][j]=acc[r];
      }
    }
    __syncthreads();

    for (int i=tid;i<ROWS*128;i+=THREADS){
      int r=i>>7, u=i&127;
      float f =sigm(sl[r][u]);
      float ig=sigm(sl[r][128+u]);
      float o =sigm(sl[r][256+u]);
      float ch=tanhf(sl[r][384+u]);
      float c=f*cl[r][u]+ig*ch;
      cl[r][u]=c; hl[r][u]=tanhf(c)*o;
    }
    for (int i=tid;i<ROWS*64;i+=THREADS){
      int r=i>>6, u=i&63;
      { float f=sigm(sa[r][u]), ig=sigm(sa[r][64+u]), o=sigm(sa[r][128+u]), ch=tanhf(sa[r][192+u]);
        float c=f*ca[r][u]+ig*ch; ca[r][u]=c; ha[r][u]=tanhf(c)*o; }
      { float f=sigm(sv[r][u]), ig=sigm(sv[r][64+u]), o=sigm(sv[r][128+u]), ch=tanhf(sv[r][192+u]);
        float c=f*cv[r][u]+ig*ch; cv[r][u]=c; hv[r][u]=tanhf(c)*o; }
    }
    __syncthreads();

    if (wave<2){
      int j=wave*64+lane;
      float acc[ROWS]; float b=p.nlb1[j];
      #pragma unroll
      for (int r=0;r<ROWS;r++) acc[r]=b;
      acc_mm<ROWS,128,128,128>(p.nlW1,&cl[0][0],acc,j);
      #pragma unroll
      for (int r=0;r<ROWS;r++) hidl[r][j]=fmaxf(acc[r],0.f);
    } else if (wave<4){
      int j=(wave-2)*64+lane;
      float acc[ROWS]; float b=p.nab1[j];
      #pragma unroll
      for (int r=0;r<ROWS;r++) acc[r]=b;
      acc_mm<ROWS,128,64,64>(p.naW1,&ca[0][0],acc,j);
      #pragma unroll
      for (int r=0;r<ROWS;r++) hida[r][j]=fmaxf(acc[r],0.f);
    } else if (wave<6){
      int j=(wave-4)*64+lane;
      float acc[ROWS]; float b=p.nvb1[j];
      #pragma unroll
      for (int r=0;r<ROWS;r++) acc[r]=b;
      acc_mm<ROWS,128,64,64>(p.nvW1,&cv[0][0],acc,j);
      #pragma unroll
      for (int r=0;r<ROWS;r++) hidv[r][j]=fmaxf(acc[r],0.f);
    } else {
      int j=(wave-6)*64+lane;
      float acc[ROWS]; float b=p.attb1[j];
      #pragma unroll
      for (int r=0;r<ROWS;r++) acc[r]=b;
      acc_mm<ROWS,128,128,128>(p.attW1,          &cl[0][0],acc,j);
      acc_mm<ROWS,128, 64, 64>(p.attW1+128*128,  &ca[0][0],acc,j);
      acc_mm<ROWS,128, 64, 64>(p.attW1+192*128,  &cv[0][0],acc,j);
      #pragma unroll
      for (int r=0;r<ROWS;r++) hidat[r][j]=fmaxf(acc[r],0.f);
    }
    __syncthreads();

    if (wave==0){
      float acc[ROWS]; float b=p.nlb2[lane];
      #pragma unroll
      for (int r=0;r<ROWS;r++) acc[r]=b;
      acc_mm<ROWS,64,128,128>(p.nlW2,&hidl[0][0],acc,lane);
      #pragma unroll
      for (int r=0;r<ROWS;r++) scl[r][lane]=acc[r];
    } else if (wave==1){
      float acc[ROWS]; float b=p.nab2[lane];
      #pragma unroll
      for (int r=0;r<ROWS;r++) acc[r]=b;
      acc_mm<ROWS,64,128,128>(p.naW2,&hida[0][0],acc,lane);
      #pragma unroll
      for (int r=0;r<ROWS;r++) sca[r][lane]=acc[r];
    } else if (wave==2){
      float acc[ROWS]; float b=p.nvb2[lane];
      #pragma unroll
      for (int r=0;r<ROWS;r++) acc[r]=b;
      acc_mm<ROWS,64,128,128>(p.nvW2,&hidv[0][0],acc,lane);
      #pragma unroll
      for (int r=0;r<ROWS;r++) scv[r][lane]=acc[r];
    } else if (wave==3 && lane<ROWS*3){
      int r=lane/3, m=lane-3*r;
      float a=p.attb2[m];
      for (int k=0;k<128;k++) a=fmaf(hidat[r][k],p.attW2[k*3+m],a);
      attlog[r][m]=a;
    }
    __syncthreads();

    for (int i=tid;i<ROWS*64;i+=THREADS){
      int r=i>>6, u=i&63;
      float a0=attlog[r][0], a1=attlog[r][1], a2=attlog[r][2];
      float m=fmaxf(a0,fmaxf(a1,a2));
      float e0=__expf(a0-m), e1=__expf(a1-m), e2=__expf(a2-m);
      float inv=1.f/(e0+e1+e2);
      zz[r][u]=(e0*scl[r][u]+e1*sca[r][u]+e2*scv[r][u])*inv;
    }
    __syncthreads();
  }

  if (wave<2){
    int j=wave*64+lane;
    float acc[ROWS]; float b=p.outb1[j];
    #pragma unroll
    for (int r=0;r<ROWS;r++) acc[r]=b;
    acc_mm<ROWS,128,128,128>(p.outW1,          &hl[0][0],acc,j);
    acc_mm<ROWS,128, 64, 64>(p.outW1+128*128,  &ha[0][0],acc,j);
    acc_mm<ROWS,128, 64, 64>(p.outW1+192*128,  &hv[0][0],acc,j);
    acc_mm<ROWS,128, 64, 64>(p.outW1+256*128,  &zz[0][0],acc,j);
    #pragma unroll
    for (int r=0;r<ROWS;r++) hidl[r][j]=fmaxf(acc[r],0.f);
  }
  __syncthreads();
  if (tid<ROWS){
    float acc=p.outb2[0];
    for (int k=0;k<128;k++) acc=fmaf(hidl[tid][k],p.outW2[k],acc);
    p.out[n0+tid]=acc;
  }
}

extern "C" void kernel_launch(void* const* d_in, const int* in_sizes, int n_in,
                              void* d_out, int out_size, void* d_ws, size_t ws_size,
                              hipStream_t stream) {
  const float* const* f = (const float* const*)d_in;
  Params P;
  P.x  =f[0];
  P.Wl =f[1];  P.bWl=f[2];  P.Ul =f[3];  P.bUl=f[4];  P.Vl =f[5];  P.bVl=f[6];
  P.Wa =f[7];  P.bWa=f[8];  P.Ua =f[9];  P.bUa=f[10]; P.Va =f[11]; P.bVa=f[12];
  P.Wv =f[13]; P.bWv=f[14]; P.Uv =f[15]; P.bUv=f[16]; P.Vv =f[17]; P.bVv=f[18];
  P.nlW1=f[19]; P.nlb1=f[20]; P.nlW2=f[21]; P.nlb2=f[22];
  P.naW1=f[23]; P.nab1=f[24]; P.naW2=f[25]; P.nab2=f[26];
  P.nvW1=f[27]; P.nvb1=f[28]; P.nvW2=f[29]; P.nvb2=f[30];
  P.attW1=f[31]; P.attb1=f[32]; P.attW2=f[33]; P.attb2=f[34];
  P.outW1=f[35]; P.outb1=f[36]; P.outW2=f[37]; P.outb2=f[38];
  P.out=(float*)d_out;
  P.ws =(const float*)d_ws;

  const size_t WS_NEED = ((size_t)WS_ELEMS + XWF_ELEMS) * sizeof(bf16);  // ~513 MB
  if (ws_size >= WS_NEED) {
    bf16* wsb = (bf16*)d_ws;
    struct Pk { const float* src; int off, K, Kp, N, Np; } pk[17] = {
      { f[1],  OFF_Wl,   300, 320, 512, 512 },
      { f[7],  OFF_Wa,    74,  96, 256, 256 },
      { f[13], OFF_Wv,    35,  64, 256, 256 },
      { f[3],  OFF_Ul,   128, 128, 512, 512 },
      { f[5],  OFF_Vl,    64,  64, 512, 512 },
      { f[9],  OFF_Ua,    64,  64, 256, 256 },
      { f[11], OFF_Va,    64,  64, 256, 256 },
      { f[15], OFF_Uv,    64,  64, 256, 256 },
      { f[17], OFF_Vv,    64,  64, 256, 256 },
      { f[19], OFF_nlW1, 128, 128, 128, 128 },
      { f[23], OFF_naW1,  64,  64, 128, 128 },
      { f[27], OFF_nvW1,  64,  64, 128, 128 },
      { f[31], OFF_attW1,256, 256, 128, 128 },
      { f[21], OFF_nlW2, 128, 128,  64,  64 },
      { f[25], OFF_naW2, 128, 128,  64,  64 },
      { f[29], OFF_nvW2, 128, 128,  64,  64 },
      { f[33], OFF_attW2,128, 128,   3,  16 },
    };
    for (int i=0;i<17;i++){
      int total = (pk[i].Np>>4) * (pk[i].Kp>>5) * 64;
      hipLaunchKernelGGL(pack_w, dim3((total+255)/256), dim3(256), 0, stream,
                         pk[i].src, wsb + pk[i].off, pk[i].K, pk[i].Kp, pk[i].N, pk[i].Np);
    }
    hipLaunchKernelGGL(xw_gemm_mfma, dim3(TSTEPS*NB/64), dim3(256), 0, stream,
                       P.x, wsb, wsb + XWF_OFF);
    hipLaunchKernelGGL(tman_mfma2, dim3(NB/MROWS), dim3(256), 0, stream, P);
  } else {
    hipLaunchKernelGGL(tman_kernel, dim3(NB/ROWS), dim3(THREADS), 0, stream, P);
  }
}

// Round 8
// 2806.757 us; speedup vs baseline: 4.9257x; 1.0463x over previous
//
#include <hip/hip_runtime.h>
#include <cmath>

#define ROWS 8
#define THREADS 512
#define NB 2048
#define TSTEPS 128
#define DXF 409

using bf16   = __bf16;
using bf16x8 = __attribute__((ext_vector_type(8))) __bf16;
using bf16x4 = __attribute__((ext_vector_type(4))) __bf16;
using f32x4  = __attribute__((ext_vector_type(4))) float;

struct Params {
  const float *x;
  const float *Wl,*bWl,*Ul,*bUl,*Vl,*bVl;
  const float *Wa,*bWa,*Ua,*bUa,*Va,*bVa;
  const float *Wv,*bWv,*Uv,*bUv,*Vv,*bVv;
  const float *nlW1,*nlb1,*nlW2,*nlb2;
  const float *naW1,*nab1,*naW2,*nab2;
  const float *nvW1,*nvb1,*nvW2,*nvb2;
  const float *attW1,*attb1,*attW2,*attb2;
  const float *outW1,*outb1,*outW2,*outb2;
  const float *ws;
  float *out;
};

__device__ __forceinline__ float sigm(float x){ return 1.0f/(1.0f+__expf(-x)); }
__device__ __forceinline__ float ftanh(float x){
  x = fminf(fmaxf(x,-15.f),15.f);
  float e = __expf(2.f*x);
  return (e-1.f)/(e+1.f);
}

// ===== packed-weight offsets (bf16 elements) — layout verified in round 5 =====
#define OFF_Wl    0
#define OFF_Wa    163840
#define OFF_Wv    188416
#define OFF_Ul    204800
#define OFF_Vl    270336
#define OFF_Ua    303104
#define OFF_Va    319488
#define OFF_Uv    335872
#define OFF_Vv    352256
#define OFF_nlW1  368640
#define OFF_naW1  385024
#define OFF_nvW1  393216
#define OFF_attW1 401408
#define OFF_nlW2  434176
#define OFF_naW2  442368
#define OFF_nvW2  450560
#define OFF_attW2 458752
#define WS_ELEMS  460800
#define XWF_OFF   460800
#define XWF_ELEMS ((size_t)16384*64*64*4)

__global__ __launch_bounds__(256)
void pack_w(const float* __restrict__ W, bf16* __restrict__ dst,
            int Kdim, int Kpad, int N, int Npad)
{
  const int nKT = Kpad >> 5;
  const int total = (Npad >> 4) * nKT * 64;
  int idx = blockIdx.x*256 + threadIdx.x;
  if (idx >= total) return;
  int lane = idx & 63;
  int tile = idx >> 6;
  int tn = tile / nKT, tk = tile - tn*nKT;
  int col = (tn<<4) + (lane & 15);
  int k0  = (tk<<5) + ((lane>>4)<<3);
  bf16x8 v;
  #pragma unroll
  for (int i=0;i<8;i++){
    int kr = k0 + i;
    float f = (kr < Kdim && col < N) ? W[(size_t)kr*N + col] : 0.f;
    v[i] = (bf16)f;
  }
  ((bf16x8*)dst)[idx] = v;
}

__device__ __forceinline__ f32x4 mfma16(bf16x8 a, bf16x8 b, f32x4 c){
  return __builtin_amdgcn_mfma_f32_16x16x32_bf16(a, b, c, 0, 0, 0);
}
__device__ __forceinline__ bf16x8 lda(const bf16* buf, int stride, int kt, int lane){
  return *(const bf16x8*)(buf + (lane&15)*stride + (kt<<5) + ((lane>>4)<<3));
}
__device__ __forceinline__ bf16x8 ldb(const bf16* base, int tile, int lane){
  return ((const bf16x8*)base)[tile*64 + lane];
}

// ================= XW GEMM (MFMA) — unchanged from round 7 (proven) =================
__global__ __launch_bounds__(256)
void xw_gemm_mfma(const float* __restrict__ x, const bf16* __restrict__ wsb,
                  bf16* __restrict__ xwf)
{
  __shared__ __align__(16) bf16 axl[64][324];
  __shared__ __align__(16) bf16 axa[64][104];
  __shared__ __align__(16) bf16 axv[64][72];
  const int tid=threadIdx.x, lane=tid&63, wave=tid>>6;
  const int m0 = blockIdx.x * 64;

  for (int i=tid;i<64*324;i+=256) (&axl[0][0])[i]=(bf16)0.f;
  for (int i=tid;i<64*104;i+=256) (&axa[0][0])[i]=(bf16)0.f;
  for (int i=tid;i<64*72;i+=256)  (&axv[0][0])[i]=(bf16)0.f;
  __syncthreads();
  for (int i=tid;i<64*DXF;i+=256){
    int r=i/DXF, d=i-r*DXF;
    bf16 v = (bf16)x[(size_t)(m0+r)*DXF + d];
    if (d<300) axl[r][d]=v;
    else if (d<374) axa[r][d-300]=v;
    else axv[r][d-374]=v;
  }
  __syncthreads();

  const size_t mt = (size_t)blockIdx.x*4 + wave;
  const int r0 = ((wave<<4) + (lane&15));
  const int k8 = ((lane>>4)<<3);

  for (int nt=0;nt<32;nt++){
    f32x4 acc = {0,0,0,0};
    #pragma unroll
    for (int kt=0;kt<10;kt++){
      bf16x8 a = *(const bf16x8*)(&axl[r0][(kt<<5)+k8]);
      acc = mfma16(a, ldb(wsb+OFF_Wl, nt*10+kt, lane), acc);
    }
    bf16x4 o;
    #pragma unroll
    for (int q=0;q<4;q++) o[q]=(bf16)acc[q];
    *(bf16x4*)(xwf + ((mt*64 + nt)*64 + lane)*4) = o;
  }
  for (int tn=0;tn<16;tn++){
    f32x4 acc = {0,0,0,0};
    #pragma unroll
    for (int kt=0;kt<3;kt++){
      bf16x8 a = *(const bf16x8*)(&axa[r0][(kt<<5)+k8]);
      acc = mfma16(a, ldb(wsb+OFF_Wa, tn*3+kt, lane), acc);
    }
    bf16x4 o;
    #pragma unroll
    for (int q=0;q<4;q++) o[q]=(bf16)acc[q];
    *(bf16x4*)(xwf + ((mt*64 + 32 + tn)*64 + lane)*4) = o;
  }
  for (int tn=0;tn<16;tn++){
    f32x4 acc = {0,0,0,0};
    #pragma unroll
    for (int kt=0;kt<2;kt++){
      bf16x8 a = *(const bf16x8*)(&axv[r0][(kt<<5)+k8]);
      acc = mfma16(a, ldb(wsb+OFF_Wv, tn*2+kt, lane), acc);
    }
    bf16x4 o;
    #pragma unroll
    for (int q=0;q<4;q++) o[q]=(bf16)acc[q];
    *(bf16x4*)(xwf + ((mt*64 + 48 + tn)*64 + lane)*4) = o;
  }
}

// ================= recurrent kernel: 512 thr (8 waves, 2/SIMD), 8 rows/block, grid 256 =================
__global__ __launch_bounds__(512, 1)
void tman_mfma3(Params p)
{
  __shared__ float cl32[16][132], hl32[16][132];
  __shared__ float ca32[16][68], ha32[16][68], cv32[16][68], hv32[16][68], zz32[16][68];
  __shared__ float scl[16][68], sca[16][68], scv[16][68];
  __shared__ float attlog[16][4];
  __shared__ float blb[512], bab[256], bvb[256];
  __shared__ float b_nl1[128], b_na1[128], b_nv1[128], b_at1[128];
  __shared__ float b_nl2[64], b_na2[64], b_nv2[64], b_at2[4];
  __shared__ __align__(16) bf16 hl_b[16][136], cl_b[16][136];
  __shared__ __align__(16) bf16 ha_b[16][72], hv_b[16][72], ca_b[16][72], cv_b[16][72], zz_b[16][72];
  __shared__ __align__(16) bf16 hidl_b[16][136], hida_b[16][136], hidv_b[16][136], hidat_b[16][136];

  const int tid=threadIdx.x, lane=tid&63, wave=tid>>6;
  const int rb=((lane>>4)<<2), cL=lane&15;
  // XCD-pair swizzle: blocks 2k,2k+1 (sharing one xw tile) land on the same XCD
  const int b = ((blockIdx.x & 7) << 5) | (blockIdx.x >> 3);
  const int n0 = b*ROWS;
  const int roff = (b&1)*8;               // this block's rows live in fragment rows roff..roff+7
  const bool own = ((rb>>3) == (b&1));    // lane's fragment rows are the real ones
  const int j2 = wave & 3;
  const bf16* wsb=(const bf16*)p.ws;
  const bf16* xwf=wsb + XWF_OFF;

  // biases to LDS
  if (tid<512) blb[tid]=p.bWl[tid]+p.bUl[tid]+p.bVl[tid];
  if (tid<256){ bab[tid]=p.bWa[tid]+p.bUa[tid]+p.bVa[tid]; bvb[tid]=p.bWv[tid]+p.bUv[tid]+p.bVv[tid]; }
  if (tid<128){ b_nl1[tid]=p.nlb1[tid]; b_na1[tid]=p.nab1[tid]; b_nv1[tid]=p.nvb1[tid]; b_at1[tid]=p.attb1[tid]; }
  if (tid<64){ b_nl2[tid]=p.nlb2[tid]; b_na2[tid]=p.nab2[tid]; b_nv2[tid]=p.nvb2[tid]; }
  if (tid<4) b_at2[tid] = (tid<3) ? p.attb2[tid] : 0.f;
  // zero state (all 16 rows; non-owned rows stay zero forever)
  for (int i=tid;i<16*132;i+=512) (&cl32[0][0])[i]=0.f;
  for (int i=tid;i<16*68;i+=512){ (&ca32[0][0])[i]=0.f; (&cv32[0][0])[i]=0.f; (&zz32[0][0])[i]=0.f; }
  for (int i=tid;i<16*136;i+=512){
    (&hl_b[0][0])[i]=(bf16)0.f; (&cl_b[0][0])[i]=(bf16)0.f;
    (&hidl_b[0][0])[i]=(bf16)0.f; (&hida_b[0][0])[i]=(bf16)0.f;
    (&hidv_b[0][0])[i]=(bf16)0.f; (&hidat_b[0][0])[i]=(bf16)0.f;
  }
  for (int i=tid;i<16*72;i+=512){
    (&ha_b[0][0])[i]=(bf16)0.f; (&hv_b[0][0])[i]=(bf16)0.f;
    (&ca_b[0][0])[i]=(bf16)0.f; (&cv_b[0][0])[i]=(bf16)0.f;
    (&zz_b[0][0])[i]=(bf16)0.f;
  }

  // ---- persistent weights (128 VGPR): wUl 16 frags, wU2 8, wV2 8 ----
  bf16x8 wUl[4][4], wU2[4][2], wV2[4][2];
  #pragma unroll
  for (int g=0;g<4;g++)
    #pragma unroll
    for (int kt=0;kt<4;kt++) wUl[g][kt]=ldb(wsb+OFF_Ul,(g*8+wave)*4+kt,lane);
  {
    const int uoff = (wave<4)?OFF_Ua:OFF_Uv;
    const int voff = (wave<4)?OFF_Va:OFF_Vv;
    #pragma unroll
    for (int g=0;g<4;g++)
      #pragma unroll
      for (int kt=0;kt<2;kt++){
        wU2[g][kt]=ldb(wsb+uoff,(g*4+j2)*2+kt,lane);
        wV2[g][kt]=ldb(wsb+voff,(g*4+j2)*2+kt,lane);
      }
  }
  // streamed L z-part weights (reloaded each step during D2)
  bf16x8 wVls[4][2];
  #pragma unroll
  for (int g=0;g<4;g++)
    #pragma unroll
    for (int kt=0;kt<2;kt++) wVls[g][kt]=ldb(wsb+OFF_Vl,(g*8+wave)*2+kt,lane);
  __syncthreads();

  const bf16* hbuf2 = (wave<4) ? &ha_b[0][0] : &hv_b[0][0];

  for (int t=0;t<TSTEPS;++t){
    const bf16* xwt = xwf + ((size_t)(t*128 + (b>>1)))*16384;

    // ---- phase B ----
    bf16x4 xwL[4], xw2[4];
    #pragma unroll
    for (int g=0;g<4;g++){
      xwL[g] = *(const bf16x4*)(xwt + ((size_t)(g*8+wave)*64+lane)*4);
      int nt2 = (wave<4) ? (32 + g*4 + j2) : (48 + g*4 + j2);
      xw2[g] = *(const bf16x4*)(xwt + ((size_t)nt2*64+lane)*4);
    }

    f32x4 accL[4], acc2[4];
    #pragma unroll
    for (int g=0;g<4;g++){ accL[g]=(f32x4){0,0,0,0}; acc2[g]=(f32x4){0,0,0,0}; }

    // z-parts first (frees wVls early)
    #pragma unroll
    for (int kt=0;kt<2;kt++){
      bf16x8 a = lda(&zz_b[0][0],72,kt,lane);
      #pragma unroll
      for (int g=0;g<4;g++){ accL[g]=mfma16(a,wVls[g][kt],accL[g]); acc2[g]=mfma16(a,wV2[g][kt],acc2[g]); }
    }

    // issue D1 score-weight stream (consumed after bar2)
    bf16x8 d1s[8];
    #pragma unroll
    for (int kt=0;kt<4;kt++) d1s[kt]  =ldb(wsb+OFF_nlW1, wave*4+kt, lane);
    #pragma unroll
    for (int kt=0;kt<2;kt++) d1s[4+kt]=ldb(wsb+OFF_naW1, wave*2+kt, lane);
    #pragma unroll
    for (int kt=0;kt<2;kt++) d1s[6+kt]=ldb(wsb+OFF_nvW1, wave*2+kt, lane);

    // h-parts
    #pragma unroll
    for (int kt=0;kt<2;kt++){
      bf16x8 a = lda(hbuf2,72,kt,lane);
      #pragma unroll
      for (int g=0;g<4;g++) acc2[g]=mfma16(a,wU2[g][kt],acc2[g]);
    }
    #pragma unroll
    for (int kt=0;kt<4;kt++){
      bf16x8 a = lda(&hl_b[0][0],136,kt,lane);
      #pragma unroll
      for (int g=0;g<4;g++) accL[g]=mfma16(a,wUl[g][kt],accL[g]);
    }
    __syncthreads();   // bar1: all reads of prev state done

    // ---- gate combine ----
    {
      const int uL = (wave<<4)+cL;
      #pragma unroll
      for (int q=0;q<4;q++){
        const int row = rb+q;
        float f  = sigm (accL[0][q] + (float)xwL[0][q] + blb[uL]);
        float ig = sigm (accL[1][q] + (float)xwL[1][q] + blb[128+uL]);
        float o  = sigm (accL[2][q] + (float)xwL[2][q] + blb[256+uL]);
        float ch = ftanh(accL[3][q] + (float)xwL[3][q] + blb[384+uL]);
        float c = f*cl32[row][uL] + ig*ch;
        float h = ftanh(c)*o;
        if (own){
          cl32[row][uL]=c; hl32[row][uL]=h;
          cl_b[row][uL]=(bf16)c; hl_b[row][uL]=(bf16)h;
        }
      }
      const int u2 = (j2<<4)+cL;
      if (wave<4){
        #pragma unroll
        for (int q=0;q<4;q++){
          const int row = rb+q;
          float f  = sigm (acc2[0][q] + (float)xw2[0][q] + bab[u2]);
          float ig = sigm (acc2[1][q] + (float)xw2[1][q] + bab[64+u2]);
          float o  = sigm (acc2[2][q] + (float)xw2[2][q] + bab[128+u2]);
          float ch = ftanh(acc2[3][q] + (float)xw2[3][q] + bab[192+u2]);
          float c = f*ca32[row][u2] + ig*ch;
          float h = ftanh(c)*o;
          if (own){
            ca32[row][u2]=c; ha32[row][u2]=h;
            ca_b[row][u2]=(bf16)c; ha_b[row][u2]=(bf16)h;
          }
        }
      } else {
        #pragma unroll
        for (int q=0;q<4;q++){
          const int row = rb+q;
          float f  = sigm (acc2[0][q] + (float)xw2[0][q] + bvb[u2]);
          float ig = sigm (acc2[1][q] + (float)xw2[1][q] + bvb[64+u2]);
          float o  = sigm (acc2[2][q] + (float)xw2[2][q] + bvb[128+u2]);
          float ch = ftanh(acc2[3][q] + (float)xw2[3][q] + bvb[192+u2]);
          float c = f*cv32[row][u2] + ig*ch;
          float h = ftanh(c)*o;
          if (own){
            cv32[row][u2]=c; hv32[row][u2]=h;
            cv_b[row][u2]=(bf16)c; hv_b[row][u2]=(bf16)h;
          }
        }
      }
    }
    // issue D1 att + D2 weight streams (consumed after bar2/bar3)
    bf16x8 d1t[8], d2s[8];
    #pragma unroll
    for (int kt=0;kt<8;kt++) d1t[kt]=ldb(wsb+OFF_attW1, wave*8+kt, lane);
    if (wave<4){
      #pragma unroll
      for (int kt=0;kt<4;kt++){ d2s[kt]=ldb(wsb+OFF_nlW2, wave*4+kt, lane);
                                d2s[4+kt]=ldb(wsb+OFF_nvW2, wave*4+kt, lane); }
    } else {
      #pragma unroll
      for (int kt=0;kt<4;kt++) d2s[kt]=ldb(wsb+OFF_naW2, (wave-4)*4+kt, lane);
      if (wave==7){
        #pragma unroll
        for (int kt=0;kt<4;kt++) d2s[4+kt]=ldb(wsb+OFF_attW2, kt, lane);
      }
    }
    __syncthreads();   // bar2: new c,h visible

    // ---- D1: each wave does nl/na/nv/att tile `wave` ----
    {
      f32x4 acc={0,0,0,0};
      #pragma unroll
      for (int kt=0;kt<4;kt++) acc=mfma16(lda(&cl_b[0][0],136,kt,lane), d1s[kt], acc);
      const int col=wave*16+cL; const float bb=b_nl1[col];
      if (own){
        #pragma unroll
        for (int q=0;q<4;q++) hidl_b[rb+q][col]=(bf16)fmaxf(acc[q]+bb,0.f);
      }
    }
    {
      f32x4 acc={0,0,0,0};
      #pragma unroll
      for (int kt=0;kt<2;kt++) acc=mfma16(lda(&ca_b[0][0],72,kt,lane), d1s[4+kt], acc);
      const int col=wave*16+cL; const float bb=b_na1[col];
      if (own){
        #pragma unroll
        for (int q=0;q<4;q++) hida_b[rb+q][col]=(bf16)fmaxf(acc[q]+bb,0.f);
      }
    }
    {
      f32x4 acc={0,0,0,0};
      #pragma unroll
      for (int kt=0;kt<2;kt++) acc=mfma16(lda(&cv_b[0][0],72,kt,lane), d1s[6+kt], acc);
      const int col=wave*16+cL; const float bb=b_nv1[col];
      if (own){
        #pragma unroll
        for (int q=0;q<4;q++) hidv_b[rb+q][col]=(bf16)fmaxf(acc[q]+bb,0.f);
      }
    }
    {
      f32x4 acc={0,0,0,0};
      #pragma unroll
      for (int kt=0;kt<8;kt++){
        bf16x8 a = (kt<4) ? lda(&cl_b[0][0],136,kt,lane)
                 : (kt<6) ? lda(&ca_b[0][0],72,kt-4,lane)
                          : lda(&cv_b[0][0],72,kt-6,lane);
        acc=mfma16(a, d1t[kt], acc);
      }
      const int col=wave*16+cL; const float bb=b_at1[col];
      if (own){
        #pragma unroll
        for (int q=0;q<4;q++) hidat_b[rb+q][col]=(bf16)fmaxf(acc[q]+bb,0.f);
      }
    }
    __syncthreads();   // bar3

    // ---- D2 ----
    if (wave<4){
      f32x4 acc={0,0,0,0};
      #pragma unroll
      for (int kt=0;kt<4;kt++) acc=mfma16(lda(&hidl_b[0][0],136,kt,lane), d2s[kt], acc);
      const int col=wave*16+cL;
      { const float bb=b_nl2[col];
        if (own){
          #pragma unroll
          for (int q=0;q<4;q++) scl[rb+q][col]=acc[q]+bb;
        } }
      f32x4 accv={0,0,0,0};
      #pragma unroll
      for (int kt=0;kt<4;kt++) accv=mfma16(lda(&hidv_b[0][0],136,kt,lane), d2s[4+kt], accv);
      { const float bb=b_nv2[col];
        if (own){
          #pragma unroll
          for (int q=0;q<4;q++) scv[rb+q][col]=accv[q]+bb;
        } }
    } else {
      f32x4 acc={0,0,0,0};
      #pragma unroll
      for (int kt=0;kt<4;kt++) acc=mfma16(lda(&hida_b[0][0],136,kt,lane), d2s[kt], acc);
      const int col=(wave-4)*16+cL; const float bb=b_na2[col];
      if (own){
        #pragma unroll
        for (int q=0;q<4;q++) sca[rb+q][col]=acc[q]+bb;
      }
      if (wave==7){
        f32x4 acct={0,0,0,0};
        #pragma unroll
        for (int kt=0;kt<4;kt++) acct=mfma16(lda(&hidat_b[0][0],136,kt,lane), d2s[4+kt], acct);
        if (own && cL<3){
          #pragma unroll
          for (int q=0;q<4;q++) attlog[rb+q][cL]=acct[q]+b_at2[cL];
        }
      }
    }
    // reload streamed wVl for next step (hidden under bar4/D3/bar5)
    #pragma unroll
    for (int g=0;g<4;g++)
      #pragma unroll
      for (int kt=0;kt<2;kt++) wVls[g][kt]=ldb(wsb+OFF_Vl,(g*8+wave)*2+kt,lane);
    __syncthreads();   // bar4

    // ---- D3: softmax + z (512 threads = 8 rows x 64) ----
    {
      const int r = roff + (tid>>6), u = tid&63;
      float a0=attlog[r][0], a1=attlog[r][1], a2=attlog[r][2];
      float m=fmaxf(a0,fmaxf(a1,a2));
      float e0=__expf(a0-m), e1=__expf(a1-m), e2=__expf(a2-m);
      float inv=1.f/(e0+e1+e2);
      float z=(e0*scl[r][u]+e1*sca[r][u]+e2*scv[r][u])*inv;
      zz32[r][u]=z; zz_b[r][u]=(bf16)z;
    }
    __syncthreads();   // bar5
  }

  // ---- final MLP (fp32, once): rows roff..roff+7 ----
  if (tid<128){
    const int j=tid;
    float acc[8];
    #pragma unroll
    for (int r=0;r<8;r++) acc[r]=p.outb1[j];
    for (int k=0;k<128;k++){ float wv=p.outW1[k*128+j];
      #pragma unroll
      for (int r=0;r<8;r++) acc[r]=fmaf(hl32[roff+r][k],wv,acc[r]); }
    for (int k=0;k<64;k++){ float wv=p.outW1[(128+k)*128+j];
      #pragma unroll
      for (int r=0;r<8;r++) acc[r]=fmaf(ha32[roff+r][k],wv,acc[r]); }
    for (int k=0;k<64;k++){ float wv=p.outW1[(192+k)*128+j];
      #pragma unroll
      for (int r=0;r<8;r++) acc[r]=fmaf(hv32[roff+r][k],wv,acc[r]); }
    for (int k=0;k<64;k++){ float wv=p.outW1[(256+k)*128+j];
      #pragma unroll
      for (int r=0;r<8;r++) acc[r]=fmaf(zz32[roff+r][k],wv,acc[r]); }
    #pragma unroll
    for (int r=0;r<8;r++) cl32[roff+r][j]=fmaxf(acc[r],0.f);
  }
  __syncthreads();
  if (tid<8){
    float acc=p.outb2[0];
    for (int k=0;k<128;k++) acc=fmaf(cl32[roff+tid][k],p.outW2[k],acc);
    p.out[n0+tid]=acc;
  }
}

// ================= fallback: original fp32 kernel (proven, no-ws path) =================
template<int R,int COLS,int KDIM,int INSTRIDE>
__device__ __forceinline__ void acc_mm(const float* __restrict__ W,
                                       const float* __restrict__ in,
                                       float acc[R], int j)
{
  constexpr int K4 = KDIM/4;
  #pragma unroll 2
  for (int k4=0;k4<K4;k4++){
    const int k=4*k4;
    float w0=W[(k+0)*COLS+j];
    float w1=W[(k+1)*COLS+j];
    float w2=W[(k+2)*COLS+j];
    float w3=W[(k+3)*COLS+j];
    #pragma unroll
    for (int r=0;r<R;r++){
      const float4 v = *(const float4*)(in + r*INSTRIDE + k);
      acc[r]=fmaf(v.w,w3,fmaf(v.z,w2,fmaf(v.y,w1,fmaf(v.x,w0,acc[r]))));
    }
  }
  if constexpr ((KDIM & 3) != 0) {
    #pragma unroll
    for (int k=K4*4;k<KDIM;k++){
      float wv=W[k*COLS+j];
      #pragma unroll
      for (int r=0;r<R;r++) acc[r]=fmaf(in[r*INSTRIDE+k],wv,acc[r]);
    }
  }
}

__global__ __launch_bounds__(THREADS)
void tman_kernel(Params p)
{
  __shared__ float xsl[ROWS][300];
  __shared__ float xsa[ROWS][76];
  __shared__ float xsv[ROWS][36];
  __shared__ float cl[ROWS][128], hl[ROWS][128];
  __shared__ float ca[ROWS][64],  ha[ROWS][64];
  __shared__ float cv[ROWS][64],  hv[ROWS][64];
  __shared__ float zz[ROWS][64];
  __shared__ float sl[ROWS][512];
  __shared__ float sa[ROWS][256];
  __shared__ float sv[ROWS][256];
  __shared__ float hidl[ROWS][128], hida[ROWS][128], hidv[ROWS][128], hidat[ROWS][128];
  __shared__ float scl[ROWS][64], sca[ROWS][64], scv[ROWS][64];
  __shared__ float attlog[ROWS][4];
  __shared__ float bl[512], ba[256], bv[256];

  const int tid  = threadIdx.x;
  const int lane = tid & 63;
  const int wave = tid >> 6;
  const int n0   = blockIdx.x * ROWS;

  for (int i=tid;i<512;i+=THREADS) bl[i]=p.bWl[i]+p.bUl[i]+p.bVl[i];
  for (int i=tid;i<256;i+=THREADS){ ba[i]=p.bWa[i]+p.bUa[i]+p.bVa[i]; bv[i]=p.bWv[i]+p.bUv[i]+p.bVv[i]; }
  for (int i=tid;i<ROWS*128;i+=THREADS){ (&cl[0][0])[i]=0.f; (&hl[0][0])[i]=0.f; }
  for (int i=tid;i<ROWS*64;i+=THREADS){
    (&ca[0][0])[i]=0.f; (&ha[0][0])[i]=0.f;
    (&cv[0][0])[i]=0.f; (&hv[0][0])[i]=0.f;
    (&zz[0][0])[i]=0.f;
  }
  __syncthreads();

  for (int t=0;t<TSTEPS;++t){
    const float* xt = p.x + ((size_t)t*NB + n0)*DXF;
    for (int i=tid;i<ROWS*DXF;i+=THREADS){
      int r=i/DXF, d=i-r*DXF;
      float v=xt[(size_t)r*DXF+d];
      if (d<300) xsl[r][d]=v;
      else if (d<374) xsa[r][d-300]=v;
      else xsv[r][d-374]=v;
    }
    __syncthreads();

    {
      int j = wave*64 + lane;
      float acc[ROWS]; float b=bl[j];
      #pragma unroll
      for (int r=0;r<ROWS;r++) acc[r]=b;
      acc_mm<ROWS,512,300,300>(p.Wl,&xsl[0][0],acc,j);
      acc_mm<ROWS,512,128,128>(p.Ul,&hl[0][0],acc,j);
      acc_mm<ROWS,512, 64, 64>(p.Vl,&zz[0][0],acc,j);
      #pragma unroll
      for (int r=0;r<ROWS;r++) sl[r][j]=acc[r];
    }
    {
      int item = 15-wave;
      if (item>=12){
        int j=(item-12)*64+lane;
        float acc[ROWS]; float b=bv[j];
        #pragma unroll
        for (int r=0;r<ROWS;r++) acc[r]=b;
        acc_mm<ROWS,256,35,36>(p.Wv,&xsv[0][0],acc,j);
        acc_mm<ROWS,256,64,64>(p.Uv,&hv[0][0],acc,j);
        acc_mm<ROWS,256,64,64>(p.Vv,&zz[0][0],acc,j);
        #pragma unroll
        for (int r=0;r<ROWS;r++) sv[r][j]=acc[r];
      } else {
        int j=(item-8)*64+lane;
        float acc[ROWS]; float b=ba[j];
        #pragma unroll
        for (int r=0;r<ROWS;r++) acc[r]=b;
        acc_mm<ROWS,256,74,76>(p.Wa,&xsa[0][0],acc,j);
        acc_mm<ROWS,256,64,64>(p.Ua,&ha[0][0],acc,j);
        acc_mm<ROWS,256,64,64>(p.Va,&zz[0][0],acc,j);
        #pragma unroll
        for (int r=0;r<ROWS;r++) sa[r][j]=acc[r];
      }
    }
    __syncthreads();

    for (int i=tid;i<ROWS*128;i+=THREADS){
      int r=i>>7, u=i&127;
      float f =sigm(sl[r][u]);
      float ig=sigm(sl[r][128+u]);
      float o =sigm(sl[r][256+u]);
      float ch=tanhf(sl[r][384+u]);
      float c=f*cl[r][u]+ig*ch;
      cl[r][u]=c; hl[r][u]=tanhf(c)*o;
    }
    for (int i=tid;i<ROWS*64;i+=THREADS){
      int r=i>>6, u=i&63;
      { float f=sigm(sa[r][u]), ig=sigm(sa[r][64+u]), o=sigm(sa[r][128+u]), ch=tanhf(sa[r][192+u]);
        float c=f*ca[r][u]+ig*ch; ca[r][u]=c; ha[r][u]=tanhf(c)*o; }
      { float f=sigm(sv[r][u]), ig=sigm(sv[r][64+u]), o=sigm(sv[r][128+u]), ch=tanhf(sv[r][192+u]);
        float c=f*cv[r][u]+ig*ch; cv[r][u]=c; hv[r][u]=tanhf(c)*o; }
    }
    __syncthreads();

    if (wave<2){
      int j=wave*64+lane;
      float acc[ROWS]; float b=p.nlb1[j];
      #pragma unroll
      for (int r=0;r<ROWS;r++) acc[r]=b;
      acc_mm<ROWS,128,128,128>(p.nlW1,&cl[0][0],acc,j);
      #pragma unroll
      for (int r=0;r<ROWS;r++) hidl[r][j]=fmaxf(acc[r],0.f);
    } else if (wave<4){
      int j=(wave-2)*64+lane;
      float acc[ROWS]; float b=p.nab1[j];
      #pragma unroll
      for (int r=0;r<ROWS;r++) acc[r]=b;
      acc_mm<ROWS,128,64,64>(p.naW1,&ca[0][0],acc,j);
      #pragma unroll
      for (int r=0;r<ROWS;r++) hida[r][j]=fmaxf(acc[r],0.f);
    } else if (wave<6){
      int j=(wave-4)*64+lane;
      float acc[ROWS]; float b=p.nvb1[j];
      #pragma unroll
      for (int r=0;r<ROWS;r++) acc[r]=b;
      acc_mm<ROWS,128,64,64>(p.nvW1,&cv[0][0],acc,j);
      #pragma unroll
      for (int r=0;r<ROWS;r++) hidv[r][j]=fmaxf(acc[r],0.f);
    } else {
      int j=(wave-6)*64+lane;
      float acc[ROWS]; float b=p.attb1[j];
      #pragma unroll
      for (int r=0;r<ROWS;r++) acc[r]=b;
      acc_mm<ROWS,128,128,128>(p.attW1,          &cl[0][0],acc,j);
      acc_mm<ROWS,128, 64, 64>(p.attW1+128*128,  &ca[0][0],acc,j);
      acc_mm<ROWS,128, 64, 64>(p.attW1+192*128,  &cv[0][0],acc,j);
      #pragma unroll
      for (int r=0;r<ROWS;r++) hidat[r][j]=fmaxf(acc[r],0.f);
    }
    __syncthreads();

    if (wave==0){
      float acc[ROWS]; float b=p.nlb2[lane];
      #pragma unroll
      for (int r=0;r<ROWS;r++) acc[r]=b;
      acc_mm<ROWS,64,128,128>(p.nlW2,&hidl[0][0],acc,lane);
      #pragma unroll
      for (int r=0;r<ROWS;r++) scl[r][lane]=acc[r];
    } else if (wave==1){
      float acc[ROWS]; float b=p.nab2[lane];
      #pragma unroll
      for (int r=0;r<ROWS;r++) acc[r]=b;
      acc_mm<ROWS,64,128,128>(p.naW2,&hida[0][0],acc,lane);
      #pragma unroll
      for (int r=0;r<ROWS;r++) sca[r][lane]=acc[r];
    } else if (wave==2){
      float acc[ROWS]; float b=p.nvb2[lane];
      #pragma unroll
      for (int r=0;r<ROWS;r++) acc[r]=b;
      acc_mm<ROWS,64,128,128>(p.nvW2,&hidv[0][0],acc,lane);
      #pragma unroll
      for (int r=0;r<ROWS;r++) scv[r][lane]=acc[r];
    } else if (wave==3 && lane<ROWS*3){
      int r=lane/3, m=lane-3*r;
      float a=p.attb2[m];
      for (int k=0;k<128;k++) a=fmaf(hidat[r][k],p.attW2[k*3+m],a);
      attlog[r][m]=a;
    }
    __syncthreads();

    for (int i=tid;i<ROWS*64;i+=THREADS){
      int r=i>>6, u=i&63;
      float a0=attlog[r][0], a1=attlog[r][1], a2=attlog[r][2];
      float m=fmaxf(a0,fmaxf(a1,a2));
      float e0=__expf(a0-m), e1=__expf(a1-m), e2=__expf(a2-m);
      float inv=1.f/(e0+e1+e2);
      zz[r][u]=(e0*scl[r][u]+e1*sca[r][u]+e2*scv[r][u])*inv;
    }
    __syncthreads();
  }

  if (wave<2){
    int j=wave*64+lane;
    float acc[ROWS]; float b=p.outb1[j];
    #pragma unroll
    for (int r=0;r<ROWS;r++) acc[r]=b;
    acc_mm<ROWS,128,128,128>(p.outW1,          &hl[0][0],acc,j);
    acc_mm<ROWS,128, 64, 64>(p.outW1+128*128,  &ha[0][0],acc,j);
    acc_mm<ROWS,128, 64, 64>(p.outW1+192*128,  &hv[0][0],acc,j);
    acc_mm<ROWS,128, 64, 64>(p.outW1+256*128,  &zz[0][0],acc,j);
    #pragma unroll
    for (int r=0;r<ROWS;r++) hidl[r][j]=fmaxf(acc[r],0.f);
  }
  __syncthreads();
  if (tid<ROWS){
    float acc=p.outb2[0];
    for (int k=0;k<128;k++) acc=fmaf(hidl[tid][k],p.outW2[k],acc);
    p.out[n0+tid]=acc;
  }
}

extern "C" void kernel_launch(void* const* d_in, const int* in_sizes, int n_in,
                              void* d_out, int out_size, void* d_ws, size_t ws_size,
                              hipStream_t stream) {
  const float* const* f = (const float* const*)d_in;
  Params P;
  P.x  =f[0];
  P.Wl =f[1];  P.bWl=f[2];  P.Ul =f[3];  P.bUl=f[4];  P.Vl =f[5];  P.bVl=f[6];
  P.Wa =f[7];  P.bWa=f[8];  P.Ua =f[9];  P.bUa=f[10]; P.Va =f[11]; P.bVa=f[12];
  P.Wv =f[13]; P.bWv=f[14]; P.Uv =f[15]; P.bUv=f[16]; P.Vv =f[17]; P.bVv=f[18];
  P.nlW1=f[19]; P.nlb1=f[20]; P.nlW2=f[21]; P.nlb2=f[22];
  P.naW1=f[23]; P.nab1=f[24]; P.naW2=f[25]; P.nab2=f[26];
  P.nvW1=f[27]; P.nvb1=f[28]; P.nvW2=f[29]; P.nvb2=f[30];
  P.attW1=f[31]; P.attb1=f[32]; P.attW2=f[33]; P.attb2=f[34];
  P.outW1=f[35]; P.outb1=f[36]; P.outW2=f[37]; P.outb2=f[38];
  P.out=(float*)d_out;
  P.ws =(const float*)d_ws;

  const size_t WS_NEED = ((size_t)WS_ELEMS + XWF_ELEMS) * sizeof(bf16);  // ~513 MB
  if (ws_size >= WS_NEED) {
    bf16* wsb = (bf16*)d_ws;
    struct Pk { const float* src; int off, K, Kp, N, Np; } pk[17] = {
      { f[1],  OFF_Wl,   300, 320, 512, 512 },
      { f[7],  OFF_Wa,    74,  96, 256, 256 },
      { f[13], OFF_Wv,    35,  64, 256, 256 },
      { f[3],  OFF_Ul,   128, 128, 512, 512 },
      { f[5],  OFF_Vl,    64,  64, 512, 512 },
      { f[9],  OFF_Ua,    64,  64, 256, 256 },
      { f[11], OFF_Va,    64,  64, 256, 256 },
      { f[15], OFF_Uv,    64,  64, 256, 256 },
      { f[17], OFF_Vv,    64,  64, 256, 256 },
      { f[19], OFF_nlW1, 128, 128, 128, 128 },
      { f[23], OFF_naW1,  64,  64, 128, 128 },
      { f[27], OFF_nvW1,  64,  64, 128, 128 },
      { f[31], OFF_attW1,256, 256, 128, 128 },
      { f[21], OFF_nlW2, 128, 128,  64,  64 },
      { f[25], OFF_naW2, 128, 128,  64,  64 },
      { f[29], OFF_nvW2, 128, 128,  64,  64 },
      { f[33], OFF_attW2,128, 128,   3,  16 },
    };
    for (int i=0;i<17;i++){
      int total = (pk[i].Np>>4) * (pk[i].Kp>>5) * 64;
      hipLaunchKernelGGL(pack_w, dim3((total+255)/256), dim3(256), 0, stream,
                         pk[i].src, wsb + pk[i].off, pk[i].K, pk[i].Kp, pk[i].N, pk[i].Np);
    }
    hipLaunchKernelGGL(xw_gemm_mfma, dim3(TSTEPS*NB/64), dim3(256), 0, stream,
                       P.x, wsb, wsb + XWF_OFF);
    hipLaunchKernelGGL(tman_mfma3, dim3(NB/ROWS), dim3(512), 0, stream, P);
  } else {
    hipLaunchKernelGGL(tman_kernel, dim3(NB/ROWS), dim3(THREADS), 0, stream, P);
  }
}